// Round 2
// baseline (719.509 us; speedup 1.0000x reference)
//
#include <hip/hip_runtime.h>

#define BN_EPS 1e-3f

// ---------------- threefry2x32 (JAX partitionable path, key=[0,42]) --------
__device__ __forceinline__ unsigned rotl32(unsigned v, int n) {
  return (v << n) | (v >> (32 - n));
}

// Reproduces jax.random.uniform(jax.random.key(42), (524288,)) element i
// under jax_threefry_partitionable=True (JAX >= 0.4.36 default):
// counter = uint64 iota -> x0 = hi32 = 0, x1 = lo32 = i; out = bits0 ^ bits1.
__device__ __forceinline__ float tf42_uniform(unsigned i) {
  unsigned x0 = 0u, x1 = i;
  const unsigned k0 = 0u, k1 = 42u, k2 = 0u ^ 42u ^ 0x1BD11BDAu;
  x0 += k0; x1 += k1;
#define TFR(r) { x0 += x1; x1 = rotl32(x1, r); x1 ^= x0; }
  TFR(13) TFR(15) TFR(26) TFR(6)
  x0 += k1; x1 += k2 + 1u;
  TFR(17) TFR(29) TFR(16) TFR(24)
  x0 += k2; x1 += k0 + 2u;
  TFR(13) TFR(15) TFR(26) TFR(6)
  x0 += k0; x1 += k1 + 3u;
  TFR(17) TFR(29) TFR(16) TFR(24)
  x0 += k1; x1 += k2 + 4u;
  TFR(13) TFR(15) TFR(26) TFR(6)
  x0 += k2; x1 += k0 + 5u;
#undef TFR
  unsigned bits = x0 ^ x1;
  return __uint_as_float((bits >> 9) | 0x3F800000u) - 1.0f;
}

// ---------------- K1: bn1 + conv1(4->32) + relu + maxpool2 + bn2 ----------------
// out h1: (128,36,36,32); thread per output pixel.
__global__ __launch_bounds__(256) void k_conv1(
    const float* __restrict__ img,
    const float* __restrict__ g1, const float* __restrict__ be1,
    const float* __restrict__ m1, const float* __restrict__ v1,
    const float* __restrict__ w, const float* __restrict__ bias,
    const float* __restrict__ g2, const float* __restrict__ be2,
    const float* __restrict__ m2, const float* __restrict__ v2,
    float* __restrict__ h1) {
  int t = blockIdx.x * 256 + threadIdx.x;  // grid exactly 648*256 = 128*36*36
  int ox = t % 36, oy = (t / 36) % 36, b = t / 1296;
  float s1[4], t1[4];
#pragma unroll
  for (int ci = 0; ci < 4; ++ci) {
    float s = g1[ci] / sqrtf(v1[ci] + BN_EPS);
    s1[ci] = s; t1[ci] = be1[ci] - m1[ci] * s;
  }
  float pacc[32];
#pragma unroll
  for (int co = 0; co < 32; ++co) pacc[co] = 0.f;
#pragma unroll
  for (int sy = 0; sy < 2; ++sy)
#pragma unroll
  for (int sx = 0; sx < 2; ++sx) {
    int iy = 2 * oy + sy, ix = 2 * ox + sx;
    float acc[32];
#pragma unroll
    for (int co = 0; co < 32; ++co) acc[co] = bias[co];
    for (int ky = 0; ky < 3; ++ky) {
      int yy = iy + ky - 1; if (yy < 0 || yy >= 72) continue;
      for (int kx = 0; kx < 3; ++kx) {
        int xx = ix + kx - 1; if (xx < 0 || xx >= 72) continue;
        float4 p = *(const float4*)(img + (((size_t)b * 72 + yy) * 72 + xx) * 4);
        float in0 = p.x * s1[0] + t1[0];
        float in1 = p.y * s1[1] + t1[1];
        float in2 = p.z * s1[2] + t1[2];
        float in3 = p.w * s1[3] + t1[3];
        const float* wp = w + (ky * 3 + kx) * 128;  // (3,3,4,32)
#pragma unroll
        for (int co = 0; co < 32; ++co) acc[co] = fmaf(in0, wp[co], acc[co]);
#pragma unroll
        for (int co = 0; co < 32; ++co) acc[co] = fmaf(in1, wp[32 + co], acc[co]);
#pragma unroll
        for (int co = 0; co < 32; ++co) acc[co] = fmaf(in2, wp[64 + co], acc[co]);
#pragma unroll
        for (int co = 0; co < 32; ++co) acc[co] = fmaf(in3, wp[96 + co], acc[co]);
      }
    }
#pragma unroll
    for (int co = 0; co < 32; ++co)
      pacc[co] = fmaxf(pacc[co], fmaxf(acc[co], 0.f));
  }
  // bn2 folded here (applied to pooled value, exactly as reference order)
#pragma unroll
  for (int co = 0; co < 32; ++co) {
    float s = g2[co] / sqrtf(v2[co] + BN_EPS);
    pacc[co] = pacc[co] * s + (be2[co] - m2[co] * s);
  }
  float* op = h1 + (size_t)t * 32;
#pragma unroll
  for (int c4 = 0; c4 < 8; ++c4) {
    float4 v;
    v.x = pacc[c4 * 4]; v.y = pacc[c4 * 4 + 1];
    v.z = pacc[c4 * 4 + 2]; v.w = pacc[c4 * 4 + 3];
    *(float4*)(op + c4 * 4) = v;
  }
}

// ---------------- K2: conv2(32->32) + relu + maxpool2 ----------------
__global__ __launch_bounds__(256) void k_conv2(
    const float* __restrict__ h1, const float* __restrict__ w,
    const float* __restrict__ bias, float* __restrict__ h2) {
  int t = blockIdx.x * 256 + threadIdx.x;  // grid 162*256 = 128*18*18
  int co0 = blockIdx.y * 8;
  int ox = t % 18, oy = (t / 18) % 18, b = t / 324;
  float pacc[8];
#pragma unroll
  for (int i = 0; i < 8; ++i) pacc[i] = 0.f;
#pragma unroll
  for (int sy = 0; sy < 2; ++sy)
#pragma unroll
  for (int sx = 0; sx < 2; ++sx) {
    int iy = 2 * oy + sy, ix = 2 * ox + sx;
    float acc[8];
#pragma unroll
    for (int i = 0; i < 8; ++i) acc[i] = bias[co0 + i];
    for (int ky = 0; ky < 3; ++ky) {
      int yy = iy + ky - 1; if (yy < 0 || yy >= 36) continue;
      for (int kx = 0; kx < 3; ++kx) {
        int xx = ix + kx - 1; if (xx < 0 || xx >= 36) continue;
        const float* ip = h1 + (((size_t)b * 36 + yy) * 36 + xx) * 32;
        const float* wp = w + (ky * 3 + kx) * 1024 + co0;  // (3,3,32,32)
        float in[32];
#pragma unroll
        for (int c4 = 0; c4 < 8; ++c4) {
          float4 p = *(const float4*)(ip + c4 * 4);
          in[c4 * 4] = p.x; in[c4 * 4 + 1] = p.y;
          in[c4 * 4 + 2] = p.z; in[c4 * 4 + 3] = p.w;
        }
#pragma unroll
        for (int ci = 0; ci < 32; ++ci)
#pragma unroll
          for (int i = 0; i < 8; ++i)
            acc[i] = fmaf(in[ci], wp[ci * 32 + i], acc[i]);
      }
    }
#pragma unroll
    for (int i = 0; i < 8; ++i) pacc[i] = fmaxf(pacc[i], fmaxf(acc[i], 0.f));
  }
  float* op = h2 + (size_t)t * 32 + co0;
  float4 v0, v1;
  v0.x = pacc[0]; v0.y = pacc[1]; v0.z = pacc[2]; v0.w = pacc[3];
  v1.x = pacc[4]; v1.y = pacc[5]; v1.z = pacc[6]; v1.w = pacc[7];
  *(float4*)op = v0;
  *(float4*)(op + 4) = v1;
}

// ---------------- K3a: dense partial GEMM (K-split) ----------------
#define AST 132
__global__ __launch_bounds__(256) void k_dense_part(
    const float* __restrict__ h2, const float* __restrict__ w,
    float* __restrict__ part) {
  __shared__ float a_lds[32 * AST];
  __shared__ float w_lds[32 * 64];
  int tid = threadIdx.x;
  int n0 = blockIdx.x * 64;   // 14 blocks (last ragged)
  int kc = blockIdx.y;        // 18 K-chunks of 576
  int m0 = (tid >> 4) * 8;
  int nl = (tid & 15) * 4;
  float acc[8][4];
#pragma unroll
  for (int i = 0; i < 8; ++i)
#pragma unroll
    for (int j = 0; j < 4; ++j) acc[i][j] = 0.f;
  for (int kt = 0; kt < 18; ++kt) {
    int kb = kc * 576 + kt * 32;
#pragma unroll
    for (int it = 0; it < 4; ++it) {
      int f = tid + it * 256;  // 0..1023 : 128 m rows x 8 float4
      int ml = f >> 3, kq = f & 7;
      float4 p = *(const float4*)(h2 + (size_t)ml * 10368 + kb + kq * 4);
      a_lds[(kq * 4 + 0) * AST + ml] = p.x;
      a_lds[(kq * 4 + 1) * AST + ml] = p.y;
      a_lds[(kq * 4 + 2) * AST + ml] = p.z;
      a_lds[(kq * 4 + 3) * AST + ml] = p.w;
    }
#pragma unroll
    for (int it = 0; it < 2; ++it) {
      int f = tid + it * 256;  // 0..511 : 32 k rows x 16 float4
      int kr = f >> 4, n4 = (f & 15) * 4;
      float4 p;
      if (n0 + n4 < 864)
        p = *(const float4*)(w + (size_t)(kb + kr) * 864 + n0 + n4);
      else { p.x = 0.f; p.y = 0.f; p.z = 0.f; p.w = 0.f; }
      *(float4*)(w_lds + kr * 64 + n4) = p;
    }
    __syncthreads();
#pragma unroll 4
    for (int k = 0; k < 32; ++k) {
      float4 wv = *(const float4*)(w_lds + k * 64 + nl);
      float4 a0 = *(const float4*)(a_lds + k * AST + m0);
      float4 a1 = *(const float4*)(a_lds + k * AST + m0 + 4);
      float am[8] = {a0.x, a0.y, a0.z, a0.w, a1.x, a1.y, a1.z, a1.w};
#pragma unroll
      for (int i = 0; i < 8; ++i) {
        acc[i][0] = fmaf(am[i], wv.x, acc[i][0]);
        acc[i][1] = fmaf(am[i], wv.y, acc[i][1]);
        acc[i][2] = fmaf(am[i], wv.z, acc[i][2]);
        acc[i][3] = fmaf(am[i], wv.w, acc[i][3]);
      }
    }
    __syncthreads();
  }
  if (n0 + nl < 864) {
#pragma unroll
    for (int i = 0; i < 8; ++i) {
      float4 v;
      v.x = acc[i][0]; v.y = acc[i][1]; v.z = acc[i][2]; v.w = acc[i][3];
      *(float4*)(part + ((size_t)kc * 128 + m0 + i) * 864 + n0 + nl) = v;
    }
  }
}

// ---------------- K3b: reduce K-split partials + bias + relu ----------------
__global__ __launch_bounds__(256) void k_dense_fin(
    const float* __restrict__ part, const float* __restrict__ bias,
    float* __restrict__ filt) {
  int e = blockIdx.x * 256 + threadIdx.x;  // grid 432*256 = 128*864
  float s = bias[e % 864];
#pragma unroll
  for (int kc = 0; kc < 18; ++kc) s += part[(size_t)kc * 110592 + e];
  filt[e] = fmaxf(s, 0.f);
}

// ---------------- K4: fused CA update ----------------
__global__ __launch_bounds__(256) void k_ca(
    const float* __restrict__ x, const float* __restrict__ filt,
    const float* __restrict__ W1, const float* __restrict__ B1,
    const float* __restrict__ W2, const float* __restrict__ B2,
    float* __restrict__ xnew, float* __restrict__ aold,
    float* __restrict__ anew) {
  __shared__ float fl[864];        // filters for this batch: [12][72]
  __shared__ float ia[76][100];    // img_aware halo tile, channel-major
  __shared__ float red[4][64][16]; // per-wave dx partials
  int tid = threadIdx.x;
  int b = blockIdx.y;
  int tx = (blockIdx.x & 7) * 8, ty = (blockIdx.x >> 3) * 8;

  for (int f = tid; f < 864; f += 256) fl[f] = filt[(size_t)b * 864 + f];
  __syncthreads();

  // phase B: img_aware (board 0..3, img_conv 4..75) over 10x10 halo
  if (tid < 200) {
    int pxh = tid >> 1, half = tid & 1;
    int hy = pxh / 10, hx = pxh % 10;
    int gy = ty + hy - 1, gx = tx + hx - 1;
    bool ok = (gy >= 0 && gy < 64 && gx >= 0 && gx < 64);
    int o0 = half ? 34 : 0, o1 = half ? 72 : 34;
    if (!ok) {
      if (half == 0) { ia[0][pxh] = 0.f; ia[1][pxh] = 0.f; ia[2][pxh] = 0.f; ia[3][pxh] = 0.f; }
      for (int o = o0; o < o1; ++o) ia[4 + o][pxh] = 0.f;
    } else {
      const float* xp = x + (((size_t)b * 64 + gy) * 64 + gx) * 16;
      float4 hA = *(const float4*)(xp + 4);
      float4 hB = *(const float4*)(xp + 8);
      float4 hC = *(const float4*)(xp + 12);
      float hid[12] = {hA.x, hA.y, hA.z, hA.w, hB.x, hB.y, hB.z, hB.w,
                       hC.x, hC.y, hC.z, hC.w};
      if (half == 0) {
        float4 bd = *(const float4*)xp;
        ia[0][pxh] = bd.x; ia[1][pxh] = bd.y; ia[2][pxh] = bd.z; ia[3][pxh] = bd.w;
      }
      for (int o = o0; o < o1; ++o) {
        float acc = 0.f;
#pragma unroll
        for (int c = 0; c < 12; ++c) acc = fmaf(hid[c], fl[c * 72 + o], acc);
        ia[4 + o][pxh] = acc;
      }
    }
  }
  __syncthreads();

  // phase C: perception + u = relu(P@W1+b1), wave w owns d in [32w,32w+32)
  int wv = __builtin_amdgcn_readfirstlane((int)tid >> 6);
  int lane = tid & 63;
  int ly = lane >> 3, lx = lane & 7;
  int hp = (ly + 1) * 10 + (lx + 1);
  int d0 = wv * 32;
  float u[32];
#pragma unroll
  for (int i = 0; i < 32; ++i) u[i] = B1[d0 + i];
  for (int c = 0; c < 76; ++c) {
    float n00 = ia[c][hp - 11], n01 = ia[c][hp - 10], n02 = ia[c][hp - 9];
    float n10 = ia[c][hp - 1],  n11 = ia[c][hp],      n12 = ia[c][hp + 1];
    float n20 = ia[c][hp + 9],  n21 = ia[c][hp + 10], n22 = ia[c][hp + 11];
    float pid = n11;
    float psx = ((n02 - n00) + 2.f * (n12 - n10) + (n22 - n20)) * 0.125f;
    float psy = ((n20 - n00) + 2.f * (n21 - n01) + (n22 - n02)) * 0.125f;
    const float* wr = W1 + (size_t)(3 * c) * 128 + d0;
#pragma unroll
    for (int i = 0; i < 32; ++i) u[i] = fmaf(pid, wr[i], u[i]);
#pragma unroll
    for (int i = 0; i < 32; ++i) u[i] = fmaf(psx, wr[128 + i], u[i]);
#pragma unroll
    for (int i = 0; i < 32; ++i) u[i] = fmaf(psy, wr[256 + i], u[i]);
  }
#pragma unroll
  for (int i = 0; i < 32; ++i) u[i] = fmaxf(u[i], 0.f);
  float dxp[16];
#pragma unroll
  for (int e = 0; e < 16; ++e) dxp[e] = 0.f;
#pragma unroll
  for (int i = 0; i < 32; ++i) {
    const float* w2r = W2 + (size_t)(d0 + i) * 16;
#pragma unroll
    for (int e = 0; e < 16; ++e) dxp[e] = fmaf(u[i], w2r[e], dxp[e]);
  }
#pragma unroll
  for (int e = 0; e < 16; ++e) red[wv][lane][e] = dxp[e];
  __syncthreads();

  // phase D: reduce, fire mask, write x_new + alphas
  int px = tid >> 2, q = tid & 3;
  int ply = px >> 3, plx = px & 7;
  int gy = ty + ply, gx = tx + plx;
  size_t base = (((size_t)b * 64 + gy) * 64 + gx) * 16;
  unsigned pix = (unsigned)(b * 4096 + gy * 64 + gx);
  float msk = (tf42_uniform(pix) <= 0.5f) ? 1.f : 0.f;
  int e0 = q * 4;
  float4 xo = *(const float4*)(x + base + e0);
  float d0v = red[0][px][e0 + 0] + red[1][px][e0 + 0] + red[2][px][e0 + 0] + red[3][px][e0 + 0] + B2[e0 + 0];
  float d1v = red[0][px][e0 + 1] + red[1][px][e0 + 1] + red[2][px][e0 + 1] + red[3][px][e0 + 1] + B2[e0 + 1];
  float d2v = red[0][px][e0 + 2] + red[1][px][e0 + 2] + red[2][px][e0 + 2] + red[3][px][e0 + 2] + B2[e0 + 2];
  float d3v = red[0][px][e0 + 3] + red[1][px][e0 + 3] + red[2][px][e0 + 3] + red[3][px][e0 + 3] + B2[e0 + 3];
  float4 xn;
  xn.x = xo.x + d0v * msk;
  xn.y = xo.y + d1v * msk;
  xn.z = xo.z + d2v * msk;
  xn.w = xo.w + d3v * msk;
  *(float4*)(xnew + base + e0) = xn;
  if (q == 0) {
    aold[pix] = xo.w;
    anew[pix] = xn.w;
  }
}

// ---------------- K5: living masks + final multiply (in place on d_out) ----
__global__ __launch_bounds__(256) void k_final(
    float* __restrict__ xnew, const float* __restrict__ aold,
    const float* __restrict__ anew) {
  int t = blockIdx.x * 256 + threadIdx.x;  // grid 2048*256 = 524288
  int gx = t & 63, gy = (t >> 6) & 63, b = t >> 12;
  float mo = -1e30f, mn = -1e30f;
  for (int dy = -1; dy <= 1; ++dy) {
    int yy = gy + dy; if (yy < 0 || yy >= 64) continue;
    for (int dx = -1; dx <= 1; ++dx) {
      int xx = gx + dx; if (xx < 0 || xx >= 64) continue;
      int p = b * 4096 + yy * 64 + xx;
      mo = fmaxf(mo, aold[p]);
      mn = fmaxf(mn, anew[p]);
    }
  }
  float live = (mo > 0.1f && mn > 0.1f) ? 1.f : 0.f;
  size_t base = (size_t)t * 16;
#pragma unroll
  for (int c4 = 0; c4 < 4; ++c4) {
    float4 v = *(const float4*)(xnew + base + c4 * 4);
    v.x *= live; v.y *= live; v.z *= live; v.w *= live;
    *(float4*)(xnew + base + c4 * 4) = v;
  }
}

// ---------------- launch ----------------
extern "C" void kernel_launch(void* const* d_in, const int* in_sizes, int n_in,
                              void* d_out, int out_size, void* d_ws, size_t ws_size,
                              hipStream_t stream) {
  const float* x    = (const float*)d_in[0];
  const float* img  = (const float*)d_in[1];
  const float* g1   = (const float*)d_in[2];
  const float* be1  = (const float*)d_in[3];
  const float* m1   = (const float*)d_in[4];
  const float* v1   = (const float*)d_in[5];
  const float* w1c  = (const float*)d_in[6];
  const float* b1c  = (const float*)d_in[7];
  const float* g2   = (const float*)d_in[8];
  const float* be2  = (const float*)d_in[9];
  const float* m2   = (const float*)d_in[10];
  const float* v2   = (const float*)d_in[11];
  const float* w2c  = (const float*)d_in[12];
  const float* b2c  = (const float*)d_in[13];
  const float* dw   = (const float*)d_in[14];
  const float* db   = (const float*)d_in[15];
  const float* uw1  = (const float*)d_in[16];
  const float* ub1  = (const float*)d_in[17];
  const float* uw2  = (const float*)d_in[18];
  const float* ub2  = (const float*)d_in[19];

  char* ws = (char*)d_ws;
  float* h1   = (float*)(ws);                       // 21,233,664 B
  float* part = h1;                                 // aliased after K2 done (7,962,624 B)
  float* h2   = (float*)(ws + 21233664);            // 5,308,416 B
  float* filt = (float*)(ws + 26542080);            // 442,368 B
  float* aold = (float*)(ws + 26984448);            // 2,097,152 B
  float* anew = (float*)(ws + 29081600);            // 2,097,152 B
  // total 31,178,752 B
  float* xnew = (float*)d_out;                      // (128,64,64,16) f32

  k_conv1<<<648, 256, 0, stream>>>(img, g1, be1, m1, v1, w1c, b1c,
                                   g2, be2, m2, v2, h1);
  k_conv2<<<dim3(162, 4), 256, 0, stream>>>(h1, w2c, b2c, h2);
  k_dense_part<<<dim3(14, 18), 256, 0, stream>>>(h2, dw, part);
  k_dense_fin<<<432, 256, 0, stream>>>(part, db, filt);
  k_ca<<<dim3(64, 128), 256, 0, stream>>>(x, filt, uw1, ub1, uw2, ub2,
                                          xnew, aold, anew);
  k_final<<<2048, 256, 0, stream>>>(xnew, aold, anew);
}

// Round 3
// 678.069 us; speedup vs baseline: 1.0611x; 1.0611x over previous
//
#include <hip/hip_runtime.h>

#define BN_EPS 1e-3f

// ---------------- threefry2x32 (JAX partitionable path, key=[0,42]) --------
__device__ __forceinline__ unsigned rotl32(unsigned v, int n) {
  return (v << n) | (v >> (32 - n));
}

// jax.random.uniform(key(42), (524288,)) element i, partitionable threefry:
// counter = uint64 iota -> x0 = hi32 = 0, x1 = lo32 = i; out = bits0 ^ bits1.
__device__ __forceinline__ float tf42_uniform(unsigned i) {
  unsigned x0 = 0u, x1 = i;
  const unsigned k0 = 0u, k1 = 42u, k2 = 0u ^ 42u ^ 0x1BD11BDAu;
  x0 += k0; x1 += k1;
#define TFR(r) { x0 += x1; x1 = rotl32(x1, r); x1 ^= x0; }
  TFR(13) TFR(15) TFR(26) TFR(6)
  x0 += k1; x1 += k2 + 1u;
  TFR(17) TFR(29) TFR(16) TFR(24)
  x0 += k2; x1 += k0 + 2u;
  TFR(13) TFR(15) TFR(26) TFR(6)
  x0 += k0; x1 += k1 + 3u;
  TFR(17) TFR(29) TFR(16) TFR(24)
  x0 += k1; x1 += k2 + 4u;
  TFR(13) TFR(15) TFR(26) TFR(6)
  x0 += k2; x1 += k0 + 5u;
#undef TFR
  unsigned bits = x0 ^ x1;
  return __uint_as_float((bits >> 9) | 0x3F800000u) - 1.0f;
}

// ---------------- K1: bn1 + conv1(4->32) + relu + maxpool2 + bn2 -----------
__global__ __launch_bounds__(256) void k_conv1(
    const float* __restrict__ img,
    const float* __restrict__ g1, const float* __restrict__ be1,
    const float* __restrict__ m1, const float* __restrict__ v1,
    const float* __restrict__ w, const float* __restrict__ bias,
    const float* __restrict__ g2, const float* __restrict__ be2,
    const float* __restrict__ m2, const float* __restrict__ v2,
    float* __restrict__ h1) {
  int t = blockIdx.x * 256 + threadIdx.x;  // grid exactly 648*256 = 128*36*36
  int ox = t % 36, oy = (t / 36) % 36, b = t / 1296;
  float s1[4], t1[4];
#pragma unroll
  for (int ci = 0; ci < 4; ++ci) {
    float s = g1[ci] / sqrtf(v1[ci] + BN_EPS);
    s1[ci] = s; t1[ci] = be1[ci] - m1[ci] * s;
  }
  float pacc[32];
#pragma unroll
  for (int co = 0; co < 32; ++co) pacc[co] = 0.f;
#pragma unroll
  for (int sy = 0; sy < 2; ++sy)
#pragma unroll
  for (int sx = 0; sx < 2; ++sx) {
    int iy = 2 * oy + sy, ix = 2 * ox + sx;
    float acc[32];
#pragma unroll
    for (int co = 0; co < 32; ++co) acc[co] = bias[co];
    for (int ky = 0; ky < 3; ++ky) {
      int yy = iy + ky - 1; if (yy < 0 || yy >= 72) continue;
      for (int kx = 0; kx < 3; ++kx) {
        int xx = ix + kx - 1; if (xx < 0 || xx >= 72) continue;
        float4 p = *(const float4*)(img + (((size_t)b * 72 + yy) * 72 + xx) * 4);
        float in0 = p.x * s1[0] + t1[0];
        float in1 = p.y * s1[1] + t1[1];
        float in2 = p.z * s1[2] + t1[2];
        float in3 = p.w * s1[3] + t1[3];
        const float* wp = w + (ky * 3 + kx) * 128;  // (3,3,4,32)
#pragma unroll
        for (int co = 0; co < 32; ++co) acc[co] = fmaf(in0, wp[co], acc[co]);
#pragma unroll
        for (int co = 0; co < 32; ++co) acc[co] = fmaf(in1, wp[32 + co], acc[co]);
#pragma unroll
        for (int co = 0; co < 32; ++co) acc[co] = fmaf(in2, wp[64 + co], acc[co]);
#pragma unroll
        for (int co = 0; co < 32; ++co) acc[co] = fmaf(in3, wp[96 + co], acc[co]);
      }
    }
#pragma unroll
    for (int co = 0; co < 32; ++co)
      pacc[co] = fmaxf(pacc[co], fmaxf(acc[co], 0.f));
  }
#pragma unroll
  for (int co = 0; co < 32; ++co) {
    float s = g2[co] / sqrtf(v2[co] + BN_EPS);
    pacc[co] = pacc[co] * s + (be2[co] - m2[co] * s);
  }
  float* op = h1 + (size_t)t * 32;
#pragma unroll
  for (int c4 = 0; c4 < 8; ++c4) {
    float4 v;
    v.x = pacc[c4 * 4]; v.y = pacc[c4 * 4 + 1];
    v.z = pacc[c4 * 4 + 2]; v.w = pacc[c4 * 4 + 3];
    *(float4*)(op + c4 * 4) = v;
  }
}

// ---------------- K2: conv2(32->32) + relu + maxpool2 ----------------
__global__ __launch_bounds__(256) void k_conv2(
    const float* __restrict__ h1, const float* __restrict__ w,
    const float* __restrict__ bias, float* __restrict__ h2) {
  int t = blockIdx.x * 256 + threadIdx.x;  // grid 162*256 = 128*18*18
  int co0 = blockIdx.y * 8;
  int ox = t % 18, oy = (t / 18) % 18, b = t / 324;
  float pacc[8];
#pragma unroll
  for (int i = 0; i < 8; ++i) pacc[i] = 0.f;
#pragma unroll
  for (int sy = 0; sy < 2; ++sy)
#pragma unroll
  for (int sx = 0; sx < 2; ++sx) {
    int iy = 2 * oy + sy, ix = 2 * ox + sx;
    float acc[8];
#pragma unroll
    for (int i = 0; i < 8; ++i) acc[i] = bias[co0 + i];
    for (int ky = 0; ky < 3; ++ky) {
      int yy = iy + ky - 1; if (yy < 0 || yy >= 36) continue;
      for (int kx = 0; kx < 3; ++kx) {
        int xx = ix + kx - 1; if (xx < 0 || xx >= 36) continue;
        const float* ip = h1 + (((size_t)b * 36 + yy) * 36 + xx) * 32;
        const float* wp = w + (ky * 3 + kx) * 1024 + co0;  // (3,3,32,32)
        float in[32];
#pragma unroll
        for (int c4 = 0; c4 < 8; ++c4) {
          float4 p = *(const float4*)(ip + c4 * 4);
          in[c4 * 4] = p.x; in[c4 * 4 + 1] = p.y;
          in[c4 * 4 + 2] = p.z; in[c4 * 4 + 3] = p.w;
        }
#pragma unroll
        for (int ci = 0; ci < 32; ++ci)
#pragma unroll
          for (int i = 0; i < 8; ++i)
            acc[i] = fmaf(in[ci], wp[ci * 32 + i], acc[i]);
      }
    }
#pragma unroll
    for (int i = 0; i < 8; ++i) pacc[i] = fmaxf(pacc[i], fmaxf(acc[i], 0.f));
  }
  float* op = h2 + (size_t)t * 32 + co0;
  float4 v0, v1;
  v0.x = pacc[0]; v0.y = pacc[1]; v0.z = pacc[2]; v0.w = pacc[3];
  v1.x = pacc[4]; v1.y = pacc[5]; v1.z = pacc[6]; v1.w = pacc[7];
  *(float4*)op = v0;
  *(float4*)(op + 4) = v1;
}

// ---------------- K3a: dense partial GEMM (K-split) ----------------
#define AST 132
__global__ __launch_bounds__(256) void k_dense_part(
    const float* __restrict__ h2, const float* __restrict__ w,
    float* __restrict__ part) {
  __shared__ float a_lds[32 * AST];
  __shared__ float w_lds[32 * 64];
  int tid = threadIdx.x;
  int n0 = blockIdx.x * 64;   // 14 blocks (last ragged)
  int kc = blockIdx.y;        // 18 K-chunks of 576
  int m0 = (tid >> 4) * 8;
  int nl = (tid & 15) * 4;
  float acc[8][4];
#pragma unroll
  for (int i = 0; i < 8; ++i)
#pragma unroll
    for (int j = 0; j < 4; ++j) acc[i][j] = 0.f;
  for (int kt = 0; kt < 18; ++kt) {
    int kb = kc * 576 + kt * 32;
#pragma unroll
    for (int it = 0; it < 4; ++it) {
      int f = tid + it * 256;  // 0..1023 : 128 m rows x 8 float4
      int ml = f >> 3, kq = f & 7;
      float4 p = *(const float4*)(h2 + (size_t)ml * 10368 + kb + kq * 4);
      a_lds[(kq * 4 + 0) * AST + ml] = p.x;
      a_lds[(kq * 4 + 1) * AST + ml] = p.y;
      a_lds[(kq * 4 + 2) * AST + ml] = p.z;
      a_lds[(kq * 4 + 3) * AST + ml] = p.w;
    }
#pragma unroll
    for (int it = 0; it < 2; ++it) {
      int f = tid + it * 256;  // 0..511 : 32 k rows x 16 float4
      int kr = f >> 4, n4 = (f & 15) * 4;
      float4 p;
      if (n0 + n4 < 864)
        p = *(const float4*)(w + (size_t)(kb + kr) * 864 + n0 + n4);
      else { p.x = 0.f; p.y = 0.f; p.z = 0.f; p.w = 0.f; }
      *(float4*)(w_lds + kr * 64 + n4) = p;
    }
    __syncthreads();
#pragma unroll 4
    for (int k = 0; k < 32; ++k) {
      float4 wv = *(const float4*)(w_lds + k * 64 + nl);
      float4 a0 = *(const float4*)(a_lds + k * AST + m0);
      float4 a1 = *(const float4*)(a_lds + k * AST + m0 + 4);
      float am[8] = {a0.x, a0.y, a0.z, a0.w, a1.x, a1.y, a1.z, a1.w};
#pragma unroll
      for (int i = 0; i < 8; ++i) {
        acc[i][0] = fmaf(am[i], wv.x, acc[i][0]);
        acc[i][1] = fmaf(am[i], wv.y, acc[i][1]);
        acc[i][2] = fmaf(am[i], wv.z, acc[i][2]);
        acc[i][3] = fmaf(am[i], wv.w, acc[i][3]);
      }
    }
    __syncthreads();
  }
  if (n0 + nl < 864) {
#pragma unroll
    for (int i = 0; i < 8; ++i) {
      float4 v;
      v.x = acc[i][0]; v.y = acc[i][1]; v.z = acc[i][2]; v.w = acc[i][3];
      *(float4*)(part + ((size_t)kc * 128 + m0 + i) * 864 + n0 + nl) = v;
    }
  }
}

// ---------------- K3b: reduce K-split partials + bias + relu ----------------
__global__ __launch_bounds__(256) void k_dense_fin(
    const float* __restrict__ part, const float* __restrict__ bias,
    float* __restrict__ filt) {
  int e = blockIdx.x * 256 + threadIdx.x;  // grid 432*256 = 128*864
  float s = bias[e % 864];
#pragma unroll
  for (int kc = 0; kc < 18; ++kc) s += part[(size_t)kc * 110592 + e];
  filt[e] = fmaxf(s, 0.f);
}

// ---------------- K4: fused CA update ----------------
// LDS layout change vs R2: halo patch row stride 12 (banks: {12r mod 32} =
// all 8 multiples of 4 -> 64 lanes hit each bank exactly 2x = conflict-free),
// and the cross-wave dx buffer is UNION'd into the (dead-after-read) ia space
// -> 39.9 KB LDS -> 4 blocks/CU.
#define IA_RS 12
#define IA_CS 120  // 10 rows * 12
__global__ __launch_bounds__(256) void k_ca(
    const float* __restrict__ x, const float* __restrict__ filt,
    const float* __restrict__ W1, const float* __restrict__ B1,
    const float* __restrict__ W2, const float* __restrict__ B2,
    float* __restrict__ xnew, float* __restrict__ aold,
    float* __restrict__ anew) {
  __shared__ float fl[864];           // filters for this batch: [12][72]
  __shared__ float ia[76 * IA_CS];    // halo tile; reused as red[4][64][16]
  float* red = ia;
  int tid = threadIdx.x;
  int b = blockIdx.y;
  int tx = (blockIdx.x & 7) * 8, ty = (blockIdx.x >> 3) * 8;

  for (int f = tid; f < 864; f += 256) fl[f] = filt[(size_t)b * 864 + f];
  __syncthreads();

  // phase B: img_aware (board 0..3, img_conv 4..75) over 10x10 halo
  if (tid < 200) {
    int pxh = tid >> 1, half = tid & 1;
    int hy = pxh / 10, hx = pxh % 10;
    int pp = hy * IA_RS + hx;
    int gy = ty + hy - 1, gx = tx + hx - 1;
    bool ok = (gy >= 0 && gy < 64 && gx >= 0 && gx < 64);
    int o0 = half ? 34 : 0, o1 = half ? 72 : 34;
    if (!ok) {
      if (half == 0) {
        ia[0 * IA_CS + pp] = 0.f; ia[1 * IA_CS + pp] = 0.f;
        ia[2 * IA_CS + pp] = 0.f; ia[3 * IA_CS + pp] = 0.f;
      }
      for (int o = o0; o < o1; ++o) ia[(4 + o) * IA_CS + pp] = 0.f;
    } else {
      const float* xp = x + (((size_t)b * 64 + gy) * 64 + gx) * 16;
      float4 hA = *(const float4*)(xp + 4);
      float4 hB = *(const float4*)(xp + 8);
      float4 hC = *(const float4*)(xp + 12);
      float hid[12] = {hA.x, hA.y, hA.z, hA.w, hB.x, hB.y, hB.z, hB.w,
                       hC.x, hC.y, hC.z, hC.w};
      if (half == 0) {
        float4 bd = *(const float4*)xp;
        ia[0 * IA_CS + pp] = bd.x; ia[1 * IA_CS + pp] = bd.y;
        ia[2 * IA_CS + pp] = bd.z; ia[3 * IA_CS + pp] = bd.w;
      }
      for (int o = o0; o < o1; ++o) {
        float acc = 0.f;
#pragma unroll
        for (int c = 0; c < 12; ++c) acc = fmaf(hid[c], fl[c * 72 + o], acc);
        ia[(4 + o) * IA_CS + pp] = acc;
      }
    }
  }
  __syncthreads();

  // phase C: perception + u = relu(P@W1+b1); wave w owns d in [32w,32w+32)
  int wv = __builtin_amdgcn_readfirstlane((int)tid >> 6);
  int lane = tid & 63;
  int ly = lane >> 3, lx = lane & 7;
  int hp = (ly + 1) * IA_RS + (lx + 1);
  int d0 = wv * 32;
  float u[32];
#pragma unroll
  for (int i = 0; i < 32; ++i) u[i] = B1[d0 + i];
  for (int c = 0; c < 76; ++c) {
    const float* pc = ia + c * IA_CS + hp;
    float n00 = pc[-IA_RS - 1], n01 = pc[-IA_RS], n02 = pc[-IA_RS + 1];
    float n10 = pc[-1],          n11 = pc[0],      n12 = pc[1];
    float n20 = pc[IA_RS - 1],   n21 = pc[IA_RS],  n22 = pc[IA_RS + 1];
    float pid = n11;
    float psx = ((n02 - n00) + 2.f * (n12 - n10) + (n22 - n20)) * 0.125f;
    float psy = ((n20 - n00) + 2.f * (n21 - n01) + (n22 - n02)) * 0.125f;
    const float* wr = W1 + (size_t)(3 * c) * 128 + d0;
#pragma unroll
    for (int i = 0; i < 32; ++i) u[i] = fmaf(pid, wr[i], u[i]);
#pragma unroll
    for (int i = 0; i < 32; ++i) u[i] = fmaf(psx, wr[128 + i], u[i]);
#pragma unroll
    for (int i = 0; i < 32; ++i) u[i] = fmaf(psy, wr[256 + i], u[i]);
  }
#pragma unroll
  for (int i = 0; i < 32; ++i) u[i] = fmaxf(u[i], 0.f);
  float dxp[16];
#pragma unroll
  for (int e = 0; e < 16; ++e) dxp[e] = 0.f;
#pragma unroll
  for (int i = 0; i < 32; ++i) {
    const float* w2r = W2 + (size_t)(d0 + i) * 16;
#pragma unroll
    for (int e = 0; e < 16; ++e) dxp[e] = fmaf(u[i], w2r[e], dxp[e]);
  }
  __syncthreads();  // all ia reads done before red overwrites the same LDS
#pragma unroll
  for (int e = 0; e < 16; ++e) red[(wv * 64 + lane) * 16 + e] = dxp[e];
  __syncthreads();

  // phase D: reduce, fire mask, write x_new + alphas
  int px = tid >> 2, q = tid & 3;
  int ply = px >> 3, plx = px & 7;
  int gy = ty + ply, gx = tx + plx;
  size_t base = (((size_t)b * 64 + gy) * 64 + gx) * 16;
  unsigned pix = (unsigned)(b * 4096 + gy * 64 + gx);
  float msk = (tf42_uniform(pix) <= 0.5f) ? 1.f : 0.f;
  int e0 = q * 4;
  float4 xo = *(const float4*)(x + base + e0);
  float d0v = red[(0 * 64 + px) * 16 + e0 + 0] + red[(1 * 64 + px) * 16 + e0 + 0] +
              red[(2 * 64 + px) * 16 + e0 + 0] + red[(3 * 64 + px) * 16 + e0 + 0] + B2[e0 + 0];
  float d1v = red[(0 * 64 + px) * 16 + e0 + 1] + red[(1 * 64 + px) * 16 + e0 + 1] +
              red[(2 * 64 + px) * 16 + e0 + 1] + red[(3 * 64 + px) * 16 + e0 + 1] + B2[e0 + 1];
  float d2v = red[(0 * 64 + px) * 16 + e0 + 2] + red[(1 * 64 + px) * 16 + e0 + 2] +
              red[(2 * 64 + px) * 16 + e0 + 2] + red[(3 * 64 + px) * 16 + e0 + 2] + B2[e0 + 2];
  float d3v = red[(0 * 64 + px) * 16 + e0 + 3] + red[(1 * 64 + px) * 16 + e0 + 3] +
              red[(2 * 64 + px) * 16 + e0 + 3] + red[(3 * 64 + px) * 16 + e0 + 3] + B2[e0 + 3];
  float4 xn;
  xn.x = xo.x + d0v * msk;
  xn.y = xo.y + d1v * msk;
  xn.z = xo.z + d2v * msk;
  xn.w = xo.w + d3v * msk;
  *(float4*)(xnew + base + e0) = xn;
  if (q == 0) {
    aold[pix] = xo.w;
    anew[pix] = xn.w;
  }
}

// ---------------- K5: living masks + final multiply (in place on d_out) ----
__global__ __launch_bounds__(256) void k_final(
    float* __restrict__ xnew, const float* __restrict__ aold,
    const float* __restrict__ anew) {
  int t = blockIdx.x * 256 + threadIdx.x;  // grid 2048*256 = 524288
  int gx = t & 63, gy = (t >> 6) & 63, b = t >> 12;
  float mo = -1e30f, mn = -1e30f;
  for (int dy = -1; dy <= 1; ++dy) {
    int yy = gy + dy; if (yy < 0 || yy >= 64) continue;
    for (int dx = -1; dx <= 1; ++dx) {
      int xx = gx + dx; if (xx < 0 || xx >= 64) continue;
      int p = b * 4096 + yy * 64 + xx;
      mo = fmaxf(mo, aold[p]);
      mn = fmaxf(mn, anew[p]);
    }
  }
  float live = (mo > 0.1f && mn > 0.1f) ? 1.f : 0.f;
  size_t base = (size_t)t * 16;
#pragma unroll
  for (int c4 = 0; c4 < 4; ++c4) {
    float4 v = *(const float4*)(xnew + base + c4 * 4);
    v.x *= live; v.y *= live; v.z *= live; v.w *= live;
    *(float4*)(xnew + base + c4 * 4) = v;
  }
}

// ---------------- launch ----------------
extern "C" void kernel_launch(void* const* d_in, const int* in_sizes, int n_in,
                              void* d_out, int out_size, void* d_ws, size_t ws_size,
                              hipStream_t stream) {
  const float* x    = (const float*)d_in[0];
  const float* img  = (const float*)d_in[1];
  const float* g1   = (const float*)d_in[2];
  const float* be1  = (const float*)d_in[3];
  const float* m1   = (const float*)d_in[4];
  const float* v1   = (const float*)d_in[5];
  const float* w1c  = (const float*)d_in[6];
  const float* b1c  = (const float*)d_in[7];
  const float* g2   = (const float*)d_in[8];
  const float* be2  = (const float*)d_in[9];
  const float* m2   = (const float*)d_in[10];
  const float* v2   = (const float*)d_in[11];
  const float* w2c  = (const float*)d_in[12];
  const float* b2c  = (const float*)d_in[13];
  const float* dw   = (const float*)d_in[14];
  const float* db   = (const float*)d_in[15];
  const float* uw1  = (const float*)d_in[16];
  const float* ub1  = (const float*)d_in[17];
  const float* uw2  = (const float*)d_in[18];
  const float* ub2  = (const float*)d_in[19];

  char* ws = (char*)d_ws;
  float* h1   = (float*)(ws);                       // 21,233,664 B
  float* part = h1;                                 // aliased after K2 done
  float* h2   = (float*)(ws + 21233664);            // 5,308,416 B
  float* filt = (float*)(ws + 26542080);            // 442,368 B
  float* aold = (float*)(ws + 26984448);            // 2,097,152 B
  float* anew = (float*)(ws + 29081600);            // 2,097,152 B
  float* xnew = (float*)d_out;                      // (128,64,64,16) f32

  k_conv1<<<648, 256, 0, stream>>>(img, g1, be1, m1, v1, w1c, b1c,
                                   g2, be2, m2, v2, h1);
  k_conv2<<<dim3(162, 4), 256, 0, stream>>>(h1, w2c, b2c, h2);
  k_dense_part<<<dim3(14, 18), 256, 0, stream>>>(h2, dw, part);
  k_dense_fin<<<432, 256, 0, stream>>>(part, db, filt);
  k_ca<<<dim3(64, 128), 256, 0, stream>>>(x, filt, uw1, ub1, uw2, ub2,
                                          xnew, aold, anew);
  k_final<<<2048, 256, 0, stream>>>(xnew, aold, anew);
}

// Round 4
// 568.846 us; speedup vs baseline: 1.2649x; 1.1920x over previous
//
#include <hip/hip_runtime.h>

#define BN_EPS 1e-3f

typedef unsigned short ushort_t;
typedef __attribute__((ext_vector_type(8))) short bf16x8;
typedef __attribute__((ext_vector_type(4))) float f32x4;

// ---------------- bf16 split helpers ----------------
__device__ __forceinline__ unsigned short f2bf_rne(float f) {
  unsigned u = __float_as_uint(f);
  unsigned r = u + 0x7fffu + ((u >> 16) & 1u);
  return (unsigned short)(r >> 16);
}
__device__ __forceinline__ float bf2f(unsigned short h) {
  return __uint_as_float(((unsigned)h) << 16);
}

// ---------------- threefry2x32 (JAX partitionable path, key=[0,42]) --------
__device__ __forceinline__ unsigned rotl32(unsigned v, int n) {
  return (v << n) | (v >> (32 - n));
}

__device__ __forceinline__ float tf42_uniform(unsigned i) {
  unsigned x0 = 0u, x1 = i;
  const unsigned k0 = 0u, k1 = 42u, k2 = 0u ^ 42u ^ 0x1BD11BDAu;
  x0 += k0; x1 += k1;
#define TFR(r) { x0 += x1; x1 = rotl32(x1, r); x1 ^= x0; }
  TFR(13) TFR(15) TFR(26) TFR(6)
  x0 += k1; x1 += k2 + 1u;
  TFR(17) TFR(29) TFR(16) TFR(24)
  x0 += k2; x1 += k0 + 2u;
  TFR(13) TFR(15) TFR(26) TFR(6)
  x0 += k0; x1 += k1 + 3u;
  TFR(17) TFR(29) TFR(16) TFR(24)
  x0 += k1; x1 += k2 + 4u;
  TFR(13) TFR(15) TFR(26) TFR(6)
  x0 += k2; x1 += k0 + 5u;
#undef TFR
  unsigned bits = x0 ^ x1;
  return __uint_as_float((bits >> 9) | 0x3F800000u) - 1.0f;
}

// ---------------- K1: bn1 + conv1(4->32) + relu + maxpool2 + bn2 -----------
__global__ __launch_bounds__(256) void k_conv1(
    const float* __restrict__ img,
    const float* __restrict__ g1, const float* __restrict__ be1,
    const float* __restrict__ m1, const float* __restrict__ v1,
    const float* __restrict__ w, const float* __restrict__ bias,
    const float* __restrict__ g2, const float* __restrict__ be2,
    const float* __restrict__ m2, const float* __restrict__ v2,
    float* __restrict__ h1) {
  int t = blockIdx.x * 256 + threadIdx.x;  // grid exactly 648*256 = 128*36*36
  int ox = t % 36, oy = (t / 36) % 36, b = t / 1296;
  float s1[4], t1[4];
#pragma unroll
  for (int ci = 0; ci < 4; ++ci) {
    float s = g1[ci] / sqrtf(v1[ci] + BN_EPS);
    s1[ci] = s; t1[ci] = be1[ci] - m1[ci] * s;
  }
  float pacc[32];
#pragma unroll
  for (int co = 0; co < 32; ++co) pacc[co] = 0.f;
#pragma unroll
  for (int sy = 0; sy < 2; ++sy)
#pragma unroll
  for (int sx = 0; sx < 2; ++sx) {
    int iy = 2 * oy + sy, ix = 2 * ox + sx;
    float acc[32];
#pragma unroll
    for (int co = 0; co < 32; ++co) acc[co] = bias[co];
    for (int ky = 0; ky < 3; ++ky) {
      int yy = iy + ky - 1; if (yy < 0 || yy >= 72) continue;
      for (int kx = 0; kx < 3; ++kx) {
        int xx = ix + kx - 1; if (xx < 0 || xx >= 72) continue;
        float4 p = *(const float4*)(img + (((size_t)b * 72 + yy) * 72 + xx) * 4);
        float in0 = p.x * s1[0] + t1[0];
        float in1 = p.y * s1[1] + t1[1];
        float in2 = p.z * s1[2] + t1[2];
        float in3 = p.w * s1[3] + t1[3];
        const float* wp = w + (ky * 3 + kx) * 128;  // (3,3,4,32)
#pragma unroll
        for (int co = 0; co < 32; ++co) acc[co] = fmaf(in0, wp[co], acc[co]);
#pragma unroll
        for (int co = 0; co < 32; ++co) acc[co] = fmaf(in1, wp[32 + co], acc[co]);
#pragma unroll
        for (int co = 0; co < 32; ++co) acc[co] = fmaf(in2, wp[64 + co], acc[co]);
#pragma unroll
        for (int co = 0; co < 32; ++co) acc[co] = fmaf(in3, wp[96 + co], acc[co]);
      }
    }
#pragma unroll
    for (int co = 0; co < 32; ++co)
      pacc[co] = fmaxf(pacc[co], fmaxf(acc[co], 0.f));
  }
#pragma unroll
  for (int co = 0; co < 32; ++co) {
    float s = g2[co] / sqrtf(v2[co] + BN_EPS);
    pacc[co] = pacc[co] * s + (be2[co] - m2[co] * s);
  }
  float* op = h1 + (size_t)t * 32;
#pragma unroll
  for (int c4 = 0; c4 < 8; ++c4) {
    float4 v;
    v.x = pacc[c4 * 4]; v.y = pacc[c4 * 4 + 1];
    v.z = pacc[c4 * 4 + 2]; v.w = pacc[c4 * 4 + 3];
    *(float4*)(op + c4 * 4) = v;
  }
}

// ---------------- K2: conv2(32->32) + relu + maxpool2 ----------------
__global__ __launch_bounds__(256) void k_conv2(
    const float* __restrict__ h1, const float* __restrict__ w,
    const float* __restrict__ bias, float* __restrict__ h2) {
  int t = blockIdx.x * 256 + threadIdx.x;  // grid 162*256 = 128*18*18
  int co0 = blockIdx.y * 8;
  int ox = t % 18, oy = (t / 18) % 18, b = t / 324;
  float pacc[8];
#pragma unroll
  for (int i = 0; i < 8; ++i) pacc[i] = 0.f;
#pragma unroll
  for (int sy = 0; sy < 2; ++sy)
#pragma unroll
  for (int sx = 0; sx < 2; ++sx) {
    int iy = 2 * oy + sy, ix = 2 * ox + sx;
    float acc[8];
#pragma unroll
    for (int i = 0; i < 8; ++i) acc[i] = bias[co0 + i];
    for (int ky = 0; ky < 3; ++ky) {
      int yy = iy + ky - 1; if (yy < 0 || yy >= 36) continue;
      for (int kx = 0; kx < 3; ++kx) {
        int xx = ix + kx - 1; if (xx < 0 || xx >= 36) continue;
        const float* ip = h1 + (((size_t)b * 36 + yy) * 36 + xx) * 32;
        const float* wp = w + (ky * 3 + kx) * 1024 + co0;  // (3,3,32,32)
        float in[32];
#pragma unroll
        for (int c4 = 0; c4 < 8; ++c4) {
          float4 p = *(const float4*)(ip + c4 * 4);
          in[c4 * 4] = p.x; in[c4 * 4 + 1] = p.y;
          in[c4 * 4 + 2] = p.z; in[c4 * 4 + 3] = p.w;
        }
#pragma unroll
        for (int ci = 0; ci < 32; ++ci)
#pragma unroll
          for (int i = 0; i < 8; ++i)
            acc[i] = fmaf(in[ci], wp[ci * 32 + i], acc[i]);
      }
    }
#pragma unroll
    for (int i = 0; i < 8; ++i) pacc[i] = fmaxf(pacc[i], fmaxf(acc[i], 0.f));
  }
  float* op = h2 + (size_t)t * 32 + co0;
  float4 v0, v1;
  v0.x = pacc[0]; v0.y = pacc[1]; v0.z = pacc[2]; v0.w = pacc[3];
  v1.x = pacc[4]; v1.y = pacc[5]; v1.z = pacc[6]; v1.w = pacc[7];
  *(float4*)op = v0;
  *(float4*)(op + 4) = v1;
}

// ---------------- K3a: dense partial GEMM (K-split) ----------------
#define AST 132
__global__ __launch_bounds__(256) void k_dense_part(
    const float* __restrict__ h2, const float* __restrict__ w,
    float* __restrict__ part) {
  __shared__ float a_lds[32 * AST];
  __shared__ float w_lds[32 * 64];
  int tid = threadIdx.x;
  int n0 = blockIdx.x * 64;   // 14 blocks (last ragged)
  int kc = blockIdx.y;        // 18 K-chunks of 576
  int m0 = (tid >> 4) * 8;
  int nl = (tid & 15) * 4;
  float acc[8][4];
#pragma unroll
  for (int i = 0; i < 8; ++i)
#pragma unroll
    for (int j = 0; j < 4; ++j) acc[i][j] = 0.f;
  for (int kt = 0; kt < 18; ++kt) {
    int kb = kc * 576 + kt * 32;
#pragma unroll
    for (int it = 0; it < 4; ++it) {
      int f = tid + it * 256;  // 0..1023 : 128 m rows x 8 float4
      int ml = f >> 3, kq = f & 7;
      float4 p = *(const float4*)(h2 + (size_t)ml * 10368 + kb + kq * 4);
      a_lds[(kq * 4 + 0) * AST + ml] = p.x;
      a_lds[(kq * 4 + 1) * AST + ml] = p.y;
      a_lds[(kq * 4 + 2) * AST + ml] = p.z;
      a_lds[(kq * 4 + 3) * AST + ml] = p.w;
    }
#pragma unroll
    for (int it = 0; it < 2; ++it) {
      int f = tid + it * 256;  // 0..511 : 32 k rows x 16 float4
      int kr = f >> 4, n4 = (f & 15) * 4;
      float4 p;
      if (n0 + n4 < 864)
        p = *(const float4*)(w + (size_t)(kb + kr) * 864 + n0 + n4);
      else { p.x = 0.f; p.y = 0.f; p.z = 0.f; p.w = 0.f; }
      *(float4*)(w_lds + kr * 64 + n4) = p;
    }
    __syncthreads();
#pragma unroll 4
    for (int k = 0; k < 32; ++k) {
      float4 wv = *(const float4*)(w_lds + k * 64 + nl);
      float4 a0 = *(const float4*)(a_lds + k * AST + m0);
      float4 a1 = *(const float4*)(a_lds + k * AST + m0 + 4);
      float am[8] = {a0.x, a0.y, a0.z, a0.w, a1.x, a1.y, a1.z, a1.w};
#pragma unroll
      for (int i = 0; i < 8; ++i) {
        acc[i][0] = fmaf(am[i], wv.x, acc[i][0]);
        acc[i][1] = fmaf(am[i], wv.y, acc[i][1]);
        acc[i][2] = fmaf(am[i], wv.z, acc[i][2]);
        acc[i][3] = fmaf(am[i], wv.w, acc[i][3]);
      }
    }
    __syncthreads();
  }
  if (n0 + nl < 864) {
#pragma unroll
    for (int i = 0; i < 8; ++i) {
      float4 v;
      v.x = acc[i][0]; v.y = acc[i][1]; v.z = acc[i][2]; v.w = acc[i][3];
      *(float4*)(part + ((size_t)kc * 128 + m0 + i) * 864 + n0 + nl) = v;
    }
  }
}

// ---------------- K3b: reduce K-split partials + bias + relu ----------------
__global__ __launch_bounds__(256) void k_dense_fin(
    const float* __restrict__ part, const float* __restrict__ bias,
    float* __restrict__ filt) {
  int e = blockIdx.x * 256 + threadIdx.x;  // grid 432*256 = 128*864
  float s = bias[e % 864];
#pragma unroll
  for (int kc = 0; kc < 18; ++kc) s += part[(size_t)kc * 110592 + e];
  filt[e] = fmaxf(s, 0.f);
}

// ---------------- K_prep: swizzle W1 (228x128) into bf16 hi/lo B-frags -----
// layout: [ntile(8)][kstep(8)][lane(64)][8], element = W1[k][col],
// k = 32*s + (lane>>4)*8 + j (0 beyond 227), col = 16*nt + (lane&15).
__global__ __launch_bounds__(256) void k_prep(
    const float* __restrict__ W1, unsigned short* __restrict__ Wh,
    unsigned short* __restrict__ Wl) {
  int t = blockIdx.x * 256 + threadIdx.x;  // 128 blocks -> 32768
  int j = t & 7, l = (t >> 3) & 63, s = (t >> 9) & 7, nt = t >> 12;
  int k = 32 * s + (l >> 4) * 8 + j;
  int col = 16 * nt + (l & 15);
  float v = (k < 228) ? W1[k * 128 + col] : 0.f;
  unsigned short h = f2bf_rne(v);
  Wh[t] = h;
  Wl[t] = f2bf_rne(v - bf2f(h));
}

// ---------------- K4: fused CA update (MFMA, split-bf16 3-pass) ------------
// Per (b, 8x8 tile): K=228 perception features, chunked 32 channels (96 k).
// Per chunk: build ia halo (32 ch) -> perception P -> PA (bf16 hi/lo in LDS)
// -> 16x16x32 MFMA (A=P, B=W1 frags preloaded from pre-swizzled global).
// acc = Phi*Whi + Phi*Wlo + Plo*Whi (f32 acc) ~ f32 accuracy.
// u exchanged via LDS [hidden][pixel] stride 65; W2 tail f32 as before.
__global__ __launch_bounds__(256, 3) void k_ca(
    const float* __restrict__ x, const float* __restrict__ filt,
    const unsigned short* __restrict__ W1Bh, const unsigned short* __restrict__ W1Bl,
    const float* __restrict__ B1,
    const float* __restrict__ W2, const float* __restrict__ B2,
    float* __restrict__ xnew, float* __restrict__ aold,
    float* __restrict__ anew) {
  // LDS map (dwords): fl 0..864 | hid 864..2064 | ia 2064..5904 (32x120)
  // PAh 5904..9232 (64x104 ushort), PAl 9232..12560
  // union after MFMA: u = 2064..10384 (128x65 f32); red_w = u + wv*2080
  __shared__ __align__(16) float S[12560];
  float* fl = S;
  float* hid = S + 864;
  float* ia = S + 2064;
  unsigned short* PAh = (unsigned short*)(S + 5904);
  unsigned short* PAl = (unsigned short*)(S + 9232);
  float* uB = S + 2064;

  int tid = threadIdx.x;
  int b = blockIdx.y;
  int tx = (blockIdx.x & 7) * 8, ty = (blockIdx.x >> 3) * 8;
  int wv = tid >> 6, lane = tid & 63;
  int lr = lane & 15, lhi = lane >> 4;

  for (int f = tid; f < 864; f += 256) fl[f] = filt[(size_t)b * 864 + f];

  // phase A: halo loads -> hid[100][12], board -> ia[0..3]
  if (tid < 100) {
    int hy = tid / 10, hx = tid - hy * 10;
    int pp = hy * 12 + hx;
    int gy = ty + hy - 1, gx = tx + hx - 1;
    if (gy >= 0 && gy < 64 && gx >= 0 && gx < 64) {
      const float* xp = x + (((size_t)b * 64 + gy) * 64 + gx) * 16;
      float4 bd = *(const float4*)xp;
      float4 hA = *(const float4*)(xp + 4);
      float4 hB = *(const float4*)(xp + 8);
      float4 hC = *(const float4*)(xp + 12);
      ia[0 * 120 + pp] = bd.x; ia[1 * 120 + pp] = bd.y;
      ia[2 * 120 + pp] = bd.z; ia[3 * 120 + pp] = bd.w;
      float* hp_ = hid + tid * 12;
      hp_[0] = hA.x; hp_[1] = hA.y; hp_[2] = hA.z; hp_[3] = hA.w;
      hp_[4] = hB.x; hp_[5] = hB.y; hp_[6] = hB.z; hp_[7] = hB.w;
      hp_[8] = hC.x; hp_[9] = hC.y; hp_[10] = hC.z; hp_[11] = hC.w;
    } else {
      ia[0 * 120 + pp] = 0.f; ia[1 * 120 + pp] = 0.f;
      ia[2 * 120 + pp] = 0.f; ia[3 * 120 + pp] = 0.f;
      float* hp_ = hid + tid * 12;
#pragma unroll
      for (int h = 0; h < 12; ++h) hp_[h] = 0.f;
    }
  }
  __syncthreads();

  f32x4 acc[4][2];
#pragma unroll
  for (int m = 0; m < 4; ++m)
#pragma unroll
    for (int nt = 0; nt < 2; ++nt)
      acc[m][nt] = (f32x4){0.f, 0.f, 0.f, 0.f};

  for (int chunk = 0; chunk < 3; ++chunk) {
    // ---- phase B: img_conv channels for this chunk into ia
    int nch = (chunk == 0) ? 28 : ((chunk == 1) ? 32 : 12);
    int o0 = (chunk == 0) ? 0 : ((chunk == 1) ? 28 : 60);
    int cc0 = (chunk == 0) ? 4 : 0;
    for (int idx = tid; idx < 100 * nch; idx += 256) {
      int j = idx / 100, px = idx - j * 100;
      int o = o0 + j;
      const float* hp_ = hid + px * 12;
      float a = 0.f;
#pragma unroll
      for (int h = 0; h < 12; ++h) a = fmaf(hp_[h], fl[h * 72 + o], a);
      int hy = px / 10, hx = px - hy * 10;
      ia[(cc0 + j) * 120 + hy * 12 + hx] = a;
    }
    if (chunk == 2) {  // zero PA pad region k_loc 36..63 (matches W1 zeros)
#pragma unroll
      for (int z = 0; z < 7; ++z) {
        int kk = 36 + wv * 7 + z;
        PAh[lane * 104 + kk] = 0;
        PAl[lane * 104 + kk] = 0;
      }
    }
    __syncthreads();

    // ---- phase P: perception -> PA (+ prefetch B-frags for this chunk)
    int nks = (chunk < 2) ? 3 : 2;
    bf16x8 bh[2][3], bl[2][3];
#pragma unroll
    for (int nt = 0; nt < 2; ++nt)
#pragma unroll
      for (int ks = 0; ks < 3; ++ks)
        if (ks < nks) {
          int s = chunk * 3 + ks;
          int base = (((wv * 2 + nt) * 8 + s) * 64 + lane) * 8;
          bh[nt][ks] = *(const bf16x8*)(W1Bh + base);
          bl[nt][ks] = *(const bf16x8*)(W1Bl + base);
        }
    {
      int py = lane >> 3, pxx = lane & 7;
      int hp0 = (py + 1) * 12 + (pxx + 1);
      int npc = (chunk < 2) ? 8 : 3;
      for (int ii = 0; ii < npc; ++ii) {
        int cc = wv * npc + ii;
        const float* pc = ia + cc * 120 + hp0;
        float n00 = pc[-13], n01 = pc[-12], n02 = pc[-11];
        float n10 = pc[-1], n11 = pc[0], n12 = pc[1];
        float n20 = pc[11], n21 = pc[12], n22 = pc[13];
        float pid = n11;
        float psx = ((n02 - n00) + 2.f * (n12 - n10) + (n22 - n20)) * 0.125f;
        float psy = ((n20 - n00) + 2.f * (n21 - n01) + (n22 - n02)) * 0.125f;
        unsigned short h0 = f2bf_rne(pid), h1 = f2bf_rne(psx), h2 = f2bf_rne(psy);
        unsigned short l0 = f2bf_rne(pid - bf2f(h0));
        unsigned short l1 = f2bf_rne(psx - bf2f(h1));
        unsigned short l2 = f2bf_rne(psy - bf2f(h2));
        int kk = lane * 104 + 3 * cc;
        PAh[kk + 0] = h0; PAh[kk + 1] = h1; PAh[kk + 2] = h2;
        PAl[kk + 0] = l0; PAl[kk + 1] = l1; PAl[kk + 2] = l2;
      }
    }
    __syncthreads();

    // ---- phase M: MFMA over this chunk's ksteps
#pragma unroll
    for (int ks = 0; ks < 3; ++ks) {
      if (ks < nks) {
#pragma unroll
        for (int m = 0; m < 4; ++m) {
          int arow = m * 16 + lr;
          bf16x8 ah = *(const bf16x8*)(PAh + arow * 104 + ks * 32 + lhi * 8);
          bf16x8 al = *(const bf16x8*)(PAl + arow * 104 + ks * 32 + lhi * 8);
#pragma unroll
          for (int nt = 0; nt < 2; ++nt) {
            acc[m][nt] = __builtin_amdgcn_mfma_f32_16x16x32_bf16(
                ah, bh[nt][ks], acc[m][nt], 0, 0, 0);
            acc[m][nt] = __builtin_amdgcn_mfma_f32_16x16x32_bf16(
                ah, bl[nt][ks], acc[m][nt], 0, 0, 0);
            acc[m][nt] = __builtin_amdgcn_mfma_f32_16x16x32_bf16(
                al, bh[nt][ks], acc[m][nt], 0, 0, 0);
          }
        }
      }
    }
    __syncthreads();  // PA consumed before next chunk's P (or tail's u) writes
  }

  // ---- tail: u = relu(acc + B1) -> LDS [hidden][pixel] (stride 65)
  int d0 = wv * 32;
  float b1v0 = B1[d0 + lr], b1v1 = B1[d0 + 16 + lr];
#pragma unroll
  for (int m = 0; m < 4; ++m)
#pragma unroll
    for (int nt = 0; nt < 2; ++nt) {
      int hrow = d0 + nt * 16 + lr;
      float bv = nt ? b1v1 : b1v0;
#pragma unroll
      for (int r = 0; r < 4; ++r) {
        int pxw = m * 16 + lhi * 4 + r;
        uB[hrow * 65 + pxw] = fmaxf(acc[m][nt][r] + bv, 0.f);
      }
    }
  // same wave reads back its own rows (within-wave LDS ordering)
  float uu[32];
#pragma unroll
  for (int i = 0; i < 32; ++i) uu[i] = uB[(d0 + i) * 65 + lane];
  float dxp[16];
#pragma unroll
  for (int e = 0; e < 16; ++e) dxp[e] = 0.f;
#pragma unroll
  for (int i = 0; i < 32; ++i) {
    const float* w2r = W2 + (size_t)(d0 + i) * 16;
#pragma unroll
    for (int e = 0; e < 16; ++e) dxp[e] = fmaf(uu[i], w2r[e], dxp[e]);
  }
  // red partials into this wave's own (consumed) u rows: base uB + wv*2080
  {
    float* red = uB + wv * 2080;
#pragma unroll
    for (int e = 0; e < 16; ++e) red[lane * 17 + e] = dxp[e];
  }
  __syncthreads();

  // ---- phase D: reduce 4 waves, fire mask, write x_new + alphas
  int px = tid >> 2, q = tid & 3;
  int ply = px >> 3, plx = px & 7;
  int gy = ty + ply, gx = tx + plx;
  size_t base = (((size_t)b * 64 + gy) * 64 + gx) * 16;
  unsigned pix = (unsigned)(b * 4096 + gy * 64 + gx);
  float msk = (tf42_uniform(pix) <= 0.5f) ? 1.f : 0.f;
  int e0 = q * 4;
  float4 xo = *(const float4*)(x + base + e0);
  float dv[4];
#pragma unroll
  for (int jj = 0; jj < 4; ++jj) {
    dv[jj] = uB[0 * 2080 + px * 17 + e0 + jj] + uB[1 * 2080 + px * 17 + e0 + jj] +
             uB[2 * 2080 + px * 17 + e0 + jj] + uB[3 * 2080 + px * 17 + e0 + jj] +
             B2[e0 + jj];
  }
  float4 xn;
  xn.x = xo.x + dv[0] * msk;
  xn.y = xo.y + dv[1] * msk;
  xn.z = xo.z + dv[2] * msk;
  xn.w = xo.w + dv[3] * msk;
  *(float4*)(xnew + base + e0) = xn;
  if (q == 0) {
    aold[pix] = xo.w;
    anew[pix] = xn.w;
  }
}

// ---------------- K5: living masks + final multiply (in place on d_out) ----
__global__ __launch_bounds__(256) void k_final(
    float* __restrict__ xnew, const float* __restrict__ aold,
    const float* __restrict__ anew) {
  int t = blockIdx.x * 256 + threadIdx.x;  // grid 2048*256 = 524288
  int gx = t & 63, gy = (t >> 6) & 63, b = t >> 12;
  float mo = -1e30f, mn = -1e30f;
  for (int dy = -1; dy <= 1; ++dy) {
    int yy = gy + dy; if (yy < 0 || yy >= 64) continue;
    for (int dx = -1; dx <= 1; ++dx) {
      int xx = gx + dx; if (xx < 0 || xx >= 64) continue;
      int p = b * 4096 + yy * 64 + xx;
      mo = fmaxf(mo, aold[p]);
      mn = fmaxf(mn, anew[p]);
    }
  }
  float live = (mo > 0.1f && mn > 0.1f) ? 1.f : 0.f;
  size_t base = (size_t)t * 16;
#pragma unroll
  for (int c4 = 0; c4 < 4; ++c4) {
    float4 v = *(const float4*)(xnew + base + c4 * 4);
    v.x *= live; v.y *= live; v.z *= live; v.w *= live;
    *(float4*)(xnew + base + c4 * 4) = v;
  }
}

// ---------------- launch ----------------
extern "C" void kernel_launch(void* const* d_in, const int* in_sizes, int n_in,
                              void* d_out, int out_size, void* d_ws, size_t ws_size,
                              hipStream_t stream) {
  const float* x    = (const float*)d_in[0];
  const float* img  = (const float*)d_in[1];
  const float* g1   = (const float*)d_in[2];
  const float* be1  = (const float*)d_in[3];
  const float* m1   = (const float*)d_in[4];
  const float* v1   = (const float*)d_in[5];
  const float* w1c  = (const float*)d_in[6];
  const float* b1c  = (const float*)d_in[7];
  const float* g2   = (const float*)d_in[8];
  const float* be2  = (const float*)d_in[9];
  const float* m2   = (const float*)d_in[10];
  const float* v2   = (const float*)d_in[11];
  const float* w2c  = (const float*)d_in[12];
  const float* b2c  = (const float*)d_in[13];
  const float* dw   = (const float*)d_in[14];
  const float* db   = (const float*)d_in[15];
  const float* uw1  = (const float*)d_in[16];
  const float* ub1  = (const float*)d_in[17];
  const float* uw2  = (const float*)d_in[18];
  const float* ub2  = (const float*)d_in[19];

  char* ws = (char*)d_ws;
  float* h1   = (float*)(ws);                        // 21,233,664 B
  float* part = h1;                                  // aliased after K2 done
  float* h2   = (float*)(ws + 21233664);             // 5,308,416 B
  float* filt = (float*)(ws + 26542080);             // 442,368 B
  float* aold = (float*)(ws + 26984448);             // 2,097,152 B
  float* anew = (float*)(ws + 29081600);             // 2,097,152 B
  unsigned short* W1Bh = (unsigned short*)(ws + 31178752);  // 65,536 B
  unsigned short* W1Bl = (unsigned short*)(ws + 31244288);  // 65,536 B
  // total 31,309,824 B
  float* xnew = (float*)d_out;                       // (128,64,64,16) f32

  k_prep<<<128, 256, 0, stream>>>(uw1, W1Bh, W1Bl);
  k_conv1<<<648, 256, 0, stream>>>(img, g1, be1, m1, v1, w1c, b1c,
                                   g2, be2, m2, v2, h1);
  k_conv2<<<dim3(162, 4), 256, 0, stream>>>(h1, w2c, b2c, h2);
  k_dense_part<<<dim3(14, 18), 256, 0, stream>>>(h2, dw, part);
  k_dense_fin<<<432, 256, 0, stream>>>(part, db, filt);
  k_ca<<<dim3(64, 128), 256, 0, stream>>>(x, filt, W1Bh, W1Bl, ub1, uw2, ub2,
                                          xnew, aold, anew);
  k_final<<<2048, 256, 0, stream>>>(xnew, aold, anew);
}

// Round 6
// 551.734 us; speedup vs baseline: 1.3041x; 1.0310x over previous
//
#include <hip/hip_runtime.h>

#define BN_EPS 1e-3f

typedef __attribute__((ext_vector_type(8))) short bf16x8;
typedef __attribute__((ext_vector_type(4))) float f32x4;

// ---------------- bf16 split helpers ----------------
__device__ __forceinline__ unsigned short f2bf_rne(float f) {
  unsigned u = __float_as_uint(f);
  unsigned r = u + 0x7fffu + ((u >> 16) & 1u);
  return (unsigned short)(r >> 16);
}
__device__ __forceinline__ float bf2f(unsigned short h) {
  return __uint_as_float(((unsigned)h) << 16);
}
__device__ __forceinline__ void split2(float v, unsigned short& h, unsigned short& l) {
  h = f2bf_rne(v);
  l = f2bf_rne(v - bf2f(h));
}

// ---------------- threefry2x32 (JAX partitionable path, key=[0,42]) --------
__device__ __forceinline__ unsigned rotl32(unsigned v, int n) {
  return (v << n) | (v >> (32 - n));
}

__device__ __forceinline__ float tf42_uniform(unsigned i) {
  unsigned x0 = 0u, x1 = i;
  const unsigned k0 = 0u, k1 = 42u, k2 = 0u ^ 42u ^ 0x1BD11BDAu;
  x0 += k0; x1 += k1;
#define TFR(r) { x0 += x1; x1 = rotl32(x1, r); x1 ^= x0; }
  TFR(13) TFR(15) TFR(26) TFR(6)
  x0 += k1; x1 += k2 + 1u;
  TFR(17) TFR(29) TFR(16) TFR(24)
  x0 += k2; x1 += k0 + 2u;
  TFR(13) TFR(15) TFR(26) TFR(6)
  x0 += k0; x1 += k1 + 3u;
  TFR(17) TFR(29) TFR(16) TFR(24)
  x0 += k1; x1 += k2 + 4u;
  TFR(13) TFR(15) TFR(26) TFR(6)
  x0 += k2; x1 += k0 + 5u;
#undef TFR
  unsigned bits = x0 ^ x1;
  return __uint_as_float((bits >> 9) | 0x3F800000u) - 1.0f;
}

// ---------------- K1: bn1 + conv1(4->32) + relu + maxpool2 + bn2 -----------
__global__ __launch_bounds__(256) void k_conv1(
    const float* __restrict__ img,
    const float* __restrict__ g1, const float* __restrict__ be1,
    const float* __restrict__ m1, const float* __restrict__ v1,
    const float* __restrict__ w, const float* __restrict__ bias,
    const float* __restrict__ g2, const float* __restrict__ be2,
    const float* __restrict__ m2, const float* __restrict__ v2,
    float* __restrict__ h1) {
  int t = blockIdx.x * 256 + threadIdx.x;  // grid exactly 648*256 = 128*36*36
  int ox = t % 36, oy = (t / 36) % 36, b = t / 1296;
  float s1[4], t1[4];
#pragma unroll
  for (int ci = 0; ci < 4; ++ci) {
    float s = g1[ci] / sqrtf(v1[ci] + BN_EPS);
    s1[ci] = s; t1[ci] = be1[ci] - m1[ci] * s;
  }
  float pacc[32];
#pragma unroll
  for (int co = 0; co < 32; ++co) pacc[co] = 0.f;
#pragma unroll
  for (int sy = 0; sy < 2; ++sy)
#pragma unroll
  for (int sx = 0; sx < 2; ++sx) {
    int iy = 2 * oy + sy, ix = 2 * ox + sx;
    float acc[32];
#pragma unroll
    for (int co = 0; co < 32; ++co) acc[co] = bias[co];
    for (int ky = 0; ky < 3; ++ky) {
      int yy = iy + ky - 1; if (yy < 0 || yy >= 72) continue;
      for (int kx = 0; kx < 3; ++kx) {
        int xx = ix + kx - 1; if (xx < 0 || xx >= 72) continue;
        float4 p = *(const float4*)(img + (((size_t)b * 72 + yy) * 72 + xx) * 4);
        float in0 = p.x * s1[0] + t1[0];
        float in1 = p.y * s1[1] + t1[1];
        float in2 = p.z * s1[2] + t1[2];
        float in3 = p.w * s1[3] + t1[3];
        const float* wp = w + (ky * 3 + kx) * 128;  // (3,3,4,32)
#pragma unroll
        for (int co = 0; co < 32; ++co) acc[co] = fmaf(in0, wp[co], acc[co]);
#pragma unroll
        for (int co = 0; co < 32; ++co) acc[co] = fmaf(in1, wp[32 + co], acc[co]);
#pragma unroll
        for (int co = 0; co < 32; ++co) acc[co] = fmaf(in2, wp[64 + co], acc[co]);
#pragma unroll
        for (int co = 0; co < 32; ++co) acc[co] = fmaf(in3, wp[96 + co], acc[co]);
      }
    }
#pragma unroll
    for (int co = 0; co < 32; ++co)
      pacc[co] = fmaxf(pacc[co], fmaxf(acc[co], 0.f));
  }
#pragma unroll
  for (int co = 0; co < 32; ++co) {
    float s = g2[co] / sqrtf(v2[co] + BN_EPS);
    pacc[co] = pacc[co] * s + (be2[co] - m2[co] * s);
  }
  float* op = h1 + (size_t)t * 32;
#pragma unroll
  for (int c4 = 0; c4 < 8; ++c4) {
    float4 v;
    v.x = pacc[c4 * 4]; v.y = pacc[c4 * 4 + 1];
    v.z = pacc[c4 * 4 + 2]; v.w = pacc[c4 * 4 + 3];
    *(float4*)(op + c4 * 4) = v;
  }
}

// ---------------- K2: conv2(32->32) + relu + maxpool2 ----------------
__global__ __launch_bounds__(256) void k_conv2(
    const float* __restrict__ h1, const float* __restrict__ w,
    const float* __restrict__ bias, float* __restrict__ h2) {
  int t = blockIdx.x * 256 + threadIdx.x;  // grid 162*256 = 128*18*18
  int co0 = blockIdx.y * 8;
  int ox = t % 18, oy = (t / 18) % 18, b = t / 324;
  float pacc[8];
#pragma unroll
  for (int i = 0; i < 8; ++i) pacc[i] = 0.f;
#pragma unroll
  for (int sy = 0; sy < 2; ++sy)
#pragma unroll
  for (int sx = 0; sx < 2; ++sx) {
    int iy = 2 * oy + sy, ix = 2 * ox + sx;
    float acc[8];
#pragma unroll
    for (int i = 0; i < 8; ++i) acc[i] = bias[co0 + i];
    for (int ky = 0; ky < 3; ++ky) {
      int yy = iy + ky - 1; if (yy < 0 || yy >= 36) continue;
      for (int kx = 0; kx < 3; ++kx) {
        int xx = ix + kx - 1; if (xx < 0 || xx >= 36) continue;
        const float* ip = h1 + (((size_t)b * 36 + yy) * 36 + xx) * 32;
        const float* wp = w + (ky * 3 + kx) * 1024 + co0;  // (3,3,32,32)
        float in[32];
#pragma unroll
        for (int c4 = 0; c4 < 8; ++c4) {
          float4 p = *(const float4*)(ip + c4 * 4);
          in[c4 * 4] = p.x; in[c4 * 4 + 1] = p.y;
          in[c4 * 4 + 2] = p.z; in[c4 * 4 + 3] = p.w;
        }
#pragma unroll
        for (int ci = 0; ci < 32; ++ci)
#pragma unroll
          for (int i = 0; i < 8; ++i)
            acc[i] = fmaf(in[ci], wp[ci * 32 + i], acc[i]);
      }
    }
#pragma unroll
    for (int i = 0; i < 8; ++i) pacc[i] = fmaxf(pacc[i], fmaxf(acc[i], 0.f));
  }
  float* op = h2 + (size_t)t * 32 + co0;
  float4 v0, v1;
  v0.x = pacc[0]; v0.y = pacc[1]; v0.z = pacc[2]; v0.w = pacc[3];
  v1.x = pacc[4]; v1.y = pacc[5]; v1.z = pacc[6]; v1.w = pacc[7];
  *(float4*)op = v0;
  *(float4*)(op + 4) = v1;
}

// ---------------- K3a: dense partial GEMM (K-split) ----------------
#define AST 132
__global__ __launch_bounds__(256) void k_dense_part(
    const float* __restrict__ h2, const float* __restrict__ w,
    float* __restrict__ part) {
  __shared__ float a_lds[32 * AST];
  __shared__ float w_lds[32 * 64];
  int tid = threadIdx.x;
  int n0 = blockIdx.x * 64;   // 14 blocks (last ragged)
  int kc = blockIdx.y;        // 18 K-chunks of 576
  int m0 = (tid >> 4) * 8;
  int nl = (tid & 15) * 4;
  float acc[8][4];
#pragma unroll
  for (int i = 0; i < 8; ++i)
#pragma unroll
    for (int j = 0; j < 4; ++j) acc[i][j] = 0.f;
  for (int kt = 0; kt < 18; ++kt) {
    int kb = kc * 576 + kt * 32;
#pragma unroll
    for (int it = 0; it < 4; ++it) {
      int f = tid + it * 256;  // 0..1023 : 128 m rows x 8 float4
      int ml = f >> 3, kq = f & 7;
      float4 p = *(const float4*)(h2 + (size_t)ml * 10368 + kb + kq * 4);
      a_lds[(kq * 4 + 0) * AST + ml] = p.x;
      a_lds[(kq * 4 + 1) * AST + ml] = p.y;
      a_lds[(kq * 4 + 2) * AST + ml] = p.z;
      a_lds[(kq * 4 + 3) * AST + ml] = p.w;
    }
#pragma unroll
    for (int it = 0; it < 2; ++it) {
      int f = tid + it * 256;  // 0..511 : 32 k rows x 16 float4
      int kr = f >> 4, n4 = (f & 15) * 4;
      float4 p;
      if (n0 + n4 < 864)
        p = *(const float4*)(w + (size_t)(kb + kr) * 864 + n0 + n4);
      else { p.x = 0.f; p.y = 0.f; p.z = 0.f; p.w = 0.f; }
      *(float4*)(w_lds + kr * 64 + n4) = p;
    }
    __syncthreads();
#pragma unroll 4
    for (int k = 0; k < 32; ++k) {
      float4 wv = *(const float4*)(w_lds + k * 64 + nl);
      float4 a0 = *(const float4*)(a_lds + k * AST + m0);
      float4 a1 = *(const float4*)(a_lds + k * AST + m0 + 4);
      float am[8] = {a0.x, a0.y, a0.z, a0.w, a1.x, a1.y, a1.z, a1.w};
#pragma unroll
      for (int i = 0; i < 8; ++i) {
        acc[i][0] = fmaf(am[i], wv.x, acc[i][0]);
        acc[i][1] = fmaf(am[i], wv.y, acc[i][1]);
        acc[i][2] = fmaf(am[i], wv.z, acc[i][2]);
        acc[i][3] = fmaf(am[i], wv.w, acc[i][3]);
      }
    }
    __syncthreads();
  }
  if (n0 + nl < 864) {
#pragma unroll
    for (int i = 0; i < 8; ++i) {
      float4 v;
      v.x = acc[i][0]; v.y = acc[i][1]; v.z = acc[i][2]; v.w = acc[i][3];
      *(float4*)(part + ((size_t)kc * 128 + m0 + i) * 864 + n0 + nl) = v;
    }
  }
}

// ---------------- K3b: reduce K-split partials + bias + relu ----------------
__global__ __launch_bounds__(256) void k_dense_fin(
    const float* __restrict__ part, const float* __restrict__ bias,
    float* __restrict__ filt) {
  int e = blockIdx.x * 256 + threadIdx.x;  // grid 432*256 = 128*864
  float s = bias[e % 864];
#pragma unroll
  for (int kc = 0; kc < 18; ++kc) s += part[(size_t)kc * 110592 + e];
  filt[e] = fmaxf(s, 0.f);
}

// ---------------- K_prep: swizzle W1 (228x128) into bf16 hi/lo B-frags -----
// layout: [ntile(8)][kstep(8)][lane(64)][8], element = W1[k][col],
// k = 32*s + (lane>>4)*8 + j (0 beyond 227), col = 16*nt + (lane&15).
__global__ __launch_bounds__(256) void k_prep(
    const float* __restrict__ W1, unsigned short* __restrict__ Wh,
    unsigned short* __restrict__ Wl) {
  int t = blockIdx.x * 256 + threadIdx.x;  // 128 blocks -> 32768
  int j = t & 7, l = (t >> 3) & 63, s = (t >> 9) & 7, nt = t >> 12;
  int k = 32 * s + (l >> 4) * 8 + j;
  int col = 16 * nt + (l & 15);
  float v = (k < 228) ? W1[k * 128 + col] : 0.f;
  unsigned short h = f2bf_rne(v);
  Wh[t] = h;
  Wl[t] = f2bf_rne(v - bf2f(h));
}

// ---------------- K4: fused CA update (R4-proven MFMA W1 path; ------------
// phase B restructured: hid in 12 regs/thread (global load), parity o-split
// (even/odd -> equal trips, no divergence), fl reads wave-broadcast.
__global__ __launch_bounds__(256, 3) void k_ca(
    const float* __restrict__ x, const float* __restrict__ filt,
    const unsigned short* __restrict__ W1Bh, const unsigned short* __restrict__ W1Bl,
    const float* __restrict__ B1,
    const float* __restrict__ W2, const float* __restrict__ B2,
    float* __restrict__ xnew, float* __restrict__ aold,
    float* __restrict__ anew) {
  // LDS (bytes): fl@0 (3456) | ia@3456 (32x120 f32 = 15360) |
  // PAh@18816 (64x104 ushort = 13312) | PAl@32128 (13312) = 45440 total.
  // union after last M: uB = (float*)(S+3456), 33276 B.
  __shared__ __align__(16) unsigned char S[45440];
  float* fl = (float*)S;
  float* ia = (float*)(S + 3456);
  unsigned short* PAh = (unsigned short*)(S + 18816);
  unsigned short* PAl = (unsigned short*)(S + 32128);
  float* uB = (float*)(S + 3456);

  int tid = threadIdx.x;
  int b = blockIdx.y;
  int tx = (blockIdx.x & 7) * 8, ty = (blockIdx.x >> 3) * 8;
  int wv = tid >> 6, lane = tid & 63;
  int lr = lane & 15, lhi = lane >> 4;

  // ---- phase A: fl (f32), board -> ia[0..3], hid -> 12 regs (tid<200)
  for (int f = tid; f < 864; f += 256) fl[f] = filt[(size_t)b * 864 + f];
  float hidr[12];
  int px_ = tid >> 1, half = tid & 1;
  int pp_ = 0;
#pragma unroll
  for (int h = 0; h < 12; ++h) hidr[h] = 0.f;
  if (tid < 200) {
    int hy = px_ / 10, hx = px_ - hy * 10;
    pp_ = hy * 12 + hx;
    int gy = ty + hy - 1, gx = tx + hx - 1;
    if (gy >= 0 && gy < 64 && gx >= 0 && gx < 64) {
      const float* xp = x + (((size_t)b * 64 + gy) * 64 + gx) * 16;
      float4 hA = *(const float4*)(xp + 4);
      float4 hB = *(const float4*)(xp + 8);
      float4 hC = *(const float4*)(xp + 12);
      hidr[0] = hA.x; hidr[1] = hA.y; hidr[2] = hA.z; hidr[3] = hA.w;
      hidr[4] = hB.x; hidr[5] = hB.y; hidr[6] = hB.z; hidr[7] = hB.w;
      hidr[8] = hC.x; hidr[9] = hC.y; hidr[10] = hC.z; hidr[11] = hC.w;
    }
  }
  if (tid < 100) {
    int hy = tid / 10, hx = tid - hy * 10;
    int pp = hy * 12 + hx;
    int gy = ty + hy - 1, gx = tx + hx - 1;
    if (gy >= 0 && gy < 64 && gx >= 0 && gx < 64) {
      const float* xp = x + (((size_t)b * 64 + gy) * 64 + gx) * 16;
      float4 bd = *(const float4*)xp;
      ia[0 * 120 + pp] = bd.x; ia[1 * 120 + pp] = bd.y;
      ia[2 * 120 + pp] = bd.z; ia[3 * 120 + pp] = bd.w;
    } else {
      ia[0 * 120 + pp] = 0.f; ia[1 * 120 + pp] = 0.f;
      ia[2 * 120 + pp] = 0.f; ia[3 * 120 + pp] = 0.f;
    }
  }
  __syncthreads();

  f32x4 acc[4][2];
#pragma unroll
  for (int m = 0; m < 4; ++m)
#pragma unroll
    for (int nt = 0; nt < 2; ++nt)
      acc[m][nt] = (f32x4){0.f, 0.f, 0.f, 0.f};

  int py = lane >> 3, pxx = lane & 7;
  int hp0 = (py + 1) * 12 + (pxx + 1);

  for (int chunk = 0; chunk < 3; ++chunk) {
    const int nch = (chunk == 0) ? 28 : ((chunk == 1) ? 32 : 12);
    const int o_first = (chunk == 0) ? 0 : ((chunk == 1) ? 28 : 60);
    const int cc0 = (chunk == 0) ? 4 : 0;

    // ---- phase B: img_conv from regs, parity split (o = o_first+2i+half)
    if (tid < 200) {
      int nit = nch >> 1;
      for (int i = 0; i < nit; ++i) {
        int o = o_first + 2 * i + half;
        const float* flo = fl + o;
        float a = 0.f;
#pragma unroll
        for (int h = 0; h < 12; ++h) a = fmaf(hidr[h], flo[h * 72], a);
        ia[(cc0 + (o - o_first)) * 120 + pp_] = a;
      }
    }
    if (chunk == 2) {  // zero PA pad region k_loc 36..63 (matches W1 zeros)
#pragma unroll
      for (int z = 0; z < 7; ++z) {
        int kk = 36 + wv * 7 + z;
        PAh[lane * 104 + kk] = 0;
        PAl[lane * 104 + kk] = 0;
      }
    }
    __syncthreads();

    // ---- phase P: W1 B-frag prefetch + perception -> PA (R4-proven)
    int nks = (chunk < 2) ? 3 : 2;
    bf16x8 bh[2][3], bl[2][3];
#pragma unroll
    for (int nt = 0; nt < 2; ++nt)
#pragma unroll
      for (int ks = 0; ks < 3; ++ks)
        if (ks < nks) {
          int s = chunk * 3 + ks;
          int base = (((wv * 2 + nt) * 8 + s) * 64 + lane) * 8;
          bh[nt][ks] = *(const bf16x8*)(W1Bh + base);
          bl[nt][ks] = *(const bf16x8*)(W1Bl + base);
        }
    {
      int npc = (chunk < 2) ? 8 : 3;
      for (int ii = 0; ii < npc; ++ii) {
        int cc = wv * npc + ii;
        const float* pc = ia + cc * 120 + hp0;
        float n00 = pc[-13], n01 = pc[-12], n02 = pc[-11];
        float n10 = pc[-1], n11 = pc[0], n12 = pc[1];
        float n20 = pc[11], n21 = pc[12], n22 = pc[13];
        float pid = n11;
        float psx = ((n02 - n00) + 2.f * (n12 - n10) + (n22 - n20)) * 0.125f;
        float psy = ((n20 - n00) + 2.f * (n21 - n01) + (n22 - n02)) * 0.125f;
        unsigned short h0, l0, h1, l1, h2, l2;
        split2(pid, h0, l0); split2(psx, h1, l1); split2(psy, h2, l2);
        int kk = lane * 104 + 3 * cc;
        PAh[kk + 0] = h0; PAh[kk + 1] = h1; PAh[kk + 2] = h2;
        PAl[kk + 0] = l0; PAl[kk + 1] = l1; PAl[kk + 2] = l2;
      }
    }
    __syncthreads();

    // ---- phase M: MFMA over this chunk's ksteps (R4-proven)
#pragma unroll
    for (int ks = 0; ks < 3; ++ks) {
      if (ks < nks) {
#pragma unroll
        for (int m = 0; m < 4; ++m) {
          int arow = m * 16 + lr;
          bf16x8 pah = *(const bf16x8*)(PAh + arow * 104 + ks * 32 + lhi * 8);
          bf16x8 pal = *(const bf16x8*)(PAl + arow * 104 + ks * 32 + lhi * 8);
#pragma unroll
          for (int nt = 0; nt < 2; ++nt) {
            acc[m][nt] = __builtin_amdgcn_mfma_f32_16x16x32_bf16(
                pah, bh[nt][ks], acc[m][nt], 0, 0, 0);
            acc[m][nt] = __builtin_amdgcn_mfma_f32_16x16x32_bf16(
                pah, bl[nt][ks], acc[m][nt], 0, 0, 0);
            acc[m][nt] = __builtin_amdgcn_mfma_f32_16x16x32_bf16(
                pal, bh[nt][ks], acc[m][nt], 0, 0, 0);
          }
        }
      }
    }
    __syncthreads();
  }

  // ---- tail: u = relu(acc + B1) -> LDS [hidden][pixel] (stride 65)
  int d0 = wv * 32;
  float b1v0 = B1[d0 + lr], b1v1 = B1[d0 + 16 + lr];
#pragma unroll
  for (int m = 0; m < 4; ++m)
#pragma unroll
    for (int nt = 0; nt < 2; ++nt) {
      int hrow = d0 + nt * 16 + lr;
      float bv = nt ? b1v1 : b1v0;
#pragma unroll
      for (int r = 0; r < 4; ++r) {
        int pxw = m * 16 + lhi * 4 + r;
        uB[hrow * 65 + pxw] = fmaxf(acc[m][nt][r] + bv, 0.f);
      }
    }
  float uu[32];
#pragma unroll
  for (int i = 0; i < 32; ++i) uu[i] = uB[(d0 + i) * 65 + lane];
  float dxp[16];
#pragma unroll
  for (int e = 0; e < 16; ++e) dxp[e] = 0.f;
#pragma unroll
  for (int i = 0; i < 32; ++i) {
    const float* w2r = W2 + (size_t)(d0 + i) * 16;
#pragma unroll
    for (int e = 0; e < 16; ++e) dxp[e] = fmaf(uu[i], w2r[e], dxp[e]);
  }
  __syncthreads();
  {
    float* red = uB + wv * 2080;
#pragma unroll
    for (int e = 0; e < 16; ++e) red[lane * 17 + e] = dxp[e];
  }
  __syncthreads();

  // ---- phase D: reduce 4 waves, fire mask, write x_new + alphas
  int px = tid >> 2, q = tid & 3;
  int ply = px >> 3, plx = px & 7;
  int gy = ty + ply, gx = tx + plx;
  size_t base = (((size_t)b * 64 + gy) * 64 + gx) * 16;
  unsigned pix = (unsigned)(b * 4096 + gy * 64 + gx);
  float msk = (tf42_uniform(pix) <= 0.5f) ? 1.f : 0.f;
  int e0 = q * 4;
  float4 xo = *(const float4*)(x + base + e0);
  float dv[4];
#pragma unroll
  for (int jj = 0; jj < 4; ++jj) {
    dv[jj] = uB[0 * 2080 + px * 17 + e0 + jj] + uB[1 * 2080 + px * 17 + e0 + jj] +
             uB[2 * 2080 + px * 17 + e0 + jj] + uB[3 * 2080 + px * 17 + e0 + jj] +
             B2[e0 + jj];
  }
  float4 xn;
  xn.x = xo.x + dv[0] * msk;
  xn.y = xo.y + dv[1] * msk;
  xn.z = xo.z + dv[2] * msk;
  xn.w = xo.w + dv[3] * msk;
  *(float4*)(xnew + base + e0) = xn;
  if (q == 0) {
    aold[pix] = xo.w;
    anew[pix] = xn.w;
  }
}

// ---------------- K5: living masks + final multiply (in place on d_out) ----
__global__ __launch_bounds__(256) void k_final(
    float* __restrict__ xnew, const float* __restrict__ aold,
    const float* __restrict__ anew) {
  int t = blockIdx.x * 256 + threadIdx.x;  // grid 2048*256 = 524288
  int gx = t & 63, gy = (t >> 6) & 63, b = t >> 12;
  float mo = -1e30f, mn = -1e30f;
  for (int dy = -1; dy <= 1; ++dy) {
    int yy = gy + dy; if (yy < 0 || yy >= 64) continue;
    for (int dx = -1; dx <= 1; ++dx) {
      int xx = gx + dx; if (xx < 0 || xx >= 64) continue;
      int p = b * 4096 + yy * 64 + xx;
      mo = fmaxf(mo, aold[p]);
      mn = fmaxf(mn, anew[p]);
    }
  }
  float live = (mo > 0.1f && mn > 0.1f) ? 1.f : 0.f;
  size_t base = (size_t)t * 16;
#pragma unroll
  for (int c4 = 0; c4 < 4; ++c4) {
    float4 v = *(const float4*)(xnew + base + c4 * 4);
    v.x *= live; v.y *= live; v.z *= live; v.w *= live;
    *(float4*)(xnew + base + c4 * 4) = v;
  }
}

// ---------------- launch ----------------
extern "C" void kernel_launch(void* const* d_in, const int* in_sizes, int n_in,
                              void* d_out, int out_size, void* d_ws, size_t ws_size,
                              hipStream_t stream) {
  const float* x    = (const float*)d_in[0];
  const float* img  = (const float*)d_in[1];
  const float* g1   = (const float*)d_in[2];
  const float* be1  = (const float*)d_in[3];
  const float* m1   = (const float*)d_in[4];
  const float* v1   = (const float*)d_in[5];
  const float* w1c  = (const float*)d_in[6];
  const float* b1c  = (const float*)d_in[7];
  const float* g2   = (const float*)d_in[8];
  const float* be2  = (const float*)d_in[9];
  const float* m2   = (const float*)d_in[10];
  const float* v2   = (const float*)d_in[11];
  const float* w2c  = (const float*)d_in[12];
  const float* b2c  = (const float*)d_in[13];
  const float* dw   = (const float*)d_in[14];
  const float* db   = (const float*)d_in[15];
  const float* uw1  = (const float*)d_in[16];
  const float* ub1  = (const float*)d_in[17];
  const float* uw2  = (const float*)d_in[18];
  const float* ub2  = (const float*)d_in[19];

  char* ws = (char*)d_ws;
  float* h1   = (float*)(ws);                        // 21,233,664 B
  float* part = h1;                                  // aliased after K2 done
  float* h2   = (float*)(ws + 21233664);             // 5,308,416 B
  float* filt = (float*)(ws + 26542080);             // 442,368 B
  float* aold = (float*)(ws + 26984448);             // 2,097,152 B
  float* anew = (float*)(ws + 29081600);             // 2,097,152 B
  unsigned short* W1Bh = (unsigned short*)(ws + 31178752);  // 65,536 B
  unsigned short* W1Bl = (unsigned short*)(ws + 31244288);  // 65,536 B
  float* xnew = (float*)d_out;                       // (128,64,64,16) f32

  k_prep<<<128, 256, 0, stream>>>(uw1, W1Bh, W1Bl);
  k_conv1<<<648, 256, 0, stream>>>(img, g1, be1, m1, v1, w1c, b1c,
                                   g2, be2, m2, v2, h1);
  k_conv2<<<dim3(162, 4), 256, 0, stream>>>(h1, w2c, b2c, h2);
  k_dense_part<<<dim3(14, 18), 256, 0, stream>>>(h2, dw, part);
  k_dense_fin<<<432, 256, 0, stream>>>(part, db, filt);
  k_ca<<<dim3(64, 128), 256, 0, stream>>>(x, filt, W1Bh, W1Bl, ub1, uw2, ub2,
                                          xnew, aold, anew);
  k_final<<<2048, 256, 0, stream>>>(xnew, aold, anew);
}

// Round 7
// 498.108 us; speedup vs baseline: 1.4445x; 1.1077x over previous
//
#include <hip/hip_runtime.h>

#define BN_EPS 1e-3f

typedef __attribute__((ext_vector_type(8))) short bf16x8;
typedef __attribute__((ext_vector_type(4))) short s16x4;
typedef __attribute__((ext_vector_type(4))) float f32x4;

// ---------------- bf16 split helpers ----------------
__device__ __forceinline__ unsigned short f2bf_rne(float f) {
  unsigned u = __float_as_uint(f);
  unsigned r = u + 0x7fffu + ((u >> 16) & 1u);
  return (unsigned short)(r >> 16);
}
__device__ __forceinline__ float bf2f(unsigned short h) {
  return __uint_as_float(((unsigned)h) << 16);
}
__device__ __forceinline__ void split2(float v, unsigned short& h, unsigned short& l) {
  h = f2bf_rne(v);
  l = f2bf_rne(v - bf2f(h));
}

// ---------------- threefry2x32 (JAX partitionable path, key=[0,42]) --------
__device__ __forceinline__ unsigned rotl32(unsigned v, int n) {
  return (v << n) | (v >> (32 - n));
}

__device__ __forceinline__ float tf42_uniform(unsigned i) {
  unsigned x0 = 0u, x1 = i;
  const unsigned k0 = 0u, k1 = 42u, k2 = 0u ^ 42u ^ 0x1BD11BDAu;
  x0 += k0; x1 += k1;
#define TFR(r) { x0 += x1; x1 = rotl32(x1, r); x1 ^= x0; }
  TFR(13) TFR(15) TFR(26) TFR(6)
  x0 += k1; x1 += k2 + 1u;
  TFR(17) TFR(29) TFR(16) TFR(24)
  x0 += k2; x1 += k0 + 2u;
  TFR(13) TFR(15) TFR(26) TFR(6)
  x0 += k0; x1 += k1 + 3u;
  TFR(17) TFR(29) TFR(16) TFR(24)
  x0 += k1; x1 += k2 + 4u;
  TFR(13) TFR(15) TFR(26) TFR(6)
  x0 += k2; x1 += k0 + 5u;
#undef TFR
  unsigned bits = x0 ^ x1;
  return __uint_as_float((bits >> 9) | 0x3F800000u) - 1.0f;
}

// ---------------- K1: bn1 + conv1(4->32) + relu + maxpool2 + bn2 -----------
__global__ __launch_bounds__(256) void k_conv1(
    const float* __restrict__ img,
    const float* __restrict__ g1, const float* __restrict__ be1,
    const float* __restrict__ m1, const float* __restrict__ v1,
    const float* __restrict__ w, const float* __restrict__ bias,
    const float* __restrict__ g2, const float* __restrict__ be2,
    const float* __restrict__ m2, const float* __restrict__ v2,
    float* __restrict__ h1) {
  int t = blockIdx.x * 256 + threadIdx.x;  // grid exactly 648*256 = 128*36*36
  int ox = t % 36, oy = (t / 36) % 36, b = t / 1296;
  float s1[4], t1[4];
#pragma unroll
  for (int ci = 0; ci < 4; ++ci) {
    float s = g1[ci] / sqrtf(v1[ci] + BN_EPS);
    s1[ci] = s; t1[ci] = be1[ci] - m1[ci] * s;
  }
  float pacc[32];
#pragma unroll
  for (int co = 0; co < 32; ++co) pacc[co] = 0.f;
#pragma unroll
  for (int sy = 0; sy < 2; ++sy)
#pragma unroll
  for (int sx = 0; sx < 2; ++sx) {
    int iy = 2 * oy + sy, ix = 2 * ox + sx;
    float acc[32];
#pragma unroll
    for (int co = 0; co < 32; ++co) acc[co] = bias[co];
    for (int ky = 0; ky < 3; ++ky) {
      int yy = iy + ky - 1; if (yy < 0 || yy >= 72) continue;
      for (int kx = 0; kx < 3; ++kx) {
        int xx = ix + kx - 1; if (xx < 0 || xx >= 72) continue;
        float4 p = *(const float4*)(img + (((size_t)b * 72 + yy) * 72 + xx) * 4);
        float in0 = p.x * s1[0] + t1[0];
        float in1 = p.y * s1[1] + t1[1];
        float in2 = p.z * s1[2] + t1[2];
        float in3 = p.w * s1[3] + t1[3];
        const float* wp = w + (ky * 3 + kx) * 128;  // (3,3,4,32)
#pragma unroll
        for (int co = 0; co < 32; ++co) acc[co] = fmaf(in0, wp[co], acc[co]);
#pragma unroll
        for (int co = 0; co < 32; ++co) acc[co] = fmaf(in1, wp[32 + co], acc[co]);
#pragma unroll
        for (int co = 0; co < 32; ++co) acc[co] = fmaf(in2, wp[64 + co], acc[co]);
#pragma unroll
        for (int co = 0; co < 32; ++co) acc[co] = fmaf(in3, wp[96 + co], acc[co]);
      }
    }
#pragma unroll
    for (int co = 0; co < 32; ++co)
      pacc[co] = fmaxf(pacc[co], fmaxf(acc[co], 0.f));
  }
#pragma unroll
  for (int co = 0; co < 32; ++co) {
    float s = g2[co] / sqrtf(v2[co] + BN_EPS);
    pacc[co] = pacc[co] * s + (be2[co] - m2[co] * s);
  }
  float* op = h1 + (size_t)t * 32;
#pragma unroll
  for (int c4 = 0; c4 < 8; ++c4) {
    float4 v;
    v.x = pacc[c4 * 4]; v.y = pacc[c4 * 4 + 1];
    v.z = pacc[c4 * 4 + 2]; v.w = pacc[c4 * 4 + 3];
    *(float4*)(op + c4 * 4) = v;
  }
}

// ---------------- K2: conv2(32->32) + relu + maxpool2 ----------------
__global__ __launch_bounds__(256) void k_conv2(
    const float* __restrict__ h1, const float* __restrict__ w,
    const float* __restrict__ bias, float* __restrict__ h2) {
  int t = blockIdx.x * 256 + threadIdx.x;  // grid 162*256 = 128*18*18
  int co0 = blockIdx.y * 8;
  int ox = t % 18, oy = (t / 18) % 18, b = t / 324;
  float pacc[8];
#pragma unroll
  for (int i = 0; i < 8; ++i) pacc[i] = 0.f;
#pragma unroll
  for (int sy = 0; sy < 2; ++sy)
#pragma unroll
  for (int sx = 0; sx < 2; ++sx) {
    int iy = 2 * oy + sy, ix = 2 * ox + sx;
    float acc[8];
#pragma unroll
    for (int i = 0; i < 8; ++i) acc[i] = bias[co0 + i];
    for (int ky = 0; ky < 3; ++ky) {
      int yy = iy + ky - 1; if (yy < 0 || yy >= 36) continue;
      for (int kx = 0; kx < 3; ++kx) {
        int xx = ix + kx - 1; if (xx < 0 || xx >= 36) continue;
        const float* ip = h1 + (((size_t)b * 36 + yy) * 36 + xx) * 32;
        const float* wp = w + (ky * 3 + kx) * 1024 + co0;  // (3,3,32,32)
        float in[32];
#pragma unroll
        for (int c4 = 0; c4 < 8; ++c4) {
          float4 p = *(const float4*)(ip + c4 * 4);
          in[c4 * 4] = p.x; in[c4 * 4 + 1] = p.y;
          in[c4 * 4 + 2] = p.z; in[c4 * 4 + 3] = p.w;
        }
#pragma unroll
        for (int ci = 0; ci < 32; ++ci)
#pragma unroll
          for (int i = 0; i < 8; ++i)
            acc[i] = fmaf(in[ci], wp[ci * 32 + i], acc[i]);
      }
    }
#pragma unroll
    for (int i = 0; i < 8; ++i) pacc[i] = fmaxf(pacc[i], fmaxf(acc[i], 0.f));
  }
  float* op = h2 + (size_t)t * 32 + co0;
  float4 v0, v1;
  v0.x = pacc[0]; v0.y = pacc[1]; v0.z = pacc[2]; v0.w = pacc[3];
  v1.x = pacc[4]; v1.y = pacc[5]; v1.z = pacc[6]; v1.w = pacc[7];
  *(float4*)op = v0;
  *(float4*)(op + 4) = v1;
}

// ---------------- K3a: dense partial GEMM (K-split) ----------------
#define AST 132
__global__ __launch_bounds__(256) void k_dense_part(
    const float* __restrict__ h2, const float* __restrict__ w,
    float* __restrict__ part) {
  __shared__ float a_lds[32 * AST];
  __shared__ float w_lds[32 * 64];
  int tid = threadIdx.x;
  int n0 = blockIdx.x * 64;   // 14 blocks (last ragged)
  int kc = blockIdx.y;        // 18 K-chunks of 576
  int m0 = (tid >> 4) * 8;
  int nl = (tid & 15) * 4;
  float acc[8][4];
#pragma unroll
  for (int i = 0; i < 8; ++i)
#pragma unroll
    for (int j = 0; j < 4; ++j) acc[i][j] = 0.f;
  for (int kt = 0; kt < 18; ++kt) {
    int kb = kc * 576 + kt * 32;
#pragma unroll
    for (int it = 0; it < 4; ++it) {
      int f = tid + it * 256;  // 0..1023 : 128 m rows x 8 float4
      int ml = f >> 3, kq = f & 7;
      float4 p = *(const float4*)(h2 + (size_t)ml * 10368 + kb + kq * 4);
      a_lds[(kq * 4 + 0) * AST + ml] = p.x;
      a_lds[(kq * 4 + 1) * AST + ml] = p.y;
      a_lds[(kq * 4 + 2) * AST + ml] = p.z;
      a_lds[(kq * 4 + 3) * AST + ml] = p.w;
    }
#pragma unroll
    for (int it = 0; it < 2; ++it) {
      int f = tid + it * 256;  // 0..511 : 32 k rows x 16 float4
      int kr = f >> 4, n4 = (f & 15) * 4;
      float4 p;
      if (n0 + n4 < 864)
        p = *(const float4*)(w + (size_t)(kb + kr) * 864 + n0 + n4);
      else { p.x = 0.f; p.y = 0.f; p.z = 0.f; p.w = 0.f; }
      *(float4*)(w_lds + kr * 64 + n4) = p;
    }
    __syncthreads();
#pragma unroll 4
    for (int k = 0; k < 32; ++k) {
      float4 wv = *(const float4*)(w_lds + k * 64 + nl);
      float4 a0 = *(const float4*)(a_lds + k * AST + m0);
      float4 a1 = *(const float4*)(a_lds + k * AST + m0 + 4);
      float am[8] = {a0.x, a0.y, a0.z, a0.w, a1.x, a1.y, a1.z, a1.w};
#pragma unroll
      for (int i = 0; i < 8; ++i) {
        acc[i][0] = fmaf(am[i], wv.x, acc[i][0]);
        acc[i][1] = fmaf(am[i], wv.y, acc[i][1]);
        acc[i][2] = fmaf(am[i], wv.z, acc[i][2]);
        acc[i][3] = fmaf(am[i], wv.w, acc[i][3]);
      }
    }
    __syncthreads();
  }
  if (n0 + nl < 864) {
#pragma unroll
    for (int i = 0; i < 8; ++i) {
      float4 v;
      v.x = acc[i][0]; v.y = acc[i][1]; v.z = acc[i][2]; v.w = acc[i][3];
      *(float4*)(part + ((size_t)kc * 128 + m0 + i) * 864 + n0 + nl) = v;
    }
  }
}

// ---------------- K3b: reduce K-split partials + bias + relu ----------------
__global__ __launch_bounds__(256) void k_dense_fin(
    const float* __restrict__ part, const float* __restrict__ bias,
    float* __restrict__ filt) {
  int e = blockIdx.x * 256 + threadIdx.x;  // grid 432*256 = 128*864
  float s = bias[e % 864];
#pragma unroll
  for (int kc = 0; kc < 18; ++kc) s += part[(size_t)kc * 110592 + e];
  filt[e] = fmaxf(s, 0.f);
}

// ---------------- K_prep2: per-batch effective W1 (64x128) bf16 frags ------
// W1eff[k][col]: k<12 -> W1[k][col] (board); 12<=k<48 -> sum_c fl[h][c] *
// W1[12+3c+t][col] (h=(k-12)/3, t=(k-12)%3); k>=48 -> 0.
// Frag layout per batch: [nt 8][ks 2][lane 64][8]: elem = W1eff[k][col],
// k = 32*ks + (lane>>4)*8 + j, col = 16*nt + (lane&15).
__global__ __launch_bounds__(256) void k_prep2(
    const float* __restrict__ filt, const float* __restrict__ W1,
    unsigned short* __restrict__ Eh, unsigned short* __restrict__ El) {
  __shared__ float fl[864];
  int b = blockIdx.x;
  int tid = threadIdx.x;
  for (int f = tid; f < 864; f += 256) fl[f] = filt[(size_t)b * 864 + f];
  __syncthreads();
  int col = tid & 127;
  int k0 = tid >> 7;
  for (int k = k0; k < 64; k += 2) {
    float v;
    if (k < 12) {
      v = W1[k * 128 + col];
    } else if (k < 48) {
      int h = (k - 12) / 3, t = (k - 12) % 3;
      const float* wp = W1 + (12 + t) * 128 + col;  // + c*384 walks rows 12+3c+t
      const float* fp = fl + h * 72;
      float a = 0.f;
      for (int c = 0; c < 72; ++c) a = fmaf(fp[c], wp[(size_t)c * 384], a);
      v = a;
    } else {
      v = 0.f;
    }
    unsigned short hh, ll;
    split2(v, hh, ll);
    int ks = k >> 5, j = k & 7, a4 = (k >> 3) & 3;
    int l = a4 * 16 + (col & 15), nt = col >> 4;
    size_t o = (((size_t)b * 8 + nt) * 2 + ks) * 512 + l * 8 + j;
    Eh[o] = hh;
    El[o] = ll;
  }
}

// ---------------- K4: fused CA update (W1eff form, K=48, split-bf16) -------
// u = P_x @ W1eff: P_x = perception of the 16 raw x channels (48 features);
// img_conv folded into W1eff per batch (k_prep2). 5 barriers, 33.3KB LDS.
__global__ __launch_bounds__(256, 4) void k_ca(
    const float* __restrict__ x,
    const unsigned short* __restrict__ Eh, const unsigned short* __restrict__ El,
    const float* __restrict__ B1,
    const float* __restrict__ W2, const float* __restrict__ B2,
    float* __restrict__ xnew, float* __restrict__ aold,
    float* __restrict__ anew) {
  // LDS: ia[16][120] f32 @0 (7680) | PAh @7680 (64x72 u16 = 9216) |
  // PAl @16896 (9216) -> 26112 staging; union uB f32[128*65] @0 = 33280.
  __shared__ __align__(16) unsigned char S[33280];
  float* ia = (float*)S;
  unsigned short* PAh = (unsigned short*)(S + 7680);
  unsigned short* PAl = (unsigned short*)(S + 16896);
  float* uB = (float*)S;

  int tid = threadIdx.x;
  int b = blockIdx.y;
  int tx = (blockIdx.x & 7) * 8, ty = (blockIdx.x >> 3) * 8;
  int wv = tid >> 6, lane = tid & 63;
  int lr = lane & 15, lhi = lane >> 4;

  // B-frag prefetch from global (no LDS dependency -> hides under phase A)
  bf16x8 bh[2][2], bl[2][2];
#pragma unroll
  for (int nt = 0; nt < 2; ++nt)
#pragma unroll
    for (int ks = 0; ks < 2; ++ks) {
      size_t base = (((size_t)b * 8 + (wv * 2 + nt)) * 2 + ks) * 512 + lane * 8;
      bh[nt][ks] = *(const bf16x8*)(Eh + base);
      bl[nt][ks] = *(const bf16x8*)(El + base);
    }

  // ---- phase A: stage x halo (16 ch f32) -> ia; zero PA k-pad cols 48..63
  if (tid < 200) {
    int px_ = tid >> 1, half = tid & 1;
    int hy = px_ / 10, hx = px_ - hy * 10;
    int pp = hy * 12 + hx;
    int gy = ty + hy - 1, gx = tx + hx - 1;
    float4 v0 = {0.f, 0.f, 0.f, 0.f}, v1 = {0.f, 0.f, 0.f, 0.f};
    if (gy >= 0 && gy < 64 && gx >= 0 && gx < 64) {
      const float* xp = x + (((size_t)b * 64 + gy) * 64 + gx) * 16 + half * 8;
      v0 = *(const float4*)xp;
      v1 = *(const float4*)(xp + 4);
    }
    int c0 = half * 8;
    ia[(c0 + 0) * 120 + pp] = v0.x; ia[(c0 + 1) * 120 + pp] = v0.y;
    ia[(c0 + 2) * 120 + pp] = v0.z; ia[(c0 + 3) * 120 + pp] = v0.w;
    ia[(c0 + 4) * 120 + pp] = v1.x; ia[(c0 + 5) * 120 + pp] = v1.y;
    ia[(c0 + 6) * 120 + pp] = v1.z; ia[(c0 + 7) * 120 + pp] = v1.w;
  }
  {
    const s16x4 z4 = {0, 0, 0, 0};
    if (wv == 2) {
#pragma unroll
      for (int g = 0; g < 4; ++g) *(s16x4*)(PAh + lane * 72 + 48 + 4 * g) = z4;
    }
    if (wv == 3) {
#pragma unroll
      for (int g = 0; g < 4; ++g) *(s16x4*)(PAl + lane * 72 + 48 + 4 * g) = z4;
    }
  }
  __syncthreads();

  // ---- phase P: perception of ch 4wv..4wv+3 -> PA cols 12wv..12wv+11
  {
    int py = lane >> 3, pxx = lane & 7;
    const float* pc0 = ia + (py + 1) * 12 + (pxx + 1);
    unsigned short oh[12], ol[12];
#pragma unroll
    for (int i = 0; i < 4; ++i) {
      const float* pc = pc0 + (wv * 4 + i) * 120;
      float n00 = pc[-13], n01 = pc[-12], n02 = pc[-11];
      float n10 = pc[-1],  n11 = pc[0],   n12 = pc[1];
      float n20 = pc[11],  n21 = pc[12],  n22 = pc[13];
      float pid = n11;
      float psx = ((n02 - n00) + 2.f * (n12 - n10) + (n22 - n20)) * 0.125f;
      float psy = ((n20 - n00) + 2.f * (n21 - n01) + (n22 - n02)) * 0.125f;
      split2(pid, oh[3 * i + 0], ol[3 * i + 0]);
      split2(psx, oh[3 * i + 1], ol[3 * i + 1]);
      split2(psy, oh[3 * i + 2], ol[3 * i + 2]);
    }
    int off = lane * 72 + wv * 12;
#pragma unroll
    for (int g = 0; g < 3; ++g) {
      s16x4 vh = {(short)oh[4 * g], (short)oh[4 * g + 1],
                  (short)oh[4 * g + 2], (short)oh[4 * g + 3]};
      s16x4 vl = {(short)ol[4 * g], (short)ol[4 * g + 1],
                  (short)ol[4 * g + 2], (short)ol[4 * g + 3]};
      *(s16x4*)(PAh + off + 4 * g) = vh;
      *(s16x4*)(PAl + off + 4 * g) = vl;
    }
  }
  __syncthreads();

  // ---- phase M: 2 ksteps x 4 m-tiles x 2 n-tiles x 3 split passes
  f32x4 acc[4][2];
#pragma unroll
  for (int m = 0; m < 4; ++m)
#pragma unroll
    for (int nt = 0; nt < 2; ++nt)
      acc[m][nt] = (f32x4){0.f, 0.f, 0.f, 0.f};
#pragma unroll
  for (int ks = 0; ks < 2; ++ks) {
#pragma unroll
    for (int m = 0; m < 4; ++m) {
      int arow = m * 16 + lr;
      bf16x8 pah = *(const bf16x8*)(PAh + arow * 72 + ks * 32 + lhi * 8);
      bf16x8 pal = *(const bf16x8*)(PAl + arow * 72 + ks * 32 + lhi * 8);
#pragma unroll
      for (int nt = 0; nt < 2; ++nt) {
        acc[m][nt] = __builtin_amdgcn_mfma_f32_16x16x32_bf16(
            pah, bh[nt][ks], acc[m][nt], 0, 0, 0);
        acc[m][nt] = __builtin_amdgcn_mfma_f32_16x16x32_bf16(
            pah, bl[nt][ks], acc[m][nt], 0, 0, 0);
        acc[m][nt] = __builtin_amdgcn_mfma_f32_16x16x32_bf16(
            pal, bh[nt][ks], acc[m][nt], 0, 0, 0);
      }
    }
  }
  __syncthreads();  // staging dead; uB live

  // ---- tail: u = relu(acc + B1) -> uB [hidden][pixel] stride 65; W2 f32
  int d0 = wv * 32;
  float b1v0 = B1[d0 + lr], b1v1 = B1[d0 + 16 + lr];
#pragma unroll
  for (int m = 0; m < 4; ++m)
#pragma unroll
    for (int nt = 0; nt < 2; ++nt) {
      int hrow = d0 + nt * 16 + lr;
      float bv = nt ? b1v1 : b1v0;
#pragma unroll
      for (int r = 0; r < 4; ++r) {
        int pxw = m * 16 + lhi * 4 + r;
        uB[hrow * 65 + pxw] = fmaxf(acc[m][nt][r] + bv, 0.f);
      }
    }
  float uu[32];
#pragma unroll
  for (int i = 0; i < 32; ++i) uu[i] = uB[(d0 + i) * 65 + lane];
  float dxp[16];
#pragma unroll
  for (int e = 0; e < 16; ++e) dxp[e] = 0.f;
#pragma unroll
  for (int i = 0; i < 32; ++i) {
    const float* w2r = W2 + (size_t)(d0 + i) * 16;
#pragma unroll
    for (int e = 0; e < 16; ++e) dxp[e] = fmaf(uu[i], w2r[e], dxp[e]);
  }
  __syncthreads();
  {
    float* red = uB + wv * 2080;
#pragma unroll
    for (int e = 0; e < 16; ++e) red[lane * 17 + e] = dxp[e];
  }
  __syncthreads();

  // ---- phase D: reduce 4 waves, fire mask, write x_new + alphas
  int px = tid >> 2, q = tid & 3;
  int ply = px >> 3, plx = px & 7;
  int gy = ty + ply, gx = tx + plx;
  size_t base = (((size_t)b * 64 + gy) * 64 + gx) * 16;
  unsigned pix = (unsigned)(b * 4096 + gy * 64 + gx);
  float msk = (tf42_uniform(pix) <= 0.5f) ? 1.f : 0.f;
  int e0 = q * 4;
  float4 xo = *(const float4*)(x + base + e0);
  float dv[4];
#pragma unroll
  for (int jj = 0; jj < 4; ++jj) {
    dv[jj] = uB[0 * 2080 + px * 17 + e0 + jj] + uB[1 * 2080 + px * 17 + e0 + jj] +
             uB[2 * 2080 + px * 17 + e0 + jj] + uB[3 * 2080 + px * 17 + e0 + jj] +
             B2[e0 + jj];
  }
  float4 xn;
  xn.x = xo.x + dv[0] * msk;
  xn.y = xo.y + dv[1] * msk;
  xn.z = xo.z + dv[2] * msk;
  xn.w = xo.w + dv[3] * msk;
  *(float4*)(xnew + base + e0) = xn;
  if (q == 0) {
    aold[pix] = xo.w;
    anew[pix] = xn.w;
  }
}

// ---------------- K5: living masks + final multiply (in place on d_out) ----
__global__ __launch_bounds__(256) void k_final(
    float* __restrict__ xnew, const float* __restrict__ aold,
    const float* __restrict__ anew) {
  int t = blockIdx.x * 256 + threadIdx.x;  // grid 2048*256 = 524288
  int gx = t & 63, gy = (t >> 6) & 63, b = t >> 12;
  float mo = -1e30f, mn = -1e30f;
  for (int dy = -1; dy <= 1; ++dy) {
    int yy = gy + dy; if (yy < 0 || yy >= 64) continue;
    for (int dx = -1; dx <= 1; ++dx) {
      int xx = gx + dx; if (xx < 0 || xx >= 64) continue;
      int p = b * 4096 + yy * 64 + xx;
      mo = fmaxf(mo, aold[p]);
      mn = fmaxf(mn, anew[p]);
    }
  }
  float live = (mo > 0.1f && mn > 0.1f) ? 1.f : 0.f;
  size_t base = (size_t)t * 16;
#pragma unroll
  for (int c4 = 0; c4 < 4; ++c4) {
    float4 v = *(const float4*)(xnew + base + c4 * 4);
    v.x *= live; v.y *= live; v.z *= live; v.w *= live;
    *(float4*)(xnew + base + c4 * 4) = v;
  }
}

// ---------------- launch ----------------
extern "C" void kernel_launch(void* const* d_in, const int* in_sizes, int n_in,
                              void* d_out, int out_size, void* d_ws, size_t ws_size,
                              hipStream_t stream) {
  const float* x    = (const float*)d_in[0];
  const float* img  = (const float*)d_in[1];
  const float* g1   = (const float*)d_in[2];
  const float* be1  = (const float*)d_in[3];
  const float* m1   = (const float*)d_in[4];
  const float* v1   = (const float*)d_in[5];
  const float* w1c  = (const float*)d_in[6];
  const float* b1c  = (const float*)d_in[7];
  const float* g2   = (const float*)d_in[8];
  const float* be2  = (const float*)d_in[9];
  const float* m2   = (const float*)d_in[10];
  const float* v2   = (const float*)d_in[11];
  const float* w2c  = (const float*)d_in[12];
  const float* b2c  = (const float*)d_in[13];
  const float* dw   = (const float*)d_in[14];
  const float* db   = (const float*)d_in[15];
  const float* uw1  = (const float*)d_in[16];
  const float* ub1  = (const float*)d_in[17];
  const float* uw2  = (const float*)d_in[18];
  const float* ub2  = (const float*)d_in[19];

  char* ws = (char*)d_ws;
  float* h1   = (float*)(ws);                        // 21,233,664 B (dead after dense)
  float* part = h1;                                  // aliased
  float* h2   = (float*)(ws + 21233664);             // 5,308,416 B
  float* filt = (float*)(ws + 26542080);             // 442,368 B
  float* aold = (float*)(ws + 26984448);             // 2,097,152 B
  float* anew = (float*)(ws + 29081600);             // 2,097,152 B
  // W1eff frags alias the (dead by then) h1/part region:
  unsigned short* W1Eh = (unsigned short*)(ws);             // 2,097,152 B
  unsigned short* W1El = (unsigned short*)(ws + 2097152);   // 2,097,152 B
  float* xnew = (float*)d_out;                       // (128,64,64,16) f32

  k_conv1<<<648, 256, 0, stream>>>(img, g1, be1, m1, v1, w1c, b1c,
                                   g2, be2, m2, v2, h1);
  k_conv2<<<dim3(162, 4), 256, 0, stream>>>(h1, w2c, b2c, h2);
  k_dense_part<<<dim3(14, 18), 256, 0, stream>>>(h2, dw, part);
  k_dense_fin<<<432, 256, 0, stream>>>(part, db, filt);
  k_prep2<<<128, 256, 0, stream>>>(filt, uw1, W1Eh, W1El);
  k_ca<<<dim3(64, 128), 256, 0, stream>>>(x, W1Eh, W1El, ub1, uw2, ub2,
                                          xnew, aold, anew);
  k_final<<<2048, 256, 0, stream>>>(xnew, aold, anew);
}

// Round 8
// 325.879 us; speedup vs baseline: 2.2079x; 1.5285x over previous
//
#include <hip/hip_runtime.h>

#define BN_EPS 1e-3f

typedef __attribute__((ext_vector_type(8))) short bf16x8;
typedef __attribute__((ext_vector_type(4))) short s16x4;
typedef __attribute__((ext_vector_type(4))) float f32x4;

// ---------------- bf16 split helpers ----------------
__device__ __forceinline__ unsigned short f2bf_rne(float f) {
  unsigned u = __float_as_uint(f);
  unsigned r = u + 0x7fffu + ((u >> 16) & 1u);
  return (unsigned short)(r >> 16);
}
__device__ __forceinline__ float bf2f(unsigned short h) {
  return __uint_as_float(((unsigned)h) << 16);
}
__device__ __forceinline__ void split2(float v, unsigned short& h, unsigned short& l) {
  h = f2bf_rne(v);
  l = f2bf_rne(v - bf2f(h));
}

// ---------------- threefry2x32 (JAX partitionable path, key=[0,42]) --------
__device__ __forceinline__ unsigned rotl32(unsigned v, int n) {
  return (v << n) | (v >> (32 - n));
}

__device__ __forceinline__ float tf42_uniform(unsigned i) {
  unsigned x0 = 0u, x1 = i;
  const unsigned k0 = 0u, k1 = 42u, k2 = 0u ^ 42u ^ 0x1BD11BDAu;
  x0 += k0; x1 += k1;
#define TFR(r) { x0 += x1; x1 = rotl32(x1, r); x1 ^= x0; }
  TFR(13) TFR(15) TFR(26) TFR(6)
  x0 += k1; x1 += k2 + 1u;
  TFR(17) TFR(29) TFR(16) TFR(24)
  x0 += k2; x1 += k0 + 2u;
  TFR(13) TFR(15) TFR(26) TFR(6)
  x0 += k0; x1 += k1 + 3u;
  TFR(17) TFR(29) TFR(16) TFR(24)
  x0 += k1; x1 += k2 + 4u;
  TFR(13) TFR(15) TFR(26) TFR(6)
  x0 += k2; x1 += k0 + 5u;
#undef TFR
  unsigned bits = x0 ^ x1;
  return __uint_as_float((bits >> 9) | 0x3F800000u) - 1.0f;
}

// ---------------- K1: bn1 + conv1(4->32) + relu + maxpool2 + bn2 -----------
__global__ __launch_bounds__(256) void k_conv1(
    const float* __restrict__ img,
    const float* __restrict__ g1, const float* __restrict__ be1,
    const float* __restrict__ m1, const float* __restrict__ v1,
    const float* __restrict__ w, const float* __restrict__ bias,
    const float* __restrict__ g2, const float* __restrict__ be2,
    const float* __restrict__ m2, const float* __restrict__ v2,
    float* __restrict__ h1) {
  int t = blockIdx.x * 256 + threadIdx.x;  // grid exactly 648*256 = 128*36*36
  int ox = t % 36, oy = (t / 36) % 36, b = t / 1296;
  float s1[4], t1[4];
#pragma unroll
  for (int ci = 0; ci < 4; ++ci) {
    float s = g1[ci] / sqrtf(v1[ci] + BN_EPS);
    s1[ci] = s; t1[ci] = be1[ci] - m1[ci] * s;
  }
  float pacc[32];
#pragma unroll
  for (int co = 0; co < 32; ++co) pacc[co] = 0.f;
#pragma unroll
  for (int sy = 0; sy < 2; ++sy)
#pragma unroll
  for (int sx = 0; sx < 2; ++sx) {
    int iy = 2 * oy + sy, ix = 2 * ox + sx;
    float acc[32];
#pragma unroll
    for (int co = 0; co < 32; ++co) acc[co] = bias[co];
    for (int ky = 0; ky < 3; ++ky) {
      int yy = iy + ky - 1; if (yy < 0 || yy >= 72) continue;
      for (int kx = 0; kx < 3; ++kx) {
        int xx = ix + kx - 1; if (xx < 0 || xx >= 72) continue;
        float4 p = *(const float4*)(img + (((size_t)b * 72 + yy) * 72 + xx) * 4);
        float in0 = p.x * s1[0] + t1[0];
        float in1 = p.y * s1[1] + t1[1];
        float in2 = p.z * s1[2] + t1[2];
        float in3 = p.w * s1[3] + t1[3];
        const float* wp = w + (ky * 3 + kx) * 128;  // (3,3,4,32)
#pragma unroll
        for (int co = 0; co < 32; ++co) acc[co] = fmaf(in0, wp[co], acc[co]);
#pragma unroll
        for (int co = 0; co < 32; ++co) acc[co] = fmaf(in1, wp[32 + co], acc[co]);
#pragma unroll
        for (int co = 0; co < 32; ++co) acc[co] = fmaf(in2, wp[64 + co], acc[co]);
#pragma unroll
        for (int co = 0; co < 32; ++co) acc[co] = fmaf(in3, wp[96 + co], acc[co]);
      }
    }
#pragma unroll
    for (int co = 0; co < 32; ++co)
      pacc[co] = fmaxf(pacc[co], fmaxf(acc[co], 0.f));
  }
#pragma unroll
  for (int co = 0; co < 32; ++co) {
    float s = g2[co] / sqrtf(v2[co] + BN_EPS);
    pacc[co] = pacc[co] * s + (be2[co] - m2[co] * s);
  }
  float* op = h1 + (size_t)t * 32;
#pragma unroll
  for (int c4 = 0; c4 < 8; ++c4) {
    float4 v;
    v.x = pacc[c4 * 4]; v.y = pacc[c4 * 4 + 1];
    v.z = pacc[c4 * 4 + 2]; v.w = pacc[c4 * 4 + 3];
    *(float4*)(op + c4 * 4) = v;
  }
}

// ---------------- K2: conv2(32->32) + relu + maxpool2 ----------------
__global__ __launch_bounds__(256) void k_conv2(
    const float* __restrict__ h1, const float* __restrict__ w,
    const float* __restrict__ bias, float* __restrict__ h2) {
  int t = blockIdx.x * 256 + threadIdx.x;  // grid 162*256 = 128*18*18
  int co0 = blockIdx.y * 8;
  int ox = t % 18, oy = (t / 18) % 18, b = t / 324;
  float pacc[8];
#pragma unroll
  for (int i = 0; i < 8; ++i) pacc[i] = 0.f;
#pragma unroll
  for (int sy = 0; sy < 2; ++sy)
#pragma unroll
  for (int sx = 0; sx < 2; ++sx) {
    int iy = 2 * oy + sy, ix = 2 * ox + sx;
    float acc[8];
#pragma unroll
    for (int i = 0; i < 8; ++i) acc[i] = bias[co0 + i];
    for (int ky = 0; ky < 3; ++ky) {
      int yy = iy + ky - 1; if (yy < 0 || yy >= 36) continue;
      for (int kx = 0; kx < 3; ++kx) {
        int xx = ix + kx - 1; if (xx < 0 || xx >= 36) continue;
        const float* ip = h1 + (((size_t)b * 36 + yy) * 36 + xx) * 32;
        const float* wp = w + (ky * 3 + kx) * 1024 + co0;  // (3,3,32,32)
        float in[32];
#pragma unroll
        for (int c4 = 0; c4 < 8; ++c4) {
          float4 p = *(const float4*)(ip + c4 * 4);
          in[c4 * 4] = p.x; in[c4 * 4 + 1] = p.y;
          in[c4 * 4 + 2] = p.z; in[c4 * 4 + 3] = p.w;
        }
#pragma unroll
        for (int ci = 0; ci < 32; ++ci)
#pragma unroll
          for (int i = 0; i < 8; ++i)
            acc[i] = fmaf(in[ci], wp[ci * 32 + i], acc[i]);
      }
    }
#pragma unroll
    for (int i = 0; i < 8; ++i) pacc[i] = fmaxf(pacc[i], fmaxf(acc[i], 0.f));
  }
  float* op = h2 + (size_t)t * 32 + co0;
  float4 v0, v1;
  v0.x = pacc[0]; v0.y = pacc[1]; v0.z = pacc[2]; v0.w = pacc[3];
  v1.x = pacc[4]; v1.y = pacc[5]; v1.z = pacc[6]; v1.w = pacc[7];
  *(float4*)op = v0;
  *(float4*)(op + 4) = v1;
}

// ---------------- K3a: dense partial GEMM (K-split) ----------------
#define AST 132
__global__ __launch_bounds__(256) void k_dense_part(
    const float* __restrict__ h2, const float* __restrict__ w,
    float* __restrict__ part) {
  __shared__ float a_lds[32 * AST];
  __shared__ float w_lds[32 * 64];
  int tid = threadIdx.x;
  int n0 = blockIdx.x * 64;   // 14 blocks (last ragged)
  int kc = blockIdx.y;        // 18 K-chunks of 576
  int m0 = (tid >> 4) * 8;
  int nl = (tid & 15) * 4;
  float acc[8][4];
#pragma unroll
  for (int i = 0; i < 8; ++i)
#pragma unroll
    for (int j = 0; j < 4; ++j) acc[i][j] = 0.f;
  for (int kt = 0; kt < 18; ++kt) {
    int kb = kc * 576 + kt * 32;
#pragma unroll
    for (int it = 0; it < 4; ++it) {
      int f = tid + it * 256;  // 0..1023 : 128 m rows x 8 float4
      int ml = f >> 3, kq = f & 7;
      float4 p = *(const float4*)(h2 + (size_t)ml * 10368 + kb + kq * 4);
      a_lds[(kq * 4 + 0) * AST + ml] = p.x;
      a_lds[(kq * 4 + 1) * AST + ml] = p.y;
      a_lds[(kq * 4 + 2) * AST + ml] = p.z;
      a_lds[(kq * 4 + 3) * AST + ml] = p.w;
    }
#pragma unroll
    for (int it = 0; it < 2; ++it) {
      int f = tid + it * 256;  // 0..511 : 32 k rows x 16 float4
      int kr = f >> 4, n4 = (f & 15) * 4;
      float4 p;
      if (n0 + n4 < 864)
        p = *(const float4*)(w + (size_t)(kb + kr) * 864 + n0 + n4);
      else { p.x = 0.f; p.y = 0.f; p.z = 0.f; p.w = 0.f; }
      *(float4*)(w_lds + kr * 64 + n4) = p;
    }
    __syncthreads();
#pragma unroll 4
    for (int k = 0; k < 32; ++k) {
      float4 wv = *(const float4*)(w_lds + k * 64 + nl);
      float4 a0 = *(const float4*)(a_lds + k * AST + m0);
      float4 a1 = *(const float4*)(a_lds + k * AST + m0 + 4);
      float am[8] = {a0.x, a0.y, a0.z, a0.w, a1.x, a1.y, a1.z, a1.w};
#pragma unroll
      for (int i = 0; i < 8; ++i) {
        acc[i][0] = fmaf(am[i], wv.x, acc[i][0]);
        acc[i][1] = fmaf(am[i], wv.y, acc[i][1]);
        acc[i][2] = fmaf(am[i], wv.z, acc[i][2]);
        acc[i][3] = fmaf(am[i], wv.w, acc[i][3]);
      }
    }
    __syncthreads();
  }
  if (n0 + nl < 864) {
#pragma unroll
    for (int i = 0; i < 8; ++i) {
      float4 v;
      v.x = acc[i][0]; v.y = acc[i][1]; v.z = acc[i][2]; v.w = acc[i][3];
      *(float4*)(part + ((size_t)kc * 128 + m0 + i) * 864 + n0 + nl) = v;
    }
  }
}

// ---------------- K3b: reduce K-split partials + bias + relu ----------------
__global__ __launch_bounds__(256) void k_dense_fin(
    const float* __restrict__ part, const float* __restrict__ bias,
    float* __restrict__ filt) {
  int e = blockIdx.x * 256 + threadIdx.x;  // grid 432*256 = 128*864
  float s = bias[e % 864];
#pragma unroll
  for (int kc = 0; kc < 18; ++kc) s += part[(size_t)kc * 110592 + e];
  filt[e] = fmaxf(s, 0.f);
}

// ---------------- K_prep2: per-batch W1eff frags + (block 128) W2 frags ----
// W1eff[k][col]: k<12 -> W1[k][col]; 12<=k<48 -> sum_c fl[h][c]*W1[12+3c+t][col]
// (h=(k-12)/3, t=(k-12)%3); k>=48 -> 0.  Frag: [b][nt 8][ks 2][lane 64][8]:
// k = 32ks + (lane>>4)*8 + j, col = 16nt + (lane&15).
// Block 128: W2 (128x16) frags [ks 4][lane 64][8]: k = 32ks+(lane>>4)*8+j,
// col = lane&15.
__global__ __launch_bounds__(256) void k_prep2(
    const float* __restrict__ filt, const float* __restrict__ W1,
    const float* __restrict__ W2,
    unsigned short* __restrict__ Eh, unsigned short* __restrict__ El,
    unsigned short* __restrict__ W2h, unsigned short* __restrict__ W2l) {
  __shared__ float fl[864];
  int b = blockIdx.x;
  int tid = threadIdx.x;
  if (b == 128) {  // W2 frag prep
    for (int t = tid; t < 2048; t += 256) {
      int j = t & 7, l = (t >> 3) & 63, ks = t >> 9;
      int k = 32 * ks + ((l >> 4) << 3) + j;
      int col = l & 15;
      float v = W2[k * 16 + col];
      unsigned short hh, ll;
      split2(v, hh, ll);
      W2h[t] = hh;
      W2l[t] = ll;
    }
    return;
  }
  for (int f = tid; f < 864; f += 256) fl[f] = filt[(size_t)b * 864 + f];
  __syncthreads();
  int col = tid & 127;
  int k0 = tid >> 7;
  for (int k = k0; k < 64; k += 2) {
    float v;
    if (k < 12) {
      v = W1[k * 128 + col];
    } else if (k < 48) {
      int h = (k - 12) / 3, t = (k - 12) % 3;
      const float* wp = W1 + (12 + t) * 128 + col;  // + c*384 walks rows 12+3c+t
      const float* fp = fl + h * 72;
      float a0 = 0.f, a1 = 0.f, a2 = 0.f, a3 = 0.f;
      for (int c = 0; c < 72; c += 4) {
        a0 = fmaf(fp[c], wp[(size_t)c * 384], a0);
        a1 = fmaf(fp[c + 1], wp[(size_t)(c + 1) * 384], a1);
        a2 = fmaf(fp[c + 2], wp[(size_t)(c + 2) * 384], a2);
        a3 = fmaf(fp[c + 3], wp[(size_t)(c + 3) * 384], a3);
      }
      v = (a0 + a1) + (a2 + a3);
    } else {
      v = 0.f;
    }
    unsigned short hh, ll;
    split2(v, hh, ll);
    int ks = k >> 5, j = k & 7, a4 = (k >> 3) & 3;
    int l = a4 * 16 + (col & 15), nt = col >> 4;
    size_t o = (((size_t)b * 8 + nt) * 2 + ks) * 512 + l * 8 + j;
    Eh[o] = hh;
    El[o] = ll;
  }
}

// ---------------- K4: fused CA update (all-MFMA incl. W2 tail) -------------
// u = P_x @ W1eff (K=48, split-bf16 3-pass, R7-proven), then u exchanged via
// LDS bf16 hi/lo [64px][136hid] and dx = u @ W2 on MFMA (4ks x 3 passes).
// xo prefetched at block start; threefry mask precomputed into LDS.
__global__ __launch_bounds__(256, 4) void k_ca(
    const float* __restrict__ x,
    const unsigned short* __restrict__ Eh, const unsigned short* __restrict__ El,
    const float* __restrict__ B1,
    const unsigned short* __restrict__ W2h, const unsigned short* __restrict__ W2l,
    const float* __restrict__ B2,
    float* __restrict__ xnew, float* __restrict__ aold,
    float* __restrict__ anew) {
  // LDS: stage ia[16][120] f32 @0 (7680) | PAh @7680 (9216) | PAl @16896
  // (9216) -> 26112. Union after main GEMM: Uh @0 [64][136]u16 (17408),
  // Ul @17408 (17408) -> 34816. mskL @34816 (256 f32x64) -> total 35072.
  __shared__ __align__(16) unsigned char S[35072];
  float* ia = (float*)S;
  unsigned short* PAh = (unsigned short*)(S + 7680);
  unsigned short* PAl = (unsigned short*)(S + 16896);
  unsigned short* Uh = (unsigned short*)S;
  unsigned short* Ul = (unsigned short*)(S + 17408);
  float* mskL = (float*)(S + 34816);

  int tid = threadIdx.x;
  int b = blockIdx.y;
  int tx = (blockIdx.x & 7) * 8, ty = (blockIdx.x >> 3) * 8;
  int wv = tid >> 6, lane = tid & 63;
  int lr = lane & 15, lhi = lane >> 4;

  // prefetch W1eff B-frags (global, hides under phase A)
  bf16x8 bh[2][2], bl[2][2];
#pragma unroll
  for (int nt = 0; nt < 2; ++nt)
#pragma unroll
    for (int ks = 0; ks < 2; ++ks) {
      size_t base = (((size_t)b * 8 + (wv * 2 + nt)) * 2 + ks) * 512 + lane * 8;
      bh[nt][ks] = *(const bf16x8*)(Eh + base);
      bl[nt][ks] = *(const bf16x8*)(El + base);
    }
  // prefetch xo for phase D: px = wv*16 + lhi*4 + r, channel lr
  float xo[4];
#pragma unroll
  for (int r = 0; r < 4; ++r) {
    int px = wv * 16 + lhi * 4 + r;
    int gy = ty + (px >> 3), gx = tx + (px & 7);
    xo[r] = x[(((size_t)b * 64 + gy) * 64 + gx) * 16 + lr];
  }

  // ---- phase A: x halo -> ia; threefry -> mskL; zero PA k-pad 48..63
  if (tid < 200) {
    int px_ = tid >> 1, half = tid & 1;
    int hy = px_ / 10, hx = px_ - hy * 10;
    int pp = hy * 12 + hx;
    int gy = ty + hy - 1, gx = tx + hx - 1;
    float4 v0 = {0.f, 0.f, 0.f, 0.f}, v1 = {0.f, 0.f, 0.f, 0.f};
    if (gy >= 0 && gy < 64 && gx >= 0 && gx < 64) {
      const float* xp = x + (((size_t)b * 64 + gy) * 64 + gx) * 16 + half * 8;
      v0 = *(const float4*)xp;
      v1 = *(const float4*)(xp + 4);
    }
    int c0 = half * 8;
    ia[(c0 + 0) * 120 + pp] = v0.x; ia[(c0 + 1) * 120 + pp] = v0.y;
    ia[(c0 + 2) * 120 + pp] = v0.z; ia[(c0 + 3) * 120 + pp] = v0.w;
    ia[(c0 + 4) * 120 + pp] = v1.x; ia[(c0 + 5) * 120 + pp] = v1.y;
    ia[(c0 + 6) * 120 + pp] = v1.z; ia[(c0 + 7) * 120 + pp] = v1.w;
  }
  if (tid >= 200 && tid < 264 - 0) {
    // (gap left intentionally; mask handled below by tid<64 of wave 0 would
    //  collide with halo threads -> use tid 200..263? 256 threads only.)
  }
  {
    // threefry mask: 64 px handled by threads 192..255 (wave 3 low part is
    // busy with halo only for tid<200 -> overlap is fine, separate writes)
    if (tid >= 192) {
      int p = tid - 192;
      int gy = ty + (p >> 3), gx = tx + (p & 7);
      unsigned pix = (unsigned)(b * 4096 + gy * 64 + gx);
      mskL[p] = (tf42_uniform(pix) <= 0.5f) ? 1.f : 0.f;
    }
    const s16x4 z4 = {0, 0, 0, 0};
    if (wv == 2) {
#pragma unroll
      for (int g = 0; g < 4; ++g) *(s16x4*)(PAh + lane * 72 + 48 + 4 * g) = z4;
    }
    if (wv == 3) {
#pragma unroll
      for (int g = 0; g < 4; ++g) *(s16x4*)(PAl + lane * 72 + 48 + 4 * g) = z4;
    }
  }
  __syncthreads();

  // ---- phase P: perception of ch 4wv..4wv+3 -> PA cols 12wv..12wv+11
  {
    int py = lane >> 3, pxx = lane & 7;
    const float* pc0 = ia + (py + 1) * 12 + (pxx + 1);
    unsigned short oh[12], ol[12];
#pragma unroll
    for (int i = 0; i < 4; ++i) {
      const float* pc = pc0 + (wv * 4 + i) * 120;
      float n00 = pc[-13], n01 = pc[-12], n02 = pc[-11];
      float n10 = pc[-1],  n11 = pc[0],   n12 = pc[1];
      float n20 = pc[11],  n21 = pc[12],  n22 = pc[13];
      float pid = n11;
      float psx = ((n02 - n00) + 2.f * (n12 - n10) + (n22 - n20)) * 0.125f;
      float psy = ((n20 - n00) + 2.f * (n21 - n01) + (n22 - n02)) * 0.125f;
      split2(pid, oh[3 * i + 0], ol[3 * i + 0]);
      split2(psx, oh[3 * i + 1], ol[3 * i + 1]);
      split2(psy, oh[3 * i + 2], ol[3 * i + 2]);
    }
    int off = lane * 72 + wv * 12;
#pragma unroll
    for (int g = 0; g < 3; ++g) {
      s16x4 vh = {(short)oh[4 * g], (short)oh[4 * g + 1],
                  (short)oh[4 * g + 2], (short)oh[4 * g + 3]};
      s16x4 vl = {(short)ol[4 * g], (short)ol[4 * g + 1],
                  (short)ol[4 * g + 2], (short)ol[4 * g + 3]};
      *(s16x4*)(PAh + off + 4 * g) = vh;
      *(s16x4*)(PAl + off + 4 * g) = vl;
    }
  }
  __syncthreads();

  // ---- phase M: main GEMM, 2 ks x 4 m x 2 nt x 3 passes
  f32x4 acc[4][2];
#pragma unroll
  for (int m = 0; m < 4; ++m)
#pragma unroll
    for (int nt = 0; nt < 2; ++nt)
      acc[m][nt] = (f32x4){0.f, 0.f, 0.f, 0.f};
#pragma unroll
  for (int ks = 0; ks < 2; ++ks) {
#pragma unroll
    for (int m = 0; m < 4; ++m) {
      int arow = m * 16 + lr;
      bf16x8 pah = *(const bf16x8*)(PAh + arow * 72 + ks * 32 + lhi * 8);
      bf16x8 pal = *(const bf16x8*)(PAl + arow * 72 + ks * 32 + lhi * 8);
#pragma unroll
      for (int nt = 0; nt < 2; ++nt) {
        acc[m][nt] = __builtin_amdgcn_mfma_f32_16x16x32_bf16(
            pah, bh[nt][ks], acc[m][nt], 0, 0, 0);
        acc[m][nt] = __builtin_amdgcn_mfma_f32_16x16x32_bf16(
            pah, bl[nt][ks], acc[m][nt], 0, 0, 0);
        acc[m][nt] = __builtin_amdgcn_mfma_f32_16x16x32_bf16(
            pal, bh[nt][ks], acc[m][nt], 0, 0, 0);
      }
    }
  }
  // prefetch W2 frags (consumed after next barrier)
  bf16x8 ch_[4], cl_[4];
#pragma unroll
  for (int ks = 0; ks < 4; ++ks) {
    ch_[ks] = *(const bf16x8*)(W2h + ks * 512 + lane * 8);
    cl_[ks] = *(const bf16x8*)(W2l + ks * 512 + lane * 8);
  }
  __syncthreads();  // PA dead -> U region may be written

  // ---- u-exchange: u = relu(acc + B1) as bf16 h/l into Uh/Ul [px][hid]
  int d0 = wv * 32;
  float b1v0 = B1[d0 + lr], b1v1 = B1[d0 + 16 + lr];
#pragma unroll
  for (int m = 0; m < 4; ++m)
#pragma unroll
    for (int nt = 0; nt < 2; ++nt) {
      float bv = nt ? b1v1 : b1v0;
      int hid = d0 + nt * 16 + lr;
#pragma unroll
      for (int r = 0; r < 4; ++r) {
        int px = m * 16 + lhi * 4 + r;
        float uval = fmaxf(acc[m][nt][r] + bv, 0.f);
        unsigned short hh, ll;
        split2(uval, hh, ll);
        Uh[px * 136 + hid] = hh;
        Ul[px * 136 + hid] = ll;
      }
    }
  __syncthreads();

  // ---- dx MFMA: wave w computes px tile w (16 px x 16 e), K=128 hid
  f32x4 acc2 = {0.f, 0.f, 0.f, 0.f};
#pragma unroll
  for (int ks = 0; ks < 4; ++ks) {
    bf16x8 uh_ = *(const bf16x8*)(Uh + (wv * 16 + lr) * 136 + ks * 32 + lhi * 8);
    bf16x8 ul_ = *(const bf16x8*)(Ul + (wv * 16 + lr) * 136 + ks * 32 + lhi * 8);
    acc2 = __builtin_amdgcn_mfma_f32_16x16x32_bf16(uh_, ch_[ks], acc2, 0, 0, 0);
    acc2 = __builtin_amdgcn_mfma_f32_16x16x32_bf16(uh_, cl_[ks], acc2, 0, 0, 0);
    acc2 = __builtin_amdgcn_mfma_f32_16x16x32_bf16(ul_, ch_[ks], acc2, 0, 0, 0);
  }

  // ---- phase D: dx + fire mask + write x_new + alphas (lane holds e=lr)
  float b2v = B2[lr];
#pragma unroll
  for (int r = 0; r < 4; ++r) {
    int px = wv * 16 + lhi * 4 + r;
    int gy = ty + (px >> 3), gx = tx + (px & 7);
    float m_ = mskL[px];
    float xn = xo[r] + (acc2[r] + b2v) * m_;
    size_t o = (((size_t)b * 64 + gy) * 64 + gx) * 16 + lr;
    xnew[o] = xn;
    if (lr == 3) {
      unsigned pix = (unsigned)(b * 4096 + gy * 64 + gx);
      aold[pix] = xo[r];
      anew[pix] = xn;
    }
  }
}

// ---------------- K5: living masks + final multiply (in place on d_out) ----
__global__ __launch_bounds__(256) void k_final(
    float* __restrict__ xnew, const float* __restrict__ aold,
    const float* __restrict__ anew) {
  int t = blockIdx.x * 256 + threadIdx.x;  // grid 2048*256 = 524288
  int gx = t & 63, gy = (t >> 6) & 63, b = t >> 12;
  float mo = -1e30f, mn = -1e30f;
  for (int dy = -1; dy <= 1; ++dy) {
    int yy = gy + dy; if (yy < 0 || yy >= 64) continue;
    for (int dx = -1; dx <= 1; ++dx) {
      int xx = gx + dx; if (xx < 0 || xx >= 64) continue;
      int p = b * 4096 + yy * 64 + xx;
      mo = fmaxf(mo, aold[p]);
      mn = fmaxf(mn, anew[p]);
    }
  }
  float live = (mo > 0.1f && mn > 0.1f) ? 1.f : 0.f;
  size_t base = (size_t)t * 16;
#pragma unroll
  for (int c4 = 0; c4 < 4; ++c4) {
    float4 v = *(const float4*)(xnew + base + c4 * 4);
    v.x *= live; v.y *= live; v.z *= live; v.w *= live;
    *(float4*)(xnew + base + c4 * 4) = v;
  }
}

// ---------------- launch ----------------
extern "C" void kernel_launch(void* const* d_in, const int* in_sizes, int n_in,
                              void* d_out, int out_size, void* d_ws, size_t ws_size,
                              hipStream_t stream) {
  const float* x    = (const float*)d_in[0];
  const float* img  = (const float*)d_in[1];
  const float* g1   = (const float*)d_in[2];
  const float* be1  = (const float*)d_in[3];
  const float* m1   = (const float*)d_in[4];
  const float* v1   = (const float*)d_in[5];
  const float* w1c  = (const float*)d_in[6];
  const float* b1c  = (const float*)d_in[7];
  const float* g2   = (const float*)d_in[8];
  const float* be2  = (const float*)d_in[9];
  const float* m2   = (const float*)d_in[10];
  const float* v2   = (const float*)d_in[11];
  const float* w2c  = (const float*)d_in[12];
  const float* b2c  = (const float*)d_in[13];
  const float* dw   = (const float*)d_in[14];
  const float* db   = (const float*)d_in[15];
  const float* uw1  = (const float*)d_in[16];
  const float* ub1  = (const float*)d_in[17];
  const float* uw2  = (const float*)d_in[18];
  const float* ub2  = (const float*)d_in[19];

  char* ws = (char*)d_ws;
  float* h1   = (float*)(ws);                        // 21,233,664 B (dead after dense)
  float* part = h1;                                  // aliased
  float* h2   = (float*)(ws + 21233664);             // 5,308,416 B
  float* filt = (float*)(ws + 26542080);             // 442,368 B
  float* aold = (float*)(ws + 26984448);             // 2,097,152 B
  float* anew = (float*)(ws + 29081600);             // 2,097,152 B
  unsigned short* W2Bh = (unsigned short*)(ws + 31178752);  // 4,096 B
  unsigned short* W2Bl = (unsigned short*)(ws + 31182848);  // 4,096 B
  // W1eff frags alias the (dead by then) h1/part region:
  unsigned short* W1Eh = (unsigned short*)(ws);             // 2,097,152 B
  unsigned short* W1El = (unsigned short*)(ws + 2097152);   // 2,097,152 B
  float* xnew = (float*)d_out;                       // (128,64,64,16) f32

  k_conv1<<<648, 256, 0, stream>>>(img, g1, be1, m1, v1, w1c, b1c,
                                   g2, be2, m2, v2, h1);
  k_conv2<<<dim3(162, 4), 256, 0, stream>>>(h1, w2c, b2c, h2);
  k_dense_part<<<dim3(14, 18), 256, 0, stream>>>(h2, dw, part);
  k_dense_fin<<<432, 256, 0, stream>>>(part, db, filt);
  k_prep2<<<129, 256, 0, stream>>>(filt, uw1, uw2, W1Eh, W1El, W2Bh, W2Bl);
  k_ca<<<dim3(64, 128), 256, 0, stream>>>(x, W1Eh, W1El, ub1, W2Bh, W2Bl, ub2,
                                          xnew, aold, anew);
  k_final<<<2048, 256, 0, stream>>>(xnew, aold, anew);
}

// Round 9
// 273.137 us; speedup vs baseline: 2.6342x; 1.1931x over previous
//
#include <hip/hip_runtime.h>

#define BN_EPS 1e-3f

typedef __attribute__((ext_vector_type(8))) short bf16x8;
typedef __attribute__((ext_vector_type(4))) short s16x4;
typedef __attribute__((ext_vector_type(4))) float f32x4;

// ---------------- bf16 split helpers ----------------
__device__ __forceinline__ unsigned short f2bf_rne(float f) {
  unsigned u = __float_as_uint(f);
  unsigned r = u + 0x7fffu + ((u >> 16) & 1u);
  return (unsigned short)(r >> 16);
}
__device__ __forceinline__ float bf2f(unsigned short h) {
  return __uint_as_float(((unsigned)h) << 16);
}
__device__ __forceinline__ void split2(float v, unsigned short& h, unsigned short& l) {
  h = f2bf_rne(v);
  l = f2bf_rne(v - bf2f(h));
}

// ---------------- threefry2x32 (JAX partitionable path, key=[0,42]) --------
__device__ __forceinline__ unsigned rotl32(unsigned v, int n) {
  return (v << n) | (v >> (32 - n));
}

__device__ __forceinline__ float tf42_uniform(unsigned i) {
  unsigned x0 = 0u, x1 = i;
  const unsigned k0 = 0u, k1 = 42u, k2 = 0u ^ 42u ^ 0x1BD11BDAu;
  x0 += k0; x1 += k1;
#define TFR(r) { x0 += x1; x1 = rotl32(x1, r); x1 ^= x0; }
  TFR(13) TFR(15) TFR(26) TFR(6)
  x0 += k1; x1 += k2 + 1u;
  TFR(17) TFR(29) TFR(16) TFR(24)
  x0 += k2; x1 += k0 + 2u;
  TFR(13) TFR(15) TFR(26) TFR(6)
  x0 += k0; x1 += k1 + 3u;
  TFR(17) TFR(29) TFR(16) TFR(24)
  x0 += k1; x1 += k2 + 4u;
  TFR(13) TFR(15) TFR(26) TFR(6)
  x0 += k2; x1 += k0 + 5u;
#undef TFR
  unsigned bits = x0 ^ x1;
  return __uint_as_float((bits >> 9) | 0x3F800000u) - 1.0f;
}

// ---------------- K1: bn1 + conv1(4->32) + relu + maxpool2 + bn2 -----------
__global__ __launch_bounds__(256) void k_conv1(
    const float* __restrict__ img,
    const float* __restrict__ g1, const float* __restrict__ be1,
    const float* __restrict__ m1, const float* __restrict__ v1,
    const float* __restrict__ w, const float* __restrict__ bias,
    const float* __restrict__ g2, const float* __restrict__ be2,
    const float* __restrict__ m2, const float* __restrict__ v2,
    float* __restrict__ h1) {
  int t = blockIdx.x * 256 + threadIdx.x;  // grid exactly 648*256 = 128*36*36
  int ox = t % 36, oy = (t / 36) % 36, b = t / 1296;
  float s1[4], t1[4];
#pragma unroll
  for (int ci = 0; ci < 4; ++ci) {
    float s = g1[ci] / sqrtf(v1[ci] + BN_EPS);
    s1[ci] = s; t1[ci] = be1[ci] - m1[ci] * s;
  }
  float pacc[32];
#pragma unroll
  for (int co = 0; co < 32; ++co) pacc[co] = 0.f;
#pragma unroll
  for (int sy = 0; sy < 2; ++sy)
#pragma unroll
  for (int sx = 0; sx < 2; ++sx) {
    int iy = 2 * oy + sy, ix = 2 * ox + sx;
    float acc[32];
#pragma unroll
    for (int co = 0; co < 32; ++co) acc[co] = bias[co];
    for (int ky = 0; ky < 3; ++ky) {
      int yy = iy + ky - 1; if (yy < 0 || yy >= 72) continue;
      for (int kx = 0; kx < 3; ++kx) {
        int xx = ix + kx - 1; if (xx < 0 || xx >= 72) continue;
        float4 p = *(const float4*)(img + (((size_t)b * 72 + yy) * 72 + xx) * 4);
        float in0 = p.x * s1[0] + t1[0];
        float in1 = p.y * s1[1] + t1[1];
        float in2 = p.z * s1[2] + t1[2];
        float in3 = p.w * s1[3] + t1[3];
        const float* wp = w + (ky * 3 + kx) * 128;  // (3,3,4,32)
#pragma unroll
        for (int co = 0; co < 32; ++co) acc[co] = fmaf(in0, wp[co], acc[co]);
#pragma unroll
        for (int co = 0; co < 32; ++co) acc[co] = fmaf(in1, wp[32 + co], acc[co]);
#pragma unroll
        for (int co = 0; co < 32; ++co) acc[co] = fmaf(in2, wp[64 + co], acc[co]);
#pragma unroll
        for (int co = 0; co < 32; ++co) acc[co] = fmaf(in3, wp[96 + co], acc[co]);
      }
    }
#pragma unroll
    for (int co = 0; co < 32; ++co)
      pacc[co] = fmaxf(pacc[co], fmaxf(acc[co], 0.f));
  }
#pragma unroll
  for (int co = 0; co < 32; ++co) {
    float s = g2[co] / sqrtf(v2[co] + BN_EPS);
    pacc[co] = pacc[co] * s + (be2[co] - m2[co] * s);
  }
  float* op = h1 + (size_t)t * 32;
#pragma unroll
  for (int c4 = 0; c4 < 8; ++c4) {
    float4 v;
    v.x = pacc[c4 * 4]; v.y = pacc[c4 * 4 + 1];
    v.z = pacc[c4 * 4 + 2]; v.w = pacc[c4 * 4 + 3];
    *(float4*)(op + c4 * 4) = v;
  }
}

// ---------------- K2: conv2(32->32) + relu + maxpool2 (LDS-tiled) ----------
// block = 16x16 conv positions of one batch; input region 18x18x32 staged in
// LDS once (pixel stride 36 f32 -> <=2-way b128 conflicts); all 32 co per
// thread (lane-uniform weights -> s_load broadcast); 2x2 maxpool via shfl.
__global__ __launch_bounds__(256) void k_conv2(
    const float* __restrict__ h1, const float* __restrict__ w,
    const float* __restrict__ bias, float* __restrict__ h2) {
  __shared__ __align__(16) float L[11664];  // 18*18 pixels * 36 f32 stride
  int tid = threadIdx.x;
  int b = blockIdx.y;
  int tY = (blockIdx.x / 3) * 16, tX = (blockIdx.x % 3) * 16;
  for (int idx = tid; idx < 2592; idx += 256) {
    int pix = idx >> 3, c4 = idx & 7;
    int ly = pix / 18, lx = pix - ly * 18;
    int gy = tY - 1 + ly, gx = tX - 1 + lx;
    float4 v = {0.f, 0.f, 0.f, 0.f};
    if (gy >= 0 && gy < 36 && gx >= 0 && gx < 36)
      v = *(const float4*)(h1 + (((size_t)b * 36 + gy) * 36 + gx) * 32 + c4 * 4);
    *(float4*)(L + pix * 36 + c4 * 4) = v;
  }
  __syncthreads();
  int tx = tid & 15, ty = tid >> 4;
  int cy = tY + ty, cx = tX + tx;
  float acc[32];
#pragma unroll
  for (int i = 0; i < 32; ++i) acc[i] = bias[i];
  for (int ky = 0; ky < 3; ++ky)
    for (int kx = 0; kx < 3; ++kx) {
      const float* ip = L + ((ty + ky) * 18 + (tx + kx)) * 36;
      const float* wp = w + (ky * 3 + kx) * 1024;  // (3,3,32,32)
      float in[32];
#pragma unroll
      for (int c4 = 0; c4 < 8; ++c4) {
        float4 p = *(const float4*)(ip + c4 * 4);
        in[c4 * 4] = p.x; in[c4 * 4 + 1] = p.y;
        in[c4 * 4 + 2] = p.z; in[c4 * 4 + 3] = p.w;
      }
#pragma unroll
      for (int ci = 0; ci < 32; ++ci)
#pragma unroll
        for (int co = 0; co < 32; ++co)
          acc[co] = fmaf(in[ci], wp[ci * 32 + co], acc[co]);
    }
#pragma unroll
  for (int i = 0; i < 32; ++i) acc[i] = fmaxf(acc[i], 0.f);
  // 2x2 maxpool: tx pairs = lane^1, ty pairs = lane^16 (both in-wave)
#pragma unroll
  for (int i = 0; i < 32; ++i) {
    float a = fmaxf(acc[i], __shfl_xor(acc[i], 1));
    acc[i] = fmaxf(a, __shfl_xor(a, 16));
  }
  if (((tid & 1) == 0) && ((tid & 16) == 0)) {
    int gy = cy >> 1, gx = cx >> 1;
    if (gy < 18 && gx < 18) {
      float* op = h2 + (((size_t)b * 18 + gy) * 18 + gx) * 32;
#pragma unroll
      for (int c4 = 0; c4 < 8; ++c4) {
        float4 v;
        v.x = acc[c4 * 4]; v.y = acc[c4 * 4 + 1];
        v.z = acc[c4 * 4 + 2]; v.w = acc[c4 * 4 + 3];
        *(float4*)(op + c4 * 4) = v;
      }
    }
  }
}

// ---------------- K3a: dense partial GEMM (K-split) ----------------
#define AST 132
__global__ __launch_bounds__(256) void k_dense_part(
    const float* __restrict__ h2, const float* __restrict__ w,
    float* __restrict__ part) {
  __shared__ float a_lds[32 * AST];
  __shared__ float w_lds[32 * 64];
  int tid = threadIdx.x;
  int n0 = blockIdx.x * 64;   // 14 blocks (last ragged)
  int kc = blockIdx.y;        // 18 K-chunks of 576
  int m0 = (tid >> 4) * 8;
  int nl = (tid & 15) * 4;
  float acc[8][4];
#pragma unroll
  for (int i = 0; i < 8; ++i)
#pragma unroll
    for (int j = 0; j < 4; ++j) acc[i][j] = 0.f;
  for (int kt = 0; kt < 18; ++kt) {
    int kb = kc * 576 + kt * 32;
#pragma unroll
    for (int it = 0; it < 4; ++it) {
      int f = tid + it * 256;  // 0..1023 : 128 m rows x 8 float4
      int ml = f >> 3, kq = f & 7;
      float4 p = *(const float4*)(h2 + (size_t)ml * 10368 + kb + kq * 4);
      a_lds[(kq * 4 + 0) * AST + ml] = p.x;
      a_lds[(kq * 4 + 1) * AST + ml] = p.y;
      a_lds[(kq * 4 + 2) * AST + ml] = p.z;
      a_lds[(kq * 4 + 3) * AST + ml] = p.w;
    }
#pragma unroll
    for (int it = 0; it < 2; ++it) {
      int f = tid + it * 256;  // 0..511 : 32 k rows x 16 float4
      int kr = f >> 4, n4 = (f & 15) * 4;
      float4 p;
      if (n0 + n4 < 864)
        p = *(const float4*)(w + (size_t)(kb + kr) * 864 + n0 + n4);
      else { p.x = 0.f; p.y = 0.f; p.z = 0.f; p.w = 0.f; }
      *(float4*)(w_lds + kr * 64 + n4) = p;
    }
    __syncthreads();
#pragma unroll 4
    for (int k = 0; k < 32; ++k) {
      float4 wv = *(const float4*)(w_lds + k * 64 + nl);
      float4 a0 = *(const float4*)(a_lds + k * AST + m0);
      float4 a1 = *(const float4*)(a_lds + k * AST + m0 + 4);
      float am[8] = {a0.x, a0.y, a0.z, a0.w, a1.x, a1.y, a1.z, a1.w};
#pragma unroll
      for (int i = 0; i < 8; ++i) {
        acc[i][0] = fmaf(am[i], wv.x, acc[i][0]);
        acc[i][1] = fmaf(am[i], wv.y, acc[i][1]);
        acc[i][2] = fmaf(am[i], wv.z, acc[i][2]);
        acc[i][3] = fmaf(am[i], wv.w, acc[i][3]);
      }
    }
    __syncthreads();
  }
  if (n0 + nl < 864) {
#pragma unroll
    for (int i = 0; i < 8; ++i) {
      float4 v;
      v.x = acc[i][0]; v.y = acc[i][1]; v.z = acc[i][2]; v.w = acc[i][3];
      *(float4*)(part + ((size_t)kc * 128 + m0 + i) * 864 + n0 + nl) = v;
    }
  }
}

// ---------------- K3b: reduce K-split partials + bias + relu ----------------
__global__ __launch_bounds__(256) void k_dense_fin(
    const float* __restrict__ part, const float* __restrict__ bias,
    float* __restrict__ filt) {
  int e = blockIdx.x * 256 + threadIdx.x;  // grid 432*256 = 128*864
  float s = bias[e % 864];
#pragma unroll
  for (int kc = 0; kc < 18; ++kc) s += part[(size_t)kc * 110592 + e];
  filt[e] = fmaxf(s, 0.f);
}

// ---------------- K_prep2: per-batch W1eff frags + (block 128) W2 frags ----
__global__ __launch_bounds__(256) void k_prep2(
    const float* __restrict__ filt, const float* __restrict__ W1,
    const float* __restrict__ W2,
    unsigned short* __restrict__ Eh, unsigned short* __restrict__ El,
    unsigned short* __restrict__ W2h, unsigned short* __restrict__ W2l) {
  __shared__ float fl[864];
  int b = blockIdx.x;
  int tid = threadIdx.x;
  if (b == 128) {  // W2 frag prep
    for (int t = tid; t < 2048; t += 256) {
      int j = t & 7, l = (t >> 3) & 63, ks = t >> 9;
      int k = 32 * ks + ((l >> 4) << 3) + j;
      int col = l & 15;
      float v = W2[k * 16 + col];
      unsigned short hh, ll;
      split2(v, hh, ll);
      W2h[t] = hh;
      W2l[t] = ll;
    }
    return;
  }
  for (int f = tid; f < 864; f += 256) fl[f] = filt[(size_t)b * 864 + f];
  __syncthreads();
  int col = tid & 127;
  int k0 = tid >> 7;
  for (int k = k0; k < 64; k += 2) {
    float v;
    if (k < 12) {
      v = W1[k * 128 + col];
    } else if (k < 48) {
      int h = (k - 12) / 3, t = (k - 12) % 3;
      const float* wp = W1 + (12 + t) * 128 + col;  // + c*384 walks rows 12+3c+t
      const float* fp = fl + h * 72;
      float a0 = 0.f, a1 = 0.f, a2 = 0.f, a3 = 0.f;
      for (int c = 0; c < 72; c += 4) {
        a0 = fmaf(fp[c], wp[(size_t)c * 384], a0);
        a1 = fmaf(fp[c + 1], wp[(size_t)(c + 1) * 384], a1);
        a2 = fmaf(fp[c + 2], wp[(size_t)(c + 2) * 384], a2);
        a3 = fmaf(fp[c + 3], wp[(size_t)(c + 3) * 384], a3);
      }
      v = (a0 + a1) + (a2 + a3);
    } else {
      v = 0.f;
    }
    unsigned short hh, ll;
    split2(v, hh, ll);
    int ks = k >> 5, j = k & 7, a4 = (k >> 3) & 3;
    int l = a4 * 16 + (col & 15), nt = col >> 4;
    size_t o = (((size_t)b * 8 + nt) * 2 + ks) * 512 + l * 8 + j;
    Eh[o] = hh;
    El[o] = ll;
  }
}

// ---------------- K4: fused CA update (all-MFMA incl. W2 tail) -------------
__global__ __launch_bounds__(256, 4) void k_ca(
    const float* __restrict__ x,
    const unsigned short* __restrict__ Eh, const unsigned short* __restrict__ El,
    const float* __restrict__ B1,
    const unsigned short* __restrict__ W2h, const unsigned short* __restrict__ W2l,
    const float* __restrict__ B2,
    float* __restrict__ xnew, float* __restrict__ aold,
    float* __restrict__ anew) {
  __shared__ __align__(16) unsigned char S[35072];
  float* ia = (float*)S;
  unsigned short* PAh = (unsigned short*)(S + 7680);
  unsigned short* PAl = (unsigned short*)(S + 16896);
  unsigned short* Uh = (unsigned short*)S;
  unsigned short* Ul = (unsigned short*)(S + 17408);
  float* mskL = (float*)(S + 34816);

  int tid = threadIdx.x;
  int b = blockIdx.y;
  int tx = (blockIdx.x & 7) * 8, ty = (blockIdx.x >> 3) * 8;
  int wv = tid >> 6, lane = tid & 63;
  int lr = lane & 15, lhi = lane >> 4;

  // prefetch W1eff B-frags (global, hides under phase A)
  bf16x8 bh[2][2], bl[2][2];
#pragma unroll
  for (int nt = 0; nt < 2; ++nt)
#pragma unroll
    for (int ks = 0; ks < 2; ++ks) {
      size_t base = (((size_t)b * 8 + (wv * 2 + nt)) * 2 + ks) * 512 + lane * 8;
      bh[nt][ks] = *(const bf16x8*)(Eh + base);
      bl[nt][ks] = *(const bf16x8*)(El + base);
    }
  // prefetch xo for phase D: px = wv*16 + lhi*4 + r, channel lr
  float xo[4];
#pragma unroll
  for (int r = 0; r < 4; ++r) {
    int px = wv * 16 + lhi * 4 + r;
    int gy = ty + (px >> 3), gx = tx + (px & 7);
    xo[r] = x[(((size_t)b * 64 + gy) * 64 + gx) * 16 + lr];
  }

  // ---- phase A: x halo -> ia; threefry -> mskL; zero PA k-pad 48..63
  if (tid < 200) {
    int px_ = tid >> 1, half = tid & 1;
    int hy = px_ / 10, hx = px_ - hy * 10;
    int pp = hy * 12 + hx;
    int gy = ty + hy - 1, gx = tx + hx - 1;
    float4 v0 = {0.f, 0.f, 0.f, 0.f}, v1 = {0.f, 0.f, 0.f, 0.f};
    if (gy >= 0 && gy < 64 && gx >= 0 && gx < 64) {
      const float* xp = x + (((size_t)b * 64 + gy) * 64 + gx) * 16 + half * 8;
      v0 = *(const float4*)xp;
      v1 = *(const float4*)(xp + 4);
    }
    int c0 = half * 8;
    ia[(c0 + 0) * 120 + pp] = v0.x; ia[(c0 + 1) * 120 + pp] = v0.y;
    ia[(c0 + 2) * 120 + pp] = v0.z; ia[(c0 + 3) * 120 + pp] = v0.w;
    ia[(c0 + 4) * 120 + pp] = v1.x; ia[(c0 + 5) * 120 + pp] = v1.y;
    ia[(c0 + 6) * 120 + pp] = v1.z; ia[(c0 + 7) * 120 + pp] = v1.w;
  }
  {
    if (tid >= 192) {
      int p = tid - 192;
      int gy = ty + (p >> 3), gx = tx + (p & 7);
      unsigned pix = (unsigned)(b * 4096 + gy * 64 + gx);
      mskL[p] = (tf42_uniform(pix) <= 0.5f) ? 1.f : 0.f;
    }
    const s16x4 z4 = {0, 0, 0, 0};
    if (wv == 2) {
#pragma unroll
      for (int g = 0; g < 4; ++g) *(s16x4*)(PAh + lane * 72 + 48 + 4 * g) = z4;
    }
    if (wv == 3) {
#pragma unroll
      for (int g = 0; g < 4; ++g) *(s16x4*)(PAl + lane * 72 + 48 + 4 * g) = z4;
    }
  }
  __syncthreads();

  // ---- phase P: perception of ch 4wv..4wv+3 -> PA cols 12wv..12wv+11
  {
    int py = lane >> 3, pxx = lane & 7;
    const float* pc0 = ia + (py + 1) * 12 + (pxx + 1);
    unsigned short oh[12], ol[12];
#pragma unroll
    for (int i = 0; i < 4; ++i) {
      const float* pc = pc0 + (wv * 4 + i) * 120;
      float n00 = pc[-13], n01 = pc[-12], n02 = pc[-11];
      float n10 = pc[-1],  n11 = pc[0],   n12 = pc[1];
      float n20 = pc[11],  n21 = pc[12],  n22 = pc[13];
      float pid = n11;
      float psx = ((n02 - n00) + 2.f * (n12 - n10) + (n22 - n20)) * 0.125f;
      float psy = ((n20 - n00) + 2.f * (n21 - n01) + (n22 - n02)) * 0.125f;
      split2(pid, oh[3 * i + 0], ol[3 * i + 0]);
      split2(psx, oh[3 * i + 1], ol[3 * i + 1]);
      split2(psy, oh[3 * i + 2], ol[3 * i + 2]);
    }
    int off = lane * 72 + wv * 12;
#pragma unroll
    for (int g = 0; g < 3; ++g) {
      s16x4 vh = {(short)oh[4 * g], (short)oh[4 * g + 1],
                  (short)oh[4 * g + 2], (short)oh[4 * g + 3]};
      s16x4 vl = {(short)ol[4 * g], (short)ol[4 * g + 1],
                  (short)ol[4 * g + 2], (short)ol[4 * g + 3]};
      *(s16x4*)(PAh + off + 4 * g) = vh;
      *(s16x4*)(PAl + off + 4 * g) = vl;
    }
  }
  __syncthreads();

  // ---- phase M: main GEMM, 2 ks x 4 m x 2 nt x 3 passes
  f32x4 acc[4][2];
#pragma unroll
  for (int m = 0; m < 4; ++m)
#pragma unroll
    for (int nt = 0; nt < 2; ++nt)
      acc[m][nt] = (f32x4){0.f, 0.f, 0.f, 0.f};
#pragma unroll
  for (int ks = 0; ks < 2; ++ks) {
#pragma unroll
    for (int m = 0; m < 4; ++m) {
      int arow = m * 16 + lr;
      bf16x8 pah = *(const bf16x8*)(PAh + arow * 72 + ks * 32 + lhi * 8);
      bf16x8 pal = *(const bf16x8*)(PAl + arow * 72 + ks * 32 + lhi * 8);
#pragma unroll
      for (int nt = 0; nt < 2; ++nt) {
        acc[m][nt] = __builtin_amdgcn_mfma_f32_16x16x32_bf16(
            pah, bh[nt][ks], acc[m][nt], 0, 0, 0);
        acc[m][nt] = __builtin_amdgcn_mfma_f32_16x16x32_bf16(
            pah, bl[nt][ks], acc[m][nt], 0, 0, 0);
        acc[m][nt] = __builtin_amdgcn_mfma_f32_16x16x32_bf16(
            pal, bh[nt][ks], acc[m][nt], 0, 0, 0);
      }
    }
  }
  // prefetch W2 frags (consumed after next barrier)
  bf16x8 ch_[4], cl_[4];
#pragma unroll
  for (int ks = 0; ks < 4; ++ks) {
    ch_[ks] = *(const bf16x8*)(W2h + ks * 512 + lane * 8);
    cl_[ks] = *(const bf16x8*)(W2l + ks * 512 + lane * 8);
  }
  __syncthreads();  // PA dead -> U region may be written

  // ---- u-exchange: u = relu(acc + B1) as bf16 h/l into Uh/Ul [px][hid]
  int d0 = wv * 32;
  float b1v0 = B1[d0 + lr], b1v1 = B1[d0 + 16 + lr];
#pragma unroll
  for (int m = 0; m < 4; ++m)
#pragma unroll
    for (int nt = 0; nt < 2; ++nt) {
      float bv = nt ? b1v1 : b1v0;
      int hid = d0 + nt * 16 + lr;
#pragma unroll
      for (int r = 0; r < 4; ++r) {
        int px = m * 16 + lhi * 4 + r;
        float uval = fmaxf(acc[m][nt][r] + bv, 0.f);
        unsigned short hh, ll;
        split2(uval, hh, ll);
        Uh[px * 136 + hid] = hh;
        Ul[px * 136 + hid] = ll;
      }
    }
  __syncthreads();

  // ---- dx MFMA: wave w computes px tile w (16 px x 16 e), K=128 hid
  f32x4 acc2 = {0.f, 0.f, 0.f, 0.f};
#pragma unroll
  for (int ks = 0; ks < 4; ++ks) {
    bf16x8 uh_ = *(const bf16x8*)(Uh + (wv * 16 + lr) * 136 + ks * 32 + lhi * 8);
    bf16x8 ul_ = *(const bf16x8*)(Ul + (wv * 16 + lr) * 136 + ks * 32 + lhi * 8);
    acc2 = __builtin_amdgcn_mfma_f32_16x16x32_bf16(uh_, ch_[ks], acc2, 0, 0, 0);
    acc2 = __builtin_amdgcn_mfma_f32_16x16x32_bf16(uh_, cl_[ks], acc2, 0, 0, 0);
    acc2 = __builtin_amdgcn_mfma_f32_16x16x32_bf16(ul_, ch_[ks], acc2, 0, 0, 0);
  }

  // ---- phase D: dx + fire mask + write x_new + alphas (lane holds e=lr)
  float b2v = B2[lr];
#pragma unroll
  for (int r = 0; r < 4; ++r) {
    int px = wv * 16 + lhi * 4 + r;
    int gy = ty + (px >> 3), gx = tx + (px & 7);
    float m_ = mskL[px];
    float xn = xo[r] + (acc2[r] + b2v) * m_;
    size_t o = (((size_t)b * 64 + gy) * 64 + gx) * 16 + lr;
    xnew[o] = xn;
    if (lr == 3) {
      unsigned pix = (unsigned)(b * 4096 + gy * 64 + gx);
      aold[pix] = xo[r];
      anew[pix] = xn;
    }
  }
}

// ---------------- K5: living masks + final multiply (in place on d_out) ----
__global__ __launch_bounds__(256) void k_final(
    float* __restrict__ xnew, const float* __restrict__ aold,
    const float* __restrict__ anew) {
  int t = blockIdx.x * 256 + threadIdx.x;  // grid 2048*256 = 524288
  int gx = t & 63, gy = (t >> 6) & 63, b = t >> 12;
  float mo = -1e30f, mn = -1e30f;
  for (int dy = -1; dy <= 1; ++dy) {
    int yy = gy + dy; if (yy < 0 || yy >= 64) continue;
    for (int dx = -1; dx <= 1; ++dx) {
      int xx = gx + dx; if (xx < 0 || xx >= 64) continue;
      int p = b * 4096 + yy * 64 + xx;
      mo = fmaxf(mo, aold[p]);
      mn = fmaxf(mn, anew[p]);
    }
  }
  float live = (mo > 0.1f && mn > 0.1f) ? 1.f : 0.f;
  size_t base = (size_t)t * 16;
#pragma unroll
  for (int c4 = 0; c4 < 4; ++c4) {
    float4 v = *(const float4*)(xnew + base + c4 * 4);
    v.x *= live; v.y *= live; v.z *= live; v.w *= live;
    *(float4*)(xnew + base + c4 * 4) = v;
  }
}

// ---------------- launch ----------------
extern "C" void kernel_launch(void* const* d_in, const int* in_sizes, int n_in,
                              void* d_out, int out_size, void* d_ws, size_t ws_size,
                              hipStream_t stream) {
  const float* x    = (const float*)d_in[0];
  const float* img  = (const float*)d_in[1];
  const float* g1   = (const float*)d_in[2];
  const float* be1  = (const float*)d_in[3];
  const float* m1   = (const float*)d_in[4];
  const float* v1   = (const float*)d_in[5];
  const float* w1c  = (const float*)d_in[6];
  const float* b1c  = (const float*)d_in[7];
  const float* g2   = (const float*)d_in[8];
  const float* be2  = (const float*)d_in[9];
  const float* m2   = (const float*)d_in[10];
  const float* v2   = (const float*)d_in[11];
  const float* w2c  = (const float*)d_in[12];
  const float* b2c  = (const float*)d_in[13];
  const float* dw   = (const float*)d_in[14];
  const float* db   = (const float*)d_in[15];
  const float* uw1  = (const float*)d_in[16];
  const float* ub1  = (const float*)d_in[17];
  const float* uw2  = (const float*)d_in[18];
  const float* ub2  = (const float*)d_in[19];

  char* ws = (char*)d_ws;
  float* h1   = (float*)(ws);                        // 21,233,664 B (dead after dense)
  float* part = h1;                                  // aliased
  float* h2   = (float*)(ws + 21233664);             // 5,308,416 B
  float* filt = (float*)(ws + 26542080);             // 442,368 B
  float* aold = (float*)(ws + 26984448);             // 2,097,152 B
  float* anew = (float*)(ws + 29081600);             // 2,097,152 B
  unsigned short* W2Bh = (unsigned short*)(ws + 31178752);  // 4,096 B
  unsigned short* W2Bl = (unsigned short*)(ws + 31182848);  // 4,096 B
  // W1eff frags alias the (dead by then) h1/part region:
  unsigned short* W1Eh = (unsigned short*)(ws);             // 2,097,152 B
  unsigned short* W1El = (unsigned short*)(ws + 2097152);   // 2,097,152 B
  float* xnew = (float*)d_out;                       // (128,64,64,16) f32

  k_conv1<<<648, 256, 0, stream>>>(img, g1, be1, m1, v1, w1c, b1c,
                                   g2, be2, m2, v2, h1);
  k_conv2<<<dim3(9, 128), 256, 0, stream>>>(h1, w2c, b2c, h2);
  k_dense_part<<<dim3(14, 18), 256, 0, stream>>>(h2, dw, part);
  k_dense_fin<<<432, 256, 0, stream>>>(part, db, filt);
  k_prep2<<<129, 256, 0, stream>>>(filt, uw1, uw2, W1Eh, W1El, W2Bh, W2Bl);
  k_ca<<<dim3(64, 128), 256, 0, stream>>>(x, W1Eh, W1El, ub1, W2Bh, W2Bl, ub2,
                                          xnew, aold, anew);
  k_final<<<2048, 256, 0, stream>>>(xnew, aold, anew);
}

// Round 10
// 215.406 us; speedup vs baseline: 3.3403x; 1.2680x over previous
//
#include <hip/hip_runtime.h>

#define BN_EPS 1e-3f

typedef __attribute__((ext_vector_type(8))) short bf16x8;
typedef __attribute__((ext_vector_type(4))) short s16x4;
typedef __attribute__((ext_vector_type(4))) float f32x4;

// ---------------- bf16 split helpers ----------------
__device__ __forceinline__ unsigned short f2bf_rne(float f) {
  unsigned u = __float_as_uint(f);
  unsigned r = u + 0x7fffu + ((u >> 16) & 1u);
  return (unsigned short)(r >> 16);
}
__device__ __forceinline__ float bf2f(unsigned short h) {
  return __uint_as_float(((unsigned)h) << 16);
}
__device__ __forceinline__ void split2(float v, unsigned short& h, unsigned short& l) {
  h = f2bf_rne(v);
  l = f2bf_rne(v - bf2f(h));
}

// ---------------- threefry2x32 (JAX partitionable path, key=[0,42]) --------
__device__ __forceinline__ unsigned rotl32(unsigned v, int n) {
  return (v << n) | (v >> (32 - n));
}

__device__ __forceinline__ float tf42_uniform(unsigned i) {
  unsigned x0 = 0u, x1 = i;
  const unsigned k0 = 0u, k1 = 42u, k2 = 0u ^ 42u ^ 0x1BD11BDAu;
  x0 += k0; x1 += k1;
#define TFR(r) { x0 += x1; x1 = rotl32(x1, r); x1 ^= x0; }
  TFR(13) TFR(15) TFR(26) TFR(6)
  x0 += k1; x1 += k2 + 1u;
  TFR(17) TFR(29) TFR(16) TFR(24)
  x0 += k2; x1 += k0 + 2u;
  TFR(13) TFR(15) TFR(26) TFR(6)
  x0 += k0; x1 += k1 + 3u;
  TFR(17) TFR(29) TFR(16) TFR(24)
  x0 += k1; x1 += k2 + 4u;
  TFR(13) TFR(15) TFR(26) TFR(6)
  x0 += k2; x1 += k0 + 5u;
#undef TFR
  unsigned bits = x0 ^ x1;
  return __uint_as_float((bits >> 9) | 0x3F800000u) - 1.0f;
}

// ---------------- K1: bn1 + conv1(4->32) + relu + maxpool2 + bn2 -----------
__global__ __launch_bounds__(256) void k_conv1(
    const float* __restrict__ img,
    const float* __restrict__ g1, const float* __restrict__ be1,
    const float* __restrict__ m1, const float* __restrict__ v1,
    const float* __restrict__ w, const float* __restrict__ bias,
    const float* __restrict__ g2, const float* __restrict__ be2,
    const float* __restrict__ m2, const float* __restrict__ v2,
    float* __restrict__ h1) {
  int t = blockIdx.x * 256 + threadIdx.x;  // grid exactly 648*256 = 128*36*36
  int ox = t % 36, oy = (t / 36) % 36, b = t / 1296;
  float s1[4], t1[4];
#pragma unroll
  for (int ci = 0; ci < 4; ++ci) {
    float s = g1[ci] / sqrtf(v1[ci] + BN_EPS);
    s1[ci] = s; t1[ci] = be1[ci] - m1[ci] * s;
  }
  float pacc[32];
#pragma unroll
  for (int co = 0; co < 32; ++co) pacc[co] = 0.f;
#pragma unroll
  for (int sy = 0; sy < 2; ++sy)
#pragma unroll
  for (int sx = 0; sx < 2; ++sx) {
    int iy = 2 * oy + sy, ix = 2 * ox + sx;
    float acc[32];
#pragma unroll
    for (int co = 0; co < 32; ++co) acc[co] = bias[co];
    for (int ky = 0; ky < 3; ++ky) {
      int yy = iy + ky - 1; if (yy < 0 || yy >= 72) continue;
      for (int kx = 0; kx < 3; ++kx) {
        int xx = ix + kx - 1; if (xx < 0 || xx >= 72) continue;
        float4 p = *(const float4*)(img + (((size_t)b * 72 + yy) * 72 + xx) * 4);
        float in0 = p.x * s1[0] + t1[0];
        float in1 = p.y * s1[1] + t1[1];
        float in2 = p.z * s1[2] + t1[2];
        float in3 = p.w * s1[3] + t1[3];
        const float* wp = w + (ky * 3 + kx) * 128;  // (3,3,4,32)
#pragma unroll
        for (int co = 0; co < 32; ++co) acc[co] = fmaf(in0, wp[co], acc[co]);
#pragma unroll
        for (int co = 0; co < 32; ++co) acc[co] = fmaf(in1, wp[32 + co], acc[co]);
#pragma unroll
        for (int co = 0; co < 32; ++co) acc[co] = fmaf(in2, wp[64 + co], acc[co]);
#pragma unroll
        for (int co = 0; co < 32; ++co) acc[co] = fmaf(in3, wp[96 + co], acc[co]);
      }
    }
#pragma unroll
    for (int co = 0; co < 32; ++co)
      pacc[co] = fmaxf(pacc[co], fmaxf(acc[co], 0.f));
  }
#pragma unroll
  for (int co = 0; co < 32; ++co) {
    float s = g2[co] / sqrtf(v2[co] + BN_EPS);
    pacc[co] = pacc[co] * s + (be2[co] - m2[co] * s);
  }
  float* op = h1 + (size_t)t * 32;
#pragma unroll
  for (int c4 = 0; c4 < 8; ++c4) {
    float4 v;
    v.x = pacc[c4 * 4]; v.y = pacc[c4 * 4 + 1];
    v.z = pacc[c4 * 4 + 2]; v.w = pacc[c4 * 4 + 3];
    *(float4*)(op + c4 * 4) = v;
  }
}

// ---------------- K_prep3: conv2 weights (3,3,32,32) -> bf16 hi/lo B-frags -
// layout [tap 9][nt 2][lane 64][8]: elem = w[tap][ci][co],
// ci = (lane>>4)*8 + j, co = nt*16 + (lane&15).
__global__ __launch_bounds__(256) void k_prep3(
    const float* __restrict__ w, unsigned short* __restrict__ Wh,
    unsigned short* __restrict__ Wl) {
  int t = blockIdx.x * 256 + threadIdx.x;  // grid 36 -> 9216
  int j = t & 7, l = (t >> 3) & 63, nt = (t >> 9) & 1, tap = t >> 10;
  int ci = ((l >> 4) << 3) + j, co = nt * 16 + (l & 15);
  float v = w[tap * 1024 + ci * 32 + co];
  unsigned short hh, ll;
  split2(v, hh, ll);
  Wh[t] = hh;
  Wl[t] = ll;
}

// ---------------- K2: conv2(32->32) + relu + maxpool2 (MFMA) ---------------
// block = 16x16 conv positions; halo 18x18x32 staged as bf16 hi/lo in LDS
// ([324][40] ushort, 16B-aligned frags). Implicit GEMM: 9 taps x K=32,
// split-bf16 3-pass. Wave w: co-half nt=w&1, tile rows (w>>1)*8..+7.
// bias+relu+2x2 pool in registers (px pairs = r pairs, row pairs = mt pairs).
__global__ __launch_bounds__(256, 3) void k_conv2(
    const float* __restrict__ hin,
    const unsigned short* __restrict__ Wch, const unsigned short* __restrict__ Wcl,
    const float* __restrict__ bias, float* __restrict__ h2) {
  __shared__ __align__(16) unsigned short Lh[12960];  // 324 px * 40
  __shared__ __align__(16) unsigned short Ll[12960];
  int tid = threadIdx.x;
  int b = blockIdx.y;
  int tY = (blockIdx.x / 3) * 16, tX = (blockIdx.x % 3) * 16;
  for (int idx = tid; idx < 2592; idx += 256) {
    int pix = idx >> 3, c4 = idx & 7;
    int ly = pix / 18, lx = pix - ly * 18;
    int gy = tY - 1 + ly, gx = tX - 1 + lx;
    float4 v = {0.f, 0.f, 0.f, 0.f};
    if (gy >= 0 && gy < 36 && gx >= 0 && gx < 36)
      v = *(const float4*)(hin + (((size_t)b * 36 + gy) * 36 + gx) * 32 + c4 * 4);
    unsigned short ha, la, hb, lb, hc, lc, hd, ld;
    split2(v.x, ha, la); split2(v.y, hb, lb);
    split2(v.z, hc, lc); split2(v.w, hd, ld);
    s16x4 vh = {(short)ha, (short)hb, (short)hc, (short)hd};
    s16x4 vl = {(short)la, (short)lb, (short)lc, (short)ld};
    *(s16x4*)(Lh + pix * 40 + c4 * 4) = vh;
    *(s16x4*)(Ll + pix * 40 + c4 * 4) = vl;
  }
  __syncthreads();
  int wv = tid >> 6, lane = tid & 63;
  int lr = lane & 15, lhi = lane >> 4;
  int nt = wv & 1, mrow0 = (wv >> 1) * 8;
  bf16x8 wh[9], wl[9];
#pragma unroll
  for (int tap = 0; tap < 9; ++tap) {
    int base = ((tap * 2 + nt) * 64 + lane) * 8;
    wh[tap] = *(const bf16x8*)(Wch + base);
    wl[tap] = *(const bf16x8*)(Wcl + base);
  }
  f32x4 acc[8];
#pragma unroll
  for (int mt = 0; mt < 8; ++mt) acc[mt] = (f32x4){0.f, 0.f, 0.f, 0.f};
#pragma unroll
  for (int mt = 0; mt < 8; ++mt) {
    int row = mrow0 + mt;
#pragma unroll
    for (int tap = 0; tap < 9; ++tap) {
      int dy = tap / 3, dx = tap - dy * 3;
      int pixel = (row + dy) * 18 + (lr + dx);
      bf16x8 ah = *(const bf16x8*)(Lh + pixel * 40 + lhi * 8);
      bf16x8 al = *(const bf16x8*)(Ll + pixel * 40 + lhi * 8);
      acc[mt] = __builtin_amdgcn_mfma_f32_16x16x32_bf16(ah, wh[tap], acc[mt], 0, 0, 0);
      acc[mt] = __builtin_amdgcn_mfma_f32_16x16x32_bf16(ah, wl[tap], acc[mt], 0, 0, 0);
      acc[mt] = __builtin_amdgcn_mfma_f32_16x16x32_bf16(al, wh[tap], acc[mt], 0, 0, 0);
    }
  }
  // bias + relu + 2x2 pool in registers; store pooled
  int co = nt * 16 + lr;
  float bv = bias[co];
#pragma unroll
  for (int a = 0; a < 4; ++a) {
#pragma unroll
    for (int bb = 0; bb < 2; ++bb) {
      float v00 = fmaxf(acc[2 * a][2 * bb] + bv, 0.f);
      float v01 = fmaxf(acc[2 * a][2 * bb + 1] + bv, 0.f);
      float v10 = fmaxf(acc[2 * a + 1][2 * bb] + bv, 0.f);
      float v11 = fmaxf(acc[2 * a + 1][2 * bb + 1] + bv, 0.f);
      float p = fmaxf(fmaxf(v00, v01), fmaxf(v10, v11));
      int gy = (tY >> 1) + (mrow0 >> 1) + a;
      int gx = (tX >> 1) + lhi * 2 + bb;
      if (gy < 18 && gx < 18)
        h2[(((size_t)b * 18 + gy) * 18 + gx) * 32 + co] = p;
    }
  }
}

// ---------------- K3a: dense partial GEMM (K-split) ----------------
#define AST 132
__global__ __launch_bounds__(256) void k_dense_part(
    const float* __restrict__ h2, const float* __restrict__ w,
    float* __restrict__ part) {
  __shared__ float a_lds[32 * AST];
  __shared__ float w_lds[32 * 64];
  int tid = threadIdx.x;
  int n0 = blockIdx.x * 64;   // 14 blocks (last ragged)
  int kc = blockIdx.y;        // 18 K-chunks of 576
  int m0 = (tid >> 4) * 8;
  int nl = (tid & 15) * 4;
  float acc[8][4];
#pragma unroll
  for (int i = 0; i < 8; ++i)
#pragma unroll
    for (int j = 0; j < 4; ++j) acc[i][j] = 0.f;
  for (int kt = 0; kt < 18; ++kt) {
    int kb = kc * 576 + kt * 32;
#pragma unroll
    for (int it = 0; it < 4; ++it) {
      int f = tid + it * 256;  // 0..1023 : 128 m rows x 8 float4
      int ml = f >> 3, kq = f & 7;
      float4 p = *(const float4*)(h2 + (size_t)ml * 10368 + kb + kq * 4);
      a_lds[(kq * 4 + 0) * AST + ml] = p.x;
      a_lds[(kq * 4 + 1) * AST + ml] = p.y;
      a_lds[(kq * 4 + 2) * AST + ml] = p.z;
      a_lds[(kq * 4 + 3) * AST + ml] = p.w;
    }
#pragma unroll
    for (int it = 0; it < 2; ++it) {
      int f = tid + it * 256;  // 0..511 : 32 k rows x 16 float4
      int kr = f >> 4, n4 = (f & 15) * 4;
      float4 p;
      if (n0 + n4 < 864)
        p = *(const float4*)(w + (size_t)(kb + kr) * 864 + n0 + n4);
      else { p.x = 0.f; p.y = 0.f; p.z = 0.f; p.w = 0.f; }
      *(float4*)(w_lds + kr * 64 + n4) = p;
    }
    __syncthreads();
#pragma unroll 4
    for (int k = 0; k < 32; ++k) {
      float4 wv = *(const float4*)(w_lds + k * 64 + nl);
      float4 a0 = *(const float4*)(a_lds + k * AST + m0);
      float4 a1 = *(const float4*)(a_lds + k * AST + m0 + 4);
      float am[8] = {a0.x, a0.y, a0.z, a0.w, a1.x, a1.y, a1.z, a1.w};
#pragma unroll
      for (int i = 0; i < 8; ++i) {
        acc[i][0] = fmaf(am[i], wv.x, acc[i][0]);
        acc[i][1] = fmaf(am[i], wv.y, acc[i][1]);
        acc[i][2] = fmaf(am[i], wv.z, acc[i][2]);
        acc[i][3] = fmaf(am[i], wv.w, acc[i][3]);
      }
    }
    __syncthreads();
  }
  if (n0 + nl < 864) {
#pragma unroll
    for (int i = 0; i < 8; ++i) {
      float4 v;
      v.x = acc[i][0]; v.y = acc[i][1]; v.z = acc[i][2]; v.w = acc[i][3];
      *(float4*)(part + ((size_t)kc * 128 + m0 + i) * 864 + n0 + nl) = v;
    }
  }
}

// ---------------- K3b: reduce K-split partials + bias + relu ----------------
__global__ __launch_bounds__(256) void k_dense_fin(
    const float* __restrict__ part, const float* __restrict__ bias,
    float* __restrict__ filt) {
  int e = blockIdx.x * 256 + threadIdx.x;  // grid 432*256 = 128*864
  float s = bias[e % 864];
#pragma unroll
  for (int kc = 0; kc < 18; ++kc) s += part[(size_t)kc * 110592 + e];
  filt[e] = fmaxf(s, 0.f);
}

// ---------------- K_prep2: per-batch W1eff frags + (block 128) W2 frags ----
__global__ __launch_bounds__(256) void k_prep2(
    const float* __restrict__ filt, const float* __restrict__ W1,
    const float* __restrict__ W2,
    unsigned short* __restrict__ Eh, unsigned short* __restrict__ El,
    unsigned short* __restrict__ W2h, unsigned short* __restrict__ W2l) {
  __shared__ float fl[864];
  int b = blockIdx.x;
  int tid = threadIdx.x;
  if (b == 128) {  // W2 frag prep
    for (int t = tid; t < 2048; t += 256) {
      int j = t & 7, l = (t >> 3) & 63, ks = t >> 9;
      int k = 32 * ks + ((l >> 4) << 3) + j;
      int col = l & 15;
      float v = W2[k * 16 + col];
      unsigned short hh, ll;
      split2(v, hh, ll);
      W2h[t] = hh;
      W2l[t] = ll;
    }
    return;
  }
  for (int f = tid; f < 864; f += 256) fl[f] = filt[(size_t)b * 864 + f];
  __syncthreads();
  int col = tid & 127;
  int k0 = tid >> 7;
  for (int k = k0; k < 64; k += 2) {
    float v;
    if (k < 12) {
      v = W1[k * 128 + col];
    } else if (k < 48) {
      int h = (k - 12) / 3, t = (k - 12) % 3;
      const float* wp = W1 + (12 + t) * 128 + col;  // + c*384 walks rows 12+3c+t
      const float* fp = fl + h * 72;
      float a0 = 0.f, a1 = 0.f, a2 = 0.f, a3 = 0.f;
      for (int c = 0; c < 72; c += 4) {
        a0 = fmaf(fp[c], wp[(size_t)c * 384], a0);
        a1 = fmaf(fp[c + 1], wp[(size_t)(c + 1) * 384], a1);
        a2 = fmaf(fp[c + 2], wp[(size_t)(c + 2) * 384], a2);
        a3 = fmaf(fp[c + 3], wp[(size_t)(c + 3) * 384], a3);
      }
      v = (a0 + a1) + (a2 + a3);
    } else {
      v = 0.f;
    }
    unsigned short hh, ll;
    split2(v, hh, ll);
    int ks = k >> 5, j = k & 7, a4 = (k >> 3) & 3;
    int l = a4 * 16 + (col & 15), nt = col >> 4;
    size_t o = (((size_t)b * 8 + nt) * 2 + ks) * 512 + l * 8 + j;
    Eh[o] = hh;
    El[o] = ll;
  }
}

// ---------------- K4: fused CA update (all-MFMA incl. W2 tail) -------------
__global__ __launch_bounds__(256, 4) void k_ca(
    const float* __restrict__ x,
    const unsigned short* __restrict__ Eh, const unsigned short* __restrict__ El,
    const float* __restrict__ B1,
    const unsigned short* __restrict__ W2h, const unsigned short* __restrict__ W2l,
    const float* __restrict__ B2,
    float* __restrict__ xnew, float* __restrict__ aold,
    float* __restrict__ anew) {
  __shared__ __align__(16) unsigned char S[35072];
  float* ia = (float*)S;
  unsigned short* PAh = (unsigned short*)(S + 7680);
  unsigned short* PAl = (unsigned short*)(S + 16896);
  unsigned short* Uh = (unsigned short*)S;
  unsigned short* Ul = (unsigned short*)(S + 17408);
  float* mskL = (float*)(S + 34816);

  int tid = threadIdx.x;
  int b = blockIdx.y;
  int tx = (blockIdx.x & 7) * 8, ty = (blockIdx.x >> 3) * 8;
  int wv = tid >> 6, lane = tid & 63;
  int lr = lane & 15, lhi = lane >> 4;

  // prefetch W1eff B-frags (global, hides under phase A)
  bf16x8 bh[2][2], bl[2][2];
#pragma unroll
  for (int nt = 0; nt < 2; ++nt)
#pragma unroll
    for (int ks = 0; ks < 2; ++ks) {
      size_t base = (((size_t)b * 8 + (wv * 2 + nt)) * 2 + ks) * 512 + lane * 8;
      bh[nt][ks] = *(const bf16x8*)(Eh + base);
      bl[nt][ks] = *(const bf16x8*)(El + base);
    }
  // prefetch xo for phase D: px = wv*16 + lhi*4 + r, channel lr
  float xo[4];
#pragma unroll
  for (int r = 0; r < 4; ++r) {
    int px = wv * 16 + lhi * 4 + r;
    int gy = ty + (px >> 3), gx = tx + (px & 7);
    xo[r] = x[(((size_t)b * 64 + gy) * 64 + gx) * 16 + lr];
  }

  // ---- phase A: x halo -> ia; threefry -> mskL; zero PA k-pad 48..63
  if (tid < 200) {
    int px_ = tid >> 1, half = tid & 1;
    int hy = px_ / 10, hx = px_ - hy * 10;
    int pp = hy * 12 + hx;
    int gy = ty + hy - 1, gx = tx + hx - 1;
    float4 v0 = {0.f, 0.f, 0.f, 0.f}, v1 = {0.f, 0.f, 0.f, 0.f};
    if (gy >= 0 && gy < 64 && gx >= 0 && gx < 64) {
      const float* xp = x + (((size_t)b * 64 + gy) * 64 + gx) * 16 + half * 8;
      v0 = *(const float4*)xp;
      v1 = *(const float4*)(xp + 4);
    }
    int c0 = half * 8;
    ia[(c0 + 0) * 120 + pp] = v0.x; ia[(c0 + 1) * 120 + pp] = v0.y;
    ia[(c0 + 2) * 120 + pp] = v0.z; ia[(c0 + 3) * 120 + pp] = v0.w;
    ia[(c0 + 4) * 120 + pp] = v1.x; ia[(c0 + 5) * 120 + pp] = v1.y;
    ia[(c0 + 6) * 120 + pp] = v1.z; ia[(c0 + 7) * 120 + pp] = v1.w;
  }
  {
    if (tid >= 192) {
      int p = tid - 192;
      int gy = ty + (p >> 3), gx = tx + (p & 7);
      unsigned pix = (unsigned)(b * 4096 + gy * 64 + gx);
      mskL[p] = (tf42_uniform(pix) <= 0.5f) ? 1.f : 0.f;
    }
    const s16x4 z4 = {0, 0, 0, 0};
    if (wv == 2) {
#pragma unroll
      for (int g = 0; g < 4; ++g) *(s16x4*)(PAh + lane * 72 + 48 + 4 * g) = z4;
    }
    if (wv == 3) {
#pragma unroll
      for (int g = 0; g < 4; ++g) *(s16x4*)(PAl + lane * 72 + 48 + 4 * g) = z4;
    }
  }
  __syncthreads();

  // ---- phase P: perception of ch 4wv..4wv+3 -> PA cols 12wv..12wv+11
  {
    int py = lane >> 3, pxx = lane & 7;
    const float* pc0 = ia + (py + 1) * 12 + (pxx + 1);
    unsigned short oh[12], ol[12];
#pragma unroll
    for (int i = 0; i < 4; ++i) {
      const float* pc = pc0 + (wv * 4 + i) * 120;
      float n00 = pc[-13], n01 = pc[-12], n02 = pc[-11];
      float n10 = pc[-1],  n11 = pc[0],   n12 = pc[1];
      float n20 = pc[11],  n21 = pc[12],  n22 = pc[13];
      float pid = n11;
      float psx = ((n02 - n00) + 2.f * (n12 - n10) + (n22 - n20)) * 0.125f;
      float psy = ((n20 - n00) + 2.f * (n21 - n01) + (n22 - n02)) * 0.125f;
      split2(pid, oh[3 * i + 0], ol[3 * i + 0]);
      split2(psx, oh[3 * i + 1], ol[3 * i + 1]);
      split2(psy, oh[3 * i + 2], ol[3 * i + 2]);
    }
    int off = lane * 72 + wv * 12;
#pragma unroll
    for (int g = 0; g < 3; ++g) {
      s16x4 vh = {(short)oh[4 * g], (short)oh[4 * g + 1],
                  (short)oh[4 * g + 2], (short)oh[4 * g + 3]};
      s16x4 vl = {(short)ol[4 * g], (short)ol[4 * g + 1],
                  (short)ol[4 * g + 2], (short)ol[4 * g + 3]};
      *(s16x4*)(PAh + off + 4 * g) = vh;
      *(s16x4*)(PAl + off + 4 * g) = vl;
    }
  }
  __syncthreads();

  // ---- phase M: main GEMM, 2 ks x 4 m x 2 nt x 3 passes
  f32x4 acc[4][2];
#pragma unroll
  for (int m = 0; m < 4; ++m)
#pragma unroll
    for (int nt = 0; nt < 2; ++nt)
      acc[m][nt] = (f32x4){0.f, 0.f, 0.f, 0.f};
#pragma unroll
  for (int ks = 0; ks < 2; ++ks) {
#pragma unroll
    for (int m = 0; m < 4; ++m) {
      int arow = m * 16 + lr;
      bf16x8 pah = *(const bf16x8*)(PAh + arow * 72 + ks * 32 + lhi * 8);
      bf16x8 pal = *(const bf16x8*)(PAl + arow * 72 + ks * 32 + lhi * 8);
#pragma unroll
      for (int nt = 0; nt < 2; ++nt) {
        acc[m][nt] = __builtin_amdgcn_mfma_f32_16x16x32_bf16(
            pah, bh[nt][ks], acc[m][nt], 0, 0, 0);
        acc[m][nt] = __builtin_amdgcn_mfma_f32_16x16x32_bf16(
            pah, bl[nt][ks], acc[m][nt], 0, 0, 0);
        acc[m][nt] = __builtin_amdgcn_mfma_f32_16x16x32_bf16(
            pal, bh[nt][ks], acc[m][nt], 0, 0, 0);
      }
    }
  }
  // prefetch W2 frags (consumed after next barrier)
  bf16x8 ch_[4], cl_[4];
#pragma unroll
  for (int ks = 0; ks < 4; ++ks) {
    ch_[ks] = *(const bf16x8*)(W2h + ks * 512 + lane * 8);
    cl_[ks] = *(const bf16x8*)(W2l + ks * 512 + lane * 8);
  }
  __syncthreads();  // PA dead -> U region may be written

  // ---- u-exchange: u = relu(acc + B1) as bf16 h/l into Uh/Ul [px][hid]
  int d0 = wv * 32;
  float b1v0 = B1[d0 + lr], b1v1 = B1[d0 + 16 + lr];
#pragma unroll
  for (int m = 0; m < 4; ++m)
#pragma unroll
    for (int nt = 0; nt < 2; ++nt) {
      float bv = nt ? b1v1 : b1v0;
      int hid = d0 + nt * 16 + lr;
#pragma unroll
      for (int r = 0; r < 4; ++r) {
        int px = m * 16 + lhi * 4 + r;
        float uval = fmaxf(acc[m][nt][r] + bv, 0.f);
        unsigned short hh, ll;
        split2(uval, hh, ll);
        Uh[px * 136 + hid] = hh;
        Ul[px * 136 + hid] = ll;
      }
    }
  __syncthreads();

  // ---- dx MFMA: wave w computes px tile w (16 px x 16 e), K=128 hid
  f32x4 acc2 = {0.f, 0.f, 0.f, 0.f};
#pragma unroll
  for (int ks = 0; ks < 4; ++ks) {
    bf16x8 uh_ = *(const bf16x8*)(Uh + (wv * 16 + lr) * 136 + ks * 32 + lhi * 8);
    bf16x8 ul_ = *(const bf16x8*)(Ul + (wv * 16 + lr) * 136 + ks * 32 + lhi * 8);
    acc2 = __builtin_amdgcn_mfma_f32_16x16x32_bf16(uh_, ch_[ks], acc2, 0, 0, 0);
    acc2 = __builtin_amdgcn_mfma_f32_16x16x32_bf16(uh_, cl_[ks], acc2, 0, 0, 0);
    acc2 = __builtin_amdgcn_mfma_f32_16x16x32_bf16(ul_, ch_[ks], acc2, 0, 0, 0);
  }

  // ---- phase D: dx + fire mask + write x_new + alphas (lane holds e=lr)
  float b2v = B2[lr];
#pragma unroll
  for (int r = 0; r < 4; ++r) {
    int px = wv * 16 + lhi * 4 + r;
    int gy = ty + (px >> 3), gx = tx + (px & 7);
    float m_ = mskL[px];
    float xn = xo[r] + (acc2[r] + b2v) * m_;
    size_t o = (((size_t)b * 64 + gy) * 64 + gx) * 16 + lr;
    xnew[o] = xn;
    if (lr == 3) {
      unsigned pix = (unsigned)(b * 4096 + gy * 64 + gx);
      aold[pix] = xo[r];
      anew[pix] = xn;
    }
  }
}

// ---------------- K5: living masks + final multiply (in place on d_out) ----
__global__ __launch_bounds__(256) void k_final(
    float* __restrict__ xnew, const float* __restrict__ aold,
    const float* __restrict__ anew) {
  int t = blockIdx.x * 256 + threadIdx.x;  // grid 2048*256 = 524288
  int gx = t & 63, gy = (t >> 6) & 63, b = t >> 12;
  float mo = -1e30f, mn = -1e30f;
  for (int dy = -1; dy <= 1; ++dy) {
    int yy = gy + dy; if (yy < 0 || yy >= 64) continue;
    for (int dx = -1; dx <= 1; ++dx) {
      int xx = gx + dx; if (xx < 0 || xx >= 64) continue;
      int p = b * 4096 + yy * 64 + xx;
      mo = fmaxf(mo, aold[p]);
      mn = fmaxf(mn, anew[p]);
    }
  }
  float live = (mo > 0.1f && mn > 0.1f) ? 1.f : 0.f;
  size_t base = (size_t)t * 16;
#pragma unroll
  for (int c4 = 0; c4 < 4; ++c4) {
    float4 v = *(const float4*)(xnew + base + c4 * 4);
    v.x *= live; v.y *= live; v.z *= live; v.w *= live;
    *(float4*)(xnew + base + c4 * 4) = v;
  }
}

// ---------------- launch ----------------
extern "C" void kernel_launch(void* const* d_in, const int* in_sizes, int n_in,
                              void* d_out, int out_size, void* d_ws, size_t ws_size,
                              hipStream_t stream) {
  const float* x    = (const float*)d_in[0];
  const float* img  = (const float*)d_in[1];
  const float* g1   = (const float*)d_in[2];
  const float* be1  = (const float*)d_in[3];
  const float* m1   = (const float*)d_in[4];
  const float* v1   = (const float*)d_in[5];
  const float* w1c  = (const float*)d_in[6];
  const float* b1c  = (const float*)d_in[7];
  const float* g2   = (const float*)d_in[8];
  const float* be2  = (const float*)d_in[9];
  const float* m2   = (const float*)d_in[10];
  const float* v2   = (const float*)d_in[11];
  const float* w2c  = (const float*)d_in[12];
  const float* b2c  = (const float*)d_in[13];
  const float* dw   = (const float*)d_in[14];
  const float* db   = (const float*)d_in[15];
  const float* uw1  = (const float*)d_in[16];
  const float* ub1  = (const float*)d_in[17];
  const float* uw2  = (const float*)d_in[18];
  const float* ub2  = (const float*)d_in[19];

  char* ws = (char*)d_ws;
  float* h1   = (float*)(ws);                        // 21,233,664 B (dead after dense)
  float* part = h1;                                  // aliased
  float* h2   = (float*)(ws + 21233664);             // 5,308,416 B
  float* filt = (float*)(ws + 26542080);             // 442,368 B
  float* aold = (float*)(ws + 26984448);             // 2,097,152 B
  float* anew = (float*)(ws + 29081600);             // 2,097,152 B
  unsigned short* W2Bh = (unsigned short*)(ws + 31178752);  // 4,096 B
  unsigned short* W2Bl = (unsigned short*)(ws + 31182848);  // 4,096 B
  unsigned short* Wc2h = (unsigned short*)(ws + 31186944);  // 18,432 B
  unsigned short* Wc2l = (unsigned short*)(ws + 31205376);  // 18,432 B
  // W1eff frags alias the (dead by then) h1/part region:
  unsigned short* W1Eh = (unsigned short*)(ws);             // 2,097,152 B
  unsigned short* W1El = (unsigned short*)(ws + 2097152);   // 2,097,152 B
  float* xnew = (float*)d_out;                       // (128,64,64,16) f32

  k_prep3<<<36, 256, 0, stream>>>(w2c, Wc2h, Wc2l);
  k_conv1<<<648, 256, 0, stream>>>(img, g1, be1, m1, v1, w1c, b1c,
                                   g2, be2, m2, v2, h1);
  k_conv2<<<dim3(9, 128), 256, 0, stream>>>(h1, Wc2h, Wc2l, b2c, h2);
  k_dense_part<<<dim3(14, 18), 256, 0, stream>>>(h2, dw, part);
  k_dense_fin<<<432, 256, 0, stream>>>(part, db, filt);
  k_prep2<<<129, 256, 0, stream>>>(filt, uw1, uw2, W1Eh, W1El, W2Bh, W2Bl);
  k_ca<<<dim3(64, 128), 256, 0, stream>>>(x, W1Eh, W1El, ub1, W2Bh, W2Bl, ub2,
                                          xnew, aold, anew);
  k_final<<<2048, 256, 0, stream>>>(xnew, aold, anew);
}

// Round 11
// 201.160 us; speedup vs baseline: 3.5768x; 1.0708x over previous
//
#include <hip/hip_runtime.h>

#define BN_EPS 1e-3f

typedef __attribute__((ext_vector_type(8))) short bf16x8;
typedef __attribute__((ext_vector_type(4))) short s16x4;
typedef __attribute__((ext_vector_type(4))) float f32x4;

// ---------------- bf16 split helpers ----------------
__device__ __forceinline__ unsigned short f2bf_rne(float f) {
  unsigned u = __float_as_uint(f);
  unsigned r = u + 0x7fffu + ((u >> 16) & 1u);
  return (unsigned short)(r >> 16);
}
__device__ __forceinline__ float bf2f(unsigned short h) {
  return __uint_as_float(((unsigned)h) << 16);
}
__device__ __forceinline__ void split2(float v, unsigned short& h, unsigned short& l) {
  h = f2bf_rne(v);
  l = f2bf_rne(v - bf2f(h));
}
// cheaper exact split: hi = truncated bf16 (bit AND), lo = RNE(v - hi).
// |v-hi| <= 2^-8|v|, lo rounding <= 2^-9|lo| -> total recon err <= 2^-17|v|.
__device__ __forceinline__ void split2t(float v, unsigned short& h, unsigned short& l) {
  unsigned u = __float_as_uint(v);
  float hi = __uint_as_float(u & 0xFFFF0000u);
  h = (unsigned short)(u >> 16);
  l = f2bf_rne(v - hi);
}

// ---------------- threefry2x32 (JAX partitionable path, key=[0,42]) --------
__device__ __forceinline__ unsigned rotl32(unsigned v, int n) {
  return (v << n) | (v >> (32 - n));
}

__device__ __forceinline__ float tf42_uniform(unsigned i) {
  unsigned x0 = 0u, x1 = i;
  const unsigned k0 = 0u, k1 = 42u, k2 = 0u ^ 42u ^ 0x1BD11BDAu;
  x0 += k0; x1 += k1;
#define TFR(r) { x0 += x1; x1 = rotl32(x1, r); x1 ^= x0; }
  TFR(13) TFR(15) TFR(26) TFR(6)
  x0 += k1; x1 += k2 + 1u;
  TFR(17) TFR(29) TFR(16) TFR(24)
  x0 += k2; x1 += k0 + 2u;
  TFR(13) TFR(15) TFR(26) TFR(6)
  x0 += k0; x1 += k1 + 3u;
  TFR(17) TFR(29) TFR(16) TFR(24)
  x0 += k1; x1 += k2 + 4u;
  TFR(13) TFR(15) TFR(26) TFR(6)
  x0 += k2; x1 += k0 + 5u;
#undef TFR
  unsigned bits = x0 ^ x1;
  return __uint_as_float((bits >> 9) | 0x3F800000u) - 1.0f;
}

// ---------------- K1: bn1 + conv1(4->32) + relu + maxpool2 + bn2 -----------
__global__ __launch_bounds__(256) void k_conv1(
    const float* __restrict__ img,
    const float* __restrict__ g1, const float* __restrict__ be1,
    const float* __restrict__ m1, const float* __restrict__ v1,
    const float* __restrict__ w, const float* __restrict__ bias,
    const float* __restrict__ g2, const float* __restrict__ be2,
    const float* __restrict__ m2, const float* __restrict__ v2,
    float* __restrict__ h1) {
  int t = blockIdx.x * 256 + threadIdx.x;  // grid exactly 648*256 = 128*36*36
  int ox = t % 36, oy = (t / 36) % 36, b = t / 1296;
  float s1[4], t1[4];
#pragma unroll
  for (int ci = 0; ci < 4; ++ci) {
    float s = g1[ci] / sqrtf(v1[ci] + BN_EPS);
    s1[ci] = s; t1[ci] = be1[ci] - m1[ci] * s;
  }
  float pacc[32];
#pragma unroll
  for (int co = 0; co < 32; ++co) pacc[co] = 0.f;
#pragma unroll
  for (int sy = 0; sy < 2; ++sy)
#pragma unroll
  for (int sx = 0; sx < 2; ++sx) {
    int iy = 2 * oy + sy, ix = 2 * ox + sx;
    float acc[32];
#pragma unroll
    for (int co = 0; co < 32; ++co) acc[co] = bias[co];
    for (int ky = 0; ky < 3; ++ky) {
      int yy = iy + ky - 1; if (yy < 0 || yy >= 72) continue;
      for (int kx = 0; kx < 3; ++kx) {
        int xx = ix + kx - 1; if (xx < 0 || xx >= 72) continue;
        float4 p = *(const float4*)(img + (((size_t)b * 72 + yy) * 72 + xx) * 4);
        float in0 = p.x * s1[0] + t1[0];
        float in1 = p.y * s1[1] + t1[1];
        float in2 = p.z * s1[2] + t1[2];
        float in3 = p.w * s1[3] + t1[3];
        const float* wp = w + (ky * 3 + kx) * 128;  // (3,3,4,32)
#pragma unroll
        for (int co = 0; co < 32; ++co) acc[co] = fmaf(in0, wp[co], acc[co]);
#pragma unroll
        for (int co = 0; co < 32; ++co) acc[co] = fmaf(in1, wp[32 + co], acc[co]);
#pragma unroll
        for (int co = 0; co < 32; ++co) acc[co] = fmaf(in2, wp[64 + co], acc[co]);
#pragma unroll
        for (int co = 0; co < 32; ++co) acc[co] = fmaf(in3, wp[96 + co], acc[co]);
      }
    }
#pragma unroll
    for (int co = 0; co < 32; ++co)
      pacc[co] = fmaxf(pacc[co], fmaxf(acc[co], 0.f));
  }
#pragma unroll
  for (int co = 0; co < 32; ++co) {
    float s = g2[co] / sqrtf(v2[co] + BN_EPS);
    pacc[co] = pacc[co] * s + (be2[co] - m2[co] * s);
  }
  float* op = h1 + (size_t)t * 32;
#pragma unroll
  for (int c4 = 0; c4 < 8; ++c4) {
    float4 v;
    v.x = pacc[c4 * 4]; v.y = pacc[c4 * 4 + 1];
    v.z = pacc[c4 * 4 + 2]; v.w = pacc[c4 * 4 + 3];
    *(float4*)(op + c4 * 4) = v;
  }
}

// ---------------- K_prep3: conv2 weights (3,3,32,32) -> bf16 hi/lo B-frags -
// layout [tap 9][nt 2][lane 64][8]: elem = w[tap][ci][co],
// ci = (lane>>4)*8 + j, co = nt*16 + (lane&15).
__global__ __launch_bounds__(256) void k_prep3(
    const float* __restrict__ w, unsigned short* __restrict__ Wh,
    unsigned short* __restrict__ Wl) {
  int t = blockIdx.x * 256 + threadIdx.x;  // grid 36 -> 9216
  int j = t & 7, l = (t >> 3) & 63, nt = (t >> 9) & 1, tap = t >> 10;
  int ci = ((l >> 4) << 3) + j, co = nt * 16 + (l & 15);
  float v = w[tap * 1024 + ci * 32 + co];
  unsigned short hh, ll;
  split2(v, hh, ll);
  Wh[t] = hh;
  Wl[t] = ll;
}

// ---------------- K2: conv2(32->32) + relu + maxpool2 (MFMA) ---------------
__global__ __launch_bounds__(256, 3) void k_conv2(
    const float* __restrict__ hin,
    const unsigned short* __restrict__ Wch, const unsigned short* __restrict__ Wcl,
    const float* __restrict__ bias, float* __restrict__ h2) {
  __shared__ __align__(16) unsigned short Lh[12960];  // 324 px * 40
  __shared__ __align__(16) unsigned short Ll[12960];
  int tid = threadIdx.x;
  int b = blockIdx.y;
  int tY = (blockIdx.x / 3) * 16, tX = (blockIdx.x % 3) * 16;
  for (int idx = tid; idx < 2592; idx += 256) {
    int pix = idx >> 3, c4 = idx & 7;
    int ly = pix / 18, lx = pix - ly * 18;
    int gy = tY - 1 + ly, gx = tX - 1 + lx;
    float4 v = {0.f, 0.f, 0.f, 0.f};
    if (gy >= 0 && gy < 36 && gx >= 0 && gx < 36)
      v = *(const float4*)(hin + (((size_t)b * 36 + gy) * 36 + gx) * 32 + c4 * 4);
    unsigned short ha, la, hb, lb, hc, lc, hd, ld;
    split2(v.x, ha, la); split2(v.y, hb, lb);
    split2(v.z, hc, lc); split2(v.w, hd, ld);
    s16x4 vh = {(short)ha, (short)hb, (short)hc, (short)hd};
    s16x4 vl = {(short)la, (short)lb, (short)lc, (short)ld};
    *(s16x4*)(Lh + pix * 40 + c4 * 4) = vh;
    *(s16x4*)(Ll + pix * 40 + c4 * 4) = vl;
  }
  __syncthreads();
  int wv = tid >> 6, lane = tid & 63;
  int lr = lane & 15, lhi = lane >> 4;
  int nt = wv & 1, mrow0 = (wv >> 1) * 8;
  bf16x8 wh[9], wl[9];
#pragma unroll
  for (int tap = 0; tap < 9; ++tap) {
    int base = ((tap * 2 + nt) * 64 + lane) * 8;
    wh[tap] = *(const bf16x8*)(Wch + base);
    wl[tap] = *(const bf16x8*)(Wcl + base);
  }
  f32x4 acc[8];
#pragma unroll
  for (int mt = 0; mt < 8; ++mt) acc[mt] = (f32x4){0.f, 0.f, 0.f, 0.f};
#pragma unroll
  for (int mt = 0; mt < 8; ++mt) {
    int row = mrow0 + mt;
#pragma unroll
    for (int tap = 0; tap < 9; ++tap) {
      int dy = tap / 3, dx = tap - dy * 3;
      int pixel = (row + dy) * 18 + (lr + dx);
      bf16x8 ah = *(const bf16x8*)(Lh + pixel * 40 + lhi * 8);
      bf16x8 al = *(const bf16x8*)(Ll + pixel * 40 + lhi * 8);
      acc[mt] = __builtin_amdgcn_mfma_f32_16x16x32_bf16(ah, wh[tap], acc[mt], 0, 0, 0);
      acc[mt] = __builtin_amdgcn_mfma_f32_16x16x32_bf16(ah, wl[tap], acc[mt], 0, 0, 0);
      acc[mt] = __builtin_amdgcn_mfma_f32_16x16x32_bf16(al, wh[tap], acc[mt], 0, 0, 0);
    }
  }
  // bias + relu + 2x2 pool in registers; store pooled
  int co = nt * 16 + lr;
  float bv = bias[co];
#pragma unroll
  for (int a = 0; a < 4; ++a) {
#pragma unroll
    for (int bb = 0; bb < 2; ++bb) {
      float v00 = fmaxf(acc[2 * a][2 * bb] + bv, 0.f);
      float v01 = fmaxf(acc[2 * a][2 * bb + 1] + bv, 0.f);
      float v10 = fmaxf(acc[2 * a + 1][2 * bb] + bv, 0.f);
      float v11 = fmaxf(acc[2 * a + 1][2 * bb + 1] + bv, 0.f);
      float p = fmaxf(fmaxf(v00, v01), fmaxf(v10, v11));
      int gy = (tY >> 1) + (mrow0 >> 1) + a;
      int gx = (tX >> 1) + lhi * 2 + bb;
      if (gy < 18 && gx < 18)
        h2[(((size_t)b * 18 + gy) * 18 + gx) * 32 + co] = p;
    }
  }
}

// ---------------- K3a: dense partial GEMM (K-split, MFMA split-bf16) -------
// part[kc][m][n] over K-chunk kc (576 k). Per 32-k step: stage A(128x32) and
// B^T(64x32) as bf16 hi/lo in LDS (stride 40 ushort -> <=2-way conflicts);
// wave wv owns cols n0+wv*16..+15; 8 m-tiles x 3 split passes.
__global__ __launch_bounds__(256) void k_dense_part(
    const float* __restrict__ h2, const float* __restrict__ w,
    float* __restrict__ part) {
  __shared__ __align__(16) unsigned short Ah[128 * 40];
  __shared__ __align__(16) unsigned short Al[128 * 40];
  __shared__ __align__(16) unsigned short Bh[64 * 40];
  __shared__ __align__(16) unsigned short Bl[64 * 40];
  int tid = threadIdx.x;
  int n0 = blockIdx.x * 64;   // 14 blocks (last ragged)
  int kc = blockIdx.y;        // 18 K-chunks of 576
  int wv = tid >> 6, lane = tid & 63;
  int lr = lane & 15, lhi = lane >> 4;
  f32x4 acc[8];
#pragma unroll
  for (int m = 0; m < 8; ++m) acc[m] = (f32x4){0.f, 0.f, 0.f, 0.f};
  for (int kt = 0; kt < 18; ++kt) {
    int kb = kc * 576 + kt * 32;
    if (kt) __syncthreads();  // prior compute reads done before re-staging
#pragma unroll
    for (int it = 0; it < 4; ++it) {
      int f = tid + it * 256;  // 0..1023 : 128 m rows x 8 float4
      int ml = f >> 3, kq = f & 7;
      float4 p = *(const float4*)(h2 + (size_t)ml * 10368 + kb + kq * 4);
      unsigned short h0, l0, h1, l1, h2_, l2_, h3, l3;
      split2t(p.x, h0, l0); split2t(p.y, h1, l1);
      split2t(p.z, h2_, l2_); split2t(p.w, h3, l3);
      s16x4 vh = {(short)h0, (short)h1, (short)h2_, (short)h3};
      s16x4 vl = {(short)l0, (short)l1, (short)l2_, (short)l3};
      *(s16x4*)(Ah + ml * 40 + kq * 4) = vh;
      *(s16x4*)(Al + ml * 40 + kq * 4) = vl;
    }
#pragma unroll
    for (int it = 0; it < 2; ++it) {
      int f = tid + it * 256;  // 0..511 : 32 k rows x 16 float4
      int kr = f >> 4, n4 = (f & 15) * 4;
      float4 p = {0.f, 0.f, 0.f, 0.f};
      if (n0 + n4 < 864)
        p = *(const float4*)(w + (size_t)(kb + kr) * 864 + n0 + n4);
      unsigned short hh, ll;
      split2t(p.x, hh, ll); Bh[(n4 + 0) * 40 + kr] = hh; Bl[(n4 + 0) * 40 + kr] = ll;
      split2t(p.y, hh, ll); Bh[(n4 + 1) * 40 + kr] = hh; Bl[(n4 + 1) * 40 + kr] = ll;
      split2t(p.z, hh, ll); Bh[(n4 + 2) * 40 + kr] = hh; Bl[(n4 + 2) * 40 + kr] = ll;
      split2t(p.w, hh, ll); Bh[(n4 + 3) * 40 + kr] = hh; Bl[(n4 + 3) * 40 + kr] = ll;
    }
    __syncthreads();
    bf16x8 bh_ = *(const bf16x8*)(Bh + (wv * 16 + lr) * 40 + lhi * 8);
    bf16x8 bl_ = *(const bf16x8*)(Bl + (wv * 16 + lr) * 40 + lhi * 8);
#pragma unroll
    for (int m = 0; m < 8; ++m) {
      bf16x8 ah = *(const bf16x8*)(Ah + (m * 16 + lr) * 40 + lhi * 8);
      bf16x8 al = *(const bf16x8*)(Al + (m * 16 + lr) * 40 + lhi * 8);
      acc[m] = __builtin_amdgcn_mfma_f32_16x16x32_bf16(ah, bh_, acc[m], 0, 0, 0);
      acc[m] = __builtin_amdgcn_mfma_f32_16x16x32_bf16(ah, bl_, acc[m], 0, 0, 0);
      acc[m] = __builtin_amdgcn_mfma_f32_16x16x32_bf16(al, bh_, acc[m], 0, 0, 0);
    }
  }
  int n = n0 + wv * 16 + lr;
  if (n < 864) {
#pragma unroll
    for (int m = 0; m < 8; ++m) {
#pragma unroll
      for (int r = 0; r < 4; ++r) {
        int mm = m * 16 + lhi * 4 + r;
        part[((size_t)kc * 128 + mm) * 864 + n] = acc[m][r];
      }
    }
  }
}

// ---------------- K3b: reduce K-split partials + bias + relu ----------------
__global__ __launch_bounds__(256) void k_dense_fin(
    const float* __restrict__ part, const float* __restrict__ bias,
    float* __restrict__ filt) {
  int e = blockIdx.x * 256 + threadIdx.x;  // grid 432*256 = 128*864
  float s = bias[e % 864];
#pragma unroll
  for (int kc = 0; kc < 18; ++kc) s += part[(size_t)kc * 110592 + e];
  filt[e] = fmaxf(s, 0.f);
}

// ---------------- K_prep2: per-batch W1eff frags + (block 128) W2 frags ----
__global__ __launch_bounds__(256) void k_prep2(
    const float* __restrict__ filt, const float* __restrict__ W1,
    const float* __restrict__ W2,
    unsigned short* __restrict__ Eh, unsigned short* __restrict__ El,
    unsigned short* __restrict__ W2h, unsigned short* __restrict__ W2l) {
  __shared__ float fl[864];
  int b = blockIdx.x;
  int tid = threadIdx.x;
  if (b == 128) {  // W2 frag prep
    for (int t = tid; t < 2048; t += 256) {
      int j = t & 7, l = (t >> 3) & 63, ks = t >> 9;
      int k = 32 * ks + ((l >> 4) << 3) + j;
      int col = l & 15;
      float v = W2[k * 16 + col];
      unsigned short hh, ll;
      split2(v, hh, ll);
      W2h[t] = hh;
      W2l[t] = ll;
    }
    return;
  }
  for (int f = tid; f < 864; f += 256) fl[f] = filt[(size_t)b * 864 + f];
  __syncthreads();
  int col = tid & 127;
  int k0 = tid >> 7;
  for (int k = k0; k < 64; k += 2) {
    float v;
    if (k < 12) {
      v = W1[k * 128 + col];
    } else if (k < 48) {
      int h = (k - 12) / 3, t = (k - 12) % 3;
      const float* wp = W1 + (12 + t) * 128 + col;  // + c*384 walks rows 12+3c+t
      const float* fp = fl + h * 72;
      float a0 = 0.f, a1 = 0.f, a2 = 0.f, a3 = 0.f;
      for (int c = 0; c < 72; c += 4) {
        a0 = fmaf(fp[c], wp[(size_t)c * 384], a0);
        a1 = fmaf(fp[c + 1], wp[(size_t)(c + 1) * 384], a1);
        a2 = fmaf(fp[c + 2], wp[(size_t)(c + 2) * 384], a2);
        a3 = fmaf(fp[c + 3], wp[(size_t)(c + 3) * 384], a3);
      }
      v = (a0 + a1) + (a2 + a3);
    } else {
      v = 0.f;
    }
    unsigned short hh, ll;
    split2(v, hh, ll);
    int ks = k >> 5, j = k & 7, a4 = (k >> 3) & 3;
    int l = a4 * 16 + (col & 15), nt = col >> 4;
    size_t o = (((size_t)b * 8 + nt) * 2 + ks) * 512 + l * 8 + j;
    Eh[o] = hh;
    El[o] = ll;
  }
}

// ---------------- K4: fused CA update (all-MFMA incl. W2 tail) -------------
__global__ __launch_bounds__(256, 4) void k_ca(
    const float* __restrict__ x,
    const unsigned short* __restrict__ Eh, const unsigned short* __restrict__ El,
    const float* __restrict__ B1,
    const unsigned short* __restrict__ W2h, const unsigned short* __restrict__ W2l,
    const float* __restrict__ B2,
    float* __restrict__ xnew, float* __restrict__ aold,
    float* __restrict__ anew) {
  __shared__ __align__(16) unsigned char S[35072];
  float* ia = (float*)S;
  unsigned short* PAh = (unsigned short*)(S + 7680);
  unsigned short* PAl = (unsigned short*)(S + 16896);
  unsigned short* Uh = (unsigned short*)S;
  unsigned short* Ul = (unsigned short*)(S + 17408);
  float* mskL = (float*)(S + 34816);

  int tid = threadIdx.x;
  int b = blockIdx.y;
  int tx = (blockIdx.x & 7) * 8, ty = (blockIdx.x >> 3) * 8;
  int wv = tid >> 6, lane = tid & 63;
  int lr = lane & 15, lhi = lane >> 4;

  // prefetch W1eff B-frags (global, hides under phase A)
  bf16x8 bh[2][2], bl[2][2];
#pragma unroll
  for (int nt = 0; nt < 2; ++nt)
#pragma unroll
    for (int ks = 0; ks < 2; ++ks) {
      size_t base = (((size_t)b * 8 + (wv * 2 + nt)) * 2 + ks) * 512 + lane * 8;
      bh[nt][ks] = *(const bf16x8*)(Eh + base);
      bl[nt][ks] = *(const bf16x8*)(El + base);
    }
  // prefetch xo for phase D: px = wv*16 + lhi*4 + r, channel lr
  float xo[4];
#pragma unroll
  for (int r = 0; r < 4; ++r) {
    int px = wv * 16 + lhi * 4 + r;
    int gy = ty + (px >> 3), gx = tx + (px & 7);
    xo[r] = x[(((size_t)b * 64 + gy) * 64 + gx) * 16 + lr];
  }

  // ---- phase A: x halo -> ia; threefry -> mskL; zero PA k-pad 48..63
  if (tid < 200) {
    int px_ = tid >> 1, half = tid & 1;
    int hy = px_ / 10, hx = px_ - hy * 10;
    int pp = hy * 12 + hx;
    int gy = ty + hy - 1, gx = tx + hx - 1;
    float4 v0 = {0.f, 0.f, 0.f, 0.f}, v1 = {0.f, 0.f, 0.f, 0.f};
    if (gy >= 0 && gy < 64 && gx >= 0 && gx < 64) {
      const float* xp = x + (((size_t)b * 64 + gy) * 64 + gx) * 16 + half * 8;
      v0 = *(const float4*)xp;
      v1 = *(const float4*)(xp + 4);
    }
    int c0 = half * 8;
    ia[(c0 + 0) * 120 + pp] = v0.x; ia[(c0 + 1) * 120 + pp] = v0.y;
    ia[(c0 + 2) * 120 + pp] = v0.z; ia[(c0 + 3) * 120 + pp] = v0.w;
    ia[(c0 + 4) * 120 + pp] = v1.x; ia[(c0 + 5) * 120 + pp] = v1.y;
    ia[(c0 + 6) * 120 + pp] = v1.z; ia[(c0 + 7) * 120 + pp] = v1.w;
  }
  {
    if (tid >= 192) {
      int p = tid - 192;
      int gy = ty + (p >> 3), gx = tx + (p & 7);
      unsigned pix = (unsigned)(b * 4096 + gy * 64 + gx);
      mskL[p] = (tf42_uniform(pix) <= 0.5f) ? 1.f : 0.f;
    }
    const s16x4 z4 = {0, 0, 0, 0};
    if (wv == 2) {
#pragma unroll
      for (int g = 0; g < 4; ++g) *(s16x4*)(PAh + lane * 72 + 48 + 4 * g) = z4;
    }
    if (wv == 3) {
#pragma unroll
      for (int g = 0; g < 4; ++g) *(s16x4*)(PAl + lane * 72 + 48 + 4 * g) = z4;
    }
  }
  __syncthreads();

  // ---- phase P: perception of ch 4wv..4wv+3 -> PA cols 12wv..12wv+11
  {
    int py = lane >> 3, pxx = lane & 7;
    const float* pc0 = ia + (py + 1) * 12 + (pxx + 1);
    unsigned short oh[12], ol[12];
#pragma unroll
    for (int i = 0; i < 4; ++i) {
      const float* pc = pc0 + (wv * 4 + i) * 120;
      float n00 = pc[-13], n01 = pc[-12], n02 = pc[-11];
      float n10 = pc[-1],  n11 = pc[0],   n12 = pc[1];
      float n20 = pc[11],  n21 = pc[12],  n22 = pc[13];
      float pid = n11;
      float psx = ((n02 - n00) + 2.f * (n12 - n10) + (n22 - n20)) * 0.125f;
      float psy = ((n20 - n00) + 2.f * (n21 - n01) + (n22 - n02)) * 0.125f;
      split2(pid, oh[3 * i + 0], ol[3 * i + 0]);
      split2(psx, oh[3 * i + 1], ol[3 * i + 1]);
      split2(psy, oh[3 * i + 2], ol[3 * i + 2]);
    }
    int off = lane * 72 + wv * 12;
#pragma unroll
    for (int g = 0; g < 3; ++g) {
      s16x4 vh = {(short)oh[4 * g], (short)oh[4 * g + 1],
                  (short)oh[4 * g + 2], (short)oh[4 * g + 3]};
      s16x4 vl = {(short)ol[4 * g], (short)ol[4 * g + 1],
                  (short)ol[4 * g + 2], (short)ol[4 * g + 3]};
      *(s16x4*)(PAh + off + 4 * g) = vh;
      *(s16x4*)(PAl + off + 4 * g) = vl;
    }
  }
  __syncthreads();

  // ---- phase M: main GEMM, 2 ks x 4 m x 2 nt x 3 passes
  f32x4 acc[4][2];
#pragma unroll
  for (int m = 0; m < 4; ++m)
#pragma unroll
    for (int nt = 0; nt < 2; ++nt)
      acc[m][nt] = (f32x4){0.f, 0.f, 0.f, 0.f};
#pragma unroll
  for (int ks = 0; ks < 2; ++ks) {
#pragma unroll
    for (int m = 0; m < 4; ++m) {
      int arow = m * 16 + lr;
      bf16x8 pah = *(const bf16x8*)(PAh + arow * 72 + ks * 32 + lhi * 8);
      bf16x8 pal = *(const bf16x8*)(PAl + arow * 72 + ks * 32 + lhi * 8);
#pragma unroll
      for (int nt = 0; nt < 2; ++nt) {
        acc[m][nt] = __builtin_amdgcn_mfma_f32_16x16x32_bf16(
            pah, bh[nt][ks], acc[m][nt], 0, 0, 0);
        acc[m][nt] = __builtin_amdgcn_mfma_f32_16x16x32_bf16(
            pah, bl[nt][ks], acc[m][nt], 0, 0, 0);
        acc[m][nt] = __builtin_amdgcn_mfma_f32_16x16x32_bf16(
            pal, bh[nt][ks], acc[m][nt], 0, 0, 0);
      }
    }
  }
  // prefetch W2 frags (consumed after next barrier)
  bf16x8 ch_[4], cl_[4];
#pragma unroll
  for (int ks = 0; ks < 4; ++ks) {
    ch_[ks] = *(const bf16x8*)(W2h + ks * 512 + lane * 8);
    cl_[ks] = *(const bf16x8*)(W2l + ks * 512 + lane * 8);
  }
  __syncthreads();  // PA dead -> U region may be written

  // ---- u-exchange: u = relu(acc + B1) as bf16 h/l into Uh/Ul [px][hid]
  int d0 = wv * 32;
  float b1v0 = B1[d0 + lr], b1v1 = B1[d0 + 16 + lr];
#pragma unroll
  for (int m = 0; m < 4; ++m)
#pragma unroll
    for (int nt = 0; nt < 2; ++nt) {
      float bv = nt ? b1v1 : b1v0;
      int hid = d0 + nt * 16 + lr;
#pragma unroll
      for (int r = 0; r < 4; ++r) {
        int px = m * 16 + lhi * 4 + r;
        float uval = fmaxf(acc[m][nt][r] + bv, 0.f);
        unsigned short hh, ll;
        split2(uval, hh, ll);
        Uh[px * 136 + hid] = hh;
        Ul[px * 136 + hid] = ll;
      }
    }
  __syncthreads();

  // ---- dx MFMA: wave w computes px tile w (16 px x 16 e), K=128 hid
  f32x4 acc2 = {0.f, 0.f, 0.f, 0.f};
#pragma unroll
  for (int ks = 0; ks < 4; ++ks) {
    bf16x8 uh_ = *(const bf16x8*)(Uh + (wv * 16 + lr) * 136 + ks * 32 + lhi * 8);
    bf16x8 ul_ = *(const bf16x8*)(Ul + (wv * 16 + lr) * 136 + ks * 32 + lhi * 8);
    acc2 = __builtin_amdgcn_mfma_f32_16x16x32_bf16(uh_, ch_[ks], acc2, 0, 0, 0);
    acc2 = __builtin_amdgcn_mfma_f32_16x16x32_bf16(uh_, cl_[ks], acc2, 0, 0, 0);
    acc2 = __builtin_amdgcn_mfma_f32_16x16x32_bf16(ul_, ch_[ks], acc2, 0, 0, 0);
  }

  // ---- phase D: dx + fire mask + write x_new + alphas (lane holds e=lr)
  float b2v = B2[lr];
#pragma unroll
  for (int r = 0; r < 4; ++r) {
    int px = wv * 16 + lhi * 4 + r;
    int gy = ty + (px >> 3), gx = tx + (px & 7);
    float m_ = mskL[px];
    float xn = xo[r] + (acc2[r] + b2v) * m_;
    size_t o = (((size_t)b * 64 + gy) * 64 + gx) * 16 + lr;
    xnew[o] = xn;
    if (lr == 3) {
      unsigned pix = (unsigned)(b * 4096 + gy * 64 + gx);
      aold[pix] = xo[r];
      anew[pix] = xn;
    }
  }
}

// ---------------- K5: living masks + final multiply (in place on d_out) ----
__global__ __launch_bounds__(256) void k_final(
    float* __restrict__ xnew, const float* __restrict__ aold,
    const float* __restrict__ anew) {
  int t = blockIdx.x * 256 + threadIdx.x;  // grid 2048*256 = 524288
  int gx = t & 63, gy = (t >> 6) & 63, b = t >> 12;
  float mo = -1e30f, mn = -1e30f;
  for (int dy = -1; dy <= 1; ++dy) {
    int yy = gy + dy; if (yy < 0 || yy >= 64) continue;
    for (int dx = -1; dx <= 1; ++dx) {
      int xx = gx + dx; if (xx < 0 || xx >= 64) continue;
      int p = b * 4096 + yy * 64 + xx;
      mo = fmaxf(mo, aold[p]);
      mn = fmaxf(mn, anew[p]);
    }
  }
  float live = (mo > 0.1f && mn > 0.1f) ? 1.f : 0.f;
  size_t base = (size_t)t * 16;
#pragma unroll
  for (int c4 = 0; c4 < 4; ++c4) {
    float4 v = *(const float4*)(xnew + base + c4 * 4);
    v.x *= live; v.y *= live; v.z *= live; v.w *= live;
    *(float4*)(xnew + base + c4 * 4) = v;
  }
}

// ---------------- launch ----------------
extern "C" void kernel_launch(void* const* d_in, const int* in_sizes, int n_in,
                              void* d_out, int out_size, void* d_ws, size_t ws_size,
                              hipStream_t stream) {
  const float* x    = (const float*)d_in[0];
  const float* img  = (const float*)d_in[1];
  const float* g1   = (const float*)d_in[2];
  const float* be1  = (const float*)d_in[3];
  const float* m1   = (const float*)d_in[4];
  const float* v1   = (const float*)d_in[5];
  const float* w1c  = (const float*)d_in[6];
  const float* b1c  = (const float*)d_in[7];
  const float* g2   = (const float*)d_in[8];
  const float* be2  = (const float*)d_in[9];
  const float* m2   = (const float*)d_in[10];
  const float* v2   = (const float*)d_in[11];
  const float* w2c  = (const float*)d_in[12];
  const float* b2c  = (const float*)d_in[13];
  const float* dw   = (const float*)d_in[14];
  const float* db   = (const float*)d_in[15];
  const float* uw1  = (const float*)d_in[16];
  const float* ub1  = (const float*)d_in[17];
  const float* uw2  = (const float*)d_in[18];
  const float* ub2  = (const float*)d_in[19];

  char* ws = (char*)d_ws;
  float* h1   = (float*)(ws);                        // 21,233,664 B (dead after dense)
  float* part = h1;                                  // aliased
  float* h2   = (float*)(ws + 21233664);             // 5,308,416 B
  float* filt = (float*)(ws + 26542080);             // 442,368 B
  float* aold = (float*)(ws + 26984448);             // 2,097,152 B
  float* anew = (float*)(ws + 29081600);             // 2,097,152 B
  unsigned short* W2Bh = (unsigned short*)(ws + 31178752);  // 4,096 B
  unsigned short* W2Bl = (unsigned short*)(ws + 31182848);  // 4,096 B
  unsigned short* Wc2h = (unsigned short*)(ws + 31186944);  // 18,432 B
  unsigned short* Wc2l = (unsigned short*)(ws + 31205376);  // 18,432 B
  // W1eff frags alias the (dead by then) h1/part region:
  unsigned short* W1Eh = (unsigned short*)(ws);             // 2,097,152 B
  unsigned short* W1El = (unsigned short*)(ws + 2097152);   // 2,097,152 B
  float* xnew = (float*)d_out;                       // (128,64,64,16) f32

  k_prep3<<<36, 256, 0, stream>>>(w2c, Wc2h, Wc2l);
  k_conv1<<<648, 256, 0, stream>>>(img, g1, be1, m1, v1, w1c, b1c,
                                   g2, be2, m2, v2, h1);
  k_conv2<<<dim3(9, 128), 256, 0, stream>>>(h1, Wc2h, Wc2l, b2c, h2);
  k_dense_part<<<dim3(14, 18), 256, 0, stream>>>(h2, dw, part);
  k_dense_fin<<<432, 256, 0, stream>>>(part, db, filt);
  k_prep2<<<129, 256, 0, stream>>>(filt, uw1, uw2, W1Eh, W1El, W2Bh, W2Bl);
  k_ca<<<dim3(64, 128), 256, 0, stream>>>(x, W1Eh, W1El, ub1, W2Bh, W2Bl, ub2,
                                          xnew, aold, anew);
  k_final<<<2048, 256, 0, stream>>>(xnew, aold, anew);
}

// Round 12
// 181.436 us; speedup vs baseline: 3.9656x; 1.1087x over previous
//
#include <hip/hip_runtime.h>

#define BN_EPS 1e-3f

typedef __attribute__((ext_vector_type(8))) short bf16x8;
typedef __attribute__((ext_vector_type(4))) short s16x4;
typedef __attribute__((ext_vector_type(4))) float f32x4;

// ---------------- bf16 split helpers ----------------
__device__ __forceinline__ unsigned short f2bf_rne(float f) {
  unsigned u = __float_as_uint(f);
  unsigned r = u + 0x7fffu + ((u >> 16) & 1u);
  return (unsigned short)(r >> 16);
}
__device__ __forceinline__ float bf2f(unsigned short h) {
  return __uint_as_float(((unsigned)h) << 16);
}
__device__ __forceinline__ void split2(float v, unsigned short& h, unsigned short& l) {
  h = f2bf_rne(v);
  l = f2bf_rne(v - bf2f(h));
}
// cheaper exact split: hi = truncated bf16 (bit AND), lo = RNE(v - hi).
__device__ __forceinline__ void split2t(float v, unsigned short& h, unsigned short& l) {
  unsigned u = __float_as_uint(v);
  float hi = __uint_as_float(u & 0xFFFF0000u);
  h = (unsigned short)(u >> 16);
  l = f2bf_rne(v - hi);
}

// ---------------- threefry2x32 (JAX partitionable path, key=[0,42]) --------
__device__ __forceinline__ unsigned rotl32(unsigned v, int n) {
  return (v << n) | (v >> (32 - n));
}

__device__ __forceinline__ float tf42_uniform(unsigned i) {
  unsigned x0 = 0u, x1 = i;
  const unsigned k0 = 0u, k1 = 42u, k2 = 0u ^ 42u ^ 0x1BD11BDAu;
  x0 += k0; x1 += k1;
#define TFR(r) { x0 += x1; x1 = rotl32(x1, r); x1 ^= x0; }
  TFR(13) TFR(15) TFR(26) TFR(6)
  x0 += k1; x1 += k2 + 1u;
  TFR(17) TFR(29) TFR(16) TFR(24)
  x0 += k2; x1 += k0 + 2u;
  TFR(13) TFR(15) TFR(26) TFR(6)
  x0 += k0; x1 += k1 + 3u;
  TFR(17) TFR(29) TFR(16) TFR(24)
  x0 += k1; x1 += k2 + 4u;
  TFR(13) TFR(15) TFR(26) TFR(6)
  x0 += k2; x1 += k0 + 5u;
#undef TFR
  unsigned bits = x0 ^ x1;
  return __uint_as_float((bits >> 9) | 0x3F800000u) - 1.0f;
}

// ---------------- K_prep4: conv1 weights (3,3,4,32) -> bf16 hi/lo B-frags --
// layout [ks 3][nt 2][lane 64][8]: k = 32ks + (lane>>4)*8 + j;
// tap = k>>3, ci = k&7; valid iff tap<9 && ci<4; elem = w[tap][ci][co],
// co = nt*16 + (lane&15). Invalid -> 0 (so A side never needs masking).
__global__ __launch_bounds__(256) void k_prep4(
    const float* __restrict__ w, unsigned short* __restrict__ Wh,
    unsigned short* __restrict__ Wl) {
  int t = blockIdx.x * 256 + threadIdx.x;  // grid 12 -> 3072
  int j = t & 7, l = (t >> 3) & 63, nt = (t >> 9) & 1, ks = t >> 10;
  int k = 32 * ks + ((l >> 4) << 3) + j;
  int tap = k >> 3, ci = k & 7;
  float v = (tap < 9 && ci < 4) ? w[tap * 128 + ci * 32 + nt * 16 + (l & 15)] : 0.f;
  unsigned short hh, ll;
  split2(v, hh, ll);
  Wh[t] = hh;
  Wl[t] = ll;
}

// ---------------- K1: bn1 + conv1(4->32) + relu + maxpool2 + bn2 (MFMA) ----
// block = 16x16 conv positions of the 72x72 map; halo 18x18x4 staged
// bn1-applied as bf16 hi/lo [324][8] (ch 4..7 zero; zero-padded in bn space
// = reference 'SAME' semantics). Implicit GEMM K = tap*8+ci (3 ksteps,
// invalid-K B-frags are zero). In-register 2x2 pool, bn2 on store.
__global__ __launch_bounds__(256) void k_conv1(
    const float* __restrict__ img,
    const float* __restrict__ g1, const float* __restrict__ be1,
    const float* __restrict__ m1, const float* __restrict__ v1,
    const unsigned short* __restrict__ Wc1h, const unsigned short* __restrict__ Wc1l,
    const float* __restrict__ bias,
    const float* __restrict__ g2, const float* __restrict__ be2,
    const float* __restrict__ m2, const float* __restrict__ v2,
    float* __restrict__ h1) {
  __shared__ __align__(16) unsigned short Lh[2592];  // 324 px * 8
  __shared__ __align__(16) unsigned short Ll[2592];
  int tid = threadIdx.x;
  int b = blockIdx.y;
  int tY = (blockIdx.x / 5) * 16, tX = (blockIdx.x % 5) * 16;
  float s1[4], t1[4];
#pragma unroll
  for (int ci = 0; ci < 4; ++ci) {
    float s = g1[ci] / sqrtf(v1[ci] + BN_EPS);
    s1[ci] = s; t1[ci] = be1[ci] - m1[ci] * s;
  }
  const s16x4 z4 = {0, 0, 0, 0};
  for (int idx = tid; idx < 324; idx += 256) {
    int ly = idx / 18, lx = idx - ly * 18;
    int gy = tY - 1 + ly, gx = tX - 1 + lx;
    float4 v = {0.f, 0.f, 0.f, 0.f};
    if (gy >= 0 && gy < 72 && gx >= 0 && gx < 72) {
      v = *(const float4*)(img + (((size_t)b * 72 + gy) * 72 + gx) * 4);
      v.x = v.x * s1[0] + t1[0];
      v.y = v.y * s1[1] + t1[1];
      v.z = v.z * s1[2] + t1[2];
      v.w = v.w * s1[3] + t1[3];
    }
    unsigned short ha, la, hb, lb, hc, lc, hd, ld;
    split2t(v.x, ha, la); split2t(v.y, hb, lb);
    split2t(v.z, hc, lc); split2t(v.w, hd, ld);
    s16x4 vh = {(short)ha, (short)hb, (short)hc, (short)hd};
    s16x4 vl = {(short)la, (short)lb, (short)lc, (short)ld};
    *(s16x4*)(Lh + idx * 8) = vh;
    *(s16x4*)(Lh + idx * 8 + 4) = z4;
    *(s16x4*)(Ll + idx * 8) = vl;
    *(s16x4*)(Ll + idx * 8 + 4) = z4;
  }
  __syncthreads();
  int wv = tid >> 6, lane = tid & 63;
  int lr = lane & 15, lhi = lane >> 4;
  int nt = wv & 1, mrow0 = (wv >> 1) * 8;
  bf16x8 wh[3], wl[3];
#pragma unroll
  for (int ks = 0; ks < 3; ++ks) {
    int base = ((ks * 2 + nt) * 64 + lane) * 8;
    wh[ks] = *(const bf16x8*)(Wc1h + base);
    wl[ks] = *(const bf16x8*)(Wc1l + base);
  }
  f32x4 acc[8];
#pragma unroll
  for (int mt = 0; mt < 8; ++mt) acc[mt] = (f32x4){0.f, 0.f, 0.f, 0.f};
#pragma unroll
  for (int ks = 0; ks < 3; ++ks) {
    int tap = 4 * ks + lhi;
    int tc = tap > 8 ? 8 : tap;  // invalid taps have B == 0, A value irrelevant
    int dy = tc / 3, dx = tc - 3 * dy;
#pragma unroll
    for (int mt = 0; mt < 8; ++mt) {
      int row = mrow0 + mt;
      int px = (row + dy) * 18 + lr + dx;
      bf16x8 ah = *(const bf16x8*)(Lh + px * 8);
      bf16x8 al = *(const bf16x8*)(Ll + px * 8);
      acc[mt] = __builtin_amdgcn_mfma_f32_16x16x32_bf16(ah, wh[ks], acc[mt], 0, 0, 0);
      acc[mt] = __builtin_amdgcn_mfma_f32_16x16x32_bf16(ah, wl[ks], acc[mt], 0, 0, 0);
      acc[mt] = __builtin_amdgcn_mfma_f32_16x16x32_bf16(al, wh[ks], acc[mt], 0, 0, 0);
    }
  }
  // bias + relu + 2x2 pool in registers; bn2 on store
  int co = nt * 16 + lr;
  float bv = bias[co];
  float s2 = g2[co] / sqrtf(v2[co] + BN_EPS);
  float t2 = be2[co] - m2[co] * s2;
#pragma unroll
  for (int a = 0; a < 4; ++a) {
#pragma unroll
    for (int bb = 0; bb < 2; ++bb) {
      float v00 = fmaxf(acc[2 * a][2 * bb] + bv, 0.f);
      float v01 = fmaxf(acc[2 * a][2 * bb + 1] + bv, 0.f);
      float v10 = fmaxf(acc[2 * a + 1][2 * bb] + bv, 0.f);
      float v11 = fmaxf(acc[2 * a + 1][2 * bb + 1] + bv, 0.f);
      float p = fmaxf(fmaxf(v00, v01), fmaxf(v10, v11));
      int gy = (tY >> 1) + (mrow0 >> 1) + a;
      int gx = (tX >> 1) + lhi * 2 + bb;
      if (gy < 36 && gx < 36)
        h1[(((size_t)b * 36 + gy) * 36 + gx) * 32 + co] = p * s2 + t2;
    }
  }
}

// ---------------- K_prep3: conv2 weights (3,3,32,32) -> bf16 hi/lo B-frags -
__global__ __launch_bounds__(256) void k_prep3(
    const float* __restrict__ w, unsigned short* __restrict__ Wh,
    unsigned short* __restrict__ Wl) {
  int t = blockIdx.x * 256 + threadIdx.x;  // grid 36 -> 9216
  int j = t & 7, l = (t >> 3) & 63, nt = (t >> 9) & 1, tap = t >> 10;
  int ci = ((l >> 4) << 3) + j, co = nt * 16 + (l & 15);
  float v = w[tap * 1024 + ci * 32 + co];
  unsigned short hh, ll;
  split2(v, hh, ll);
  Wh[t] = hh;
  Wl[t] = ll;
}

// ---------------- K2: conv2(32->32) + relu + maxpool2 (MFMA) ---------------
__global__ __launch_bounds__(256, 3) void k_conv2(
    const float* __restrict__ hin,
    const unsigned short* __restrict__ Wch, const unsigned short* __restrict__ Wcl,
    const float* __restrict__ bias, float* __restrict__ h2) {
  __shared__ __align__(16) unsigned short Lh[12960];  // 324 px * 40
  __shared__ __align__(16) unsigned short Ll[12960];
  int tid = threadIdx.x;
  int b = blockIdx.y;
  int tY = (blockIdx.x / 3) * 16, tX = (blockIdx.x % 3) * 16;
  for (int idx = tid; idx < 2592; idx += 256) {
    int pix = idx >> 3, c4 = idx & 7;
    int ly = pix / 18, lx = pix - ly * 18;
    int gy = tY - 1 + ly, gx = tX - 1 + lx;
    float4 v = {0.f, 0.f, 0.f, 0.f};
    if (gy >= 0 && gy < 36 && gx >= 0 && gx < 36)
      v = *(const float4*)(hin + (((size_t)b * 36 + gy) * 36 + gx) * 32 + c4 * 4);
    unsigned short ha, la, hb, lb, hc, lc, hd, ld;
    split2t(v.x, ha, la); split2t(v.y, hb, lb);
    split2t(v.z, hc, lc); split2t(v.w, hd, ld);
    s16x4 vh = {(short)ha, (short)hb, (short)hc, (short)hd};
    s16x4 vl = {(short)la, (short)lb, (short)lc, (short)ld};
    *(s16x4*)(Lh + pix * 40 + c4 * 4) = vh;
    *(s16x4*)(Ll + pix * 40 + c4 * 4) = vl;
  }
  __syncthreads();
  int wv = tid >> 6, lane = tid & 63;
  int lr = lane & 15, lhi = lane >> 4;
  int nt = wv & 1, mrow0 = (wv >> 1) * 8;
  bf16x8 wh[9], wl[9];
#pragma unroll
  for (int tap = 0; tap < 9; ++tap) {
    int base = ((tap * 2 + nt) * 64 + lane) * 8;
    wh[tap] = *(const bf16x8*)(Wch + base);
    wl[tap] = *(const bf16x8*)(Wcl + base);
  }
  f32x4 acc[8];
#pragma unroll
  for (int mt = 0; mt < 8; ++mt) acc[mt] = (f32x4){0.f, 0.f, 0.f, 0.f};
#pragma unroll
  for (int mt = 0; mt < 8; ++mt) {
    int row = mrow0 + mt;
#pragma unroll
    for (int tap = 0; tap < 9; ++tap) {
      int dy = tap / 3, dx = tap - dy * 3;
      int pixel = (row + dy) * 18 + (lr + dx);
      bf16x8 ah = *(const bf16x8*)(Lh + pixel * 40 + lhi * 8);
      bf16x8 al = *(const bf16x8*)(Ll + pixel * 40 + lhi * 8);
      acc[mt] = __builtin_amdgcn_mfma_f32_16x16x32_bf16(ah, wh[tap], acc[mt], 0, 0, 0);
      acc[mt] = __builtin_amdgcn_mfma_f32_16x16x32_bf16(ah, wl[tap], acc[mt], 0, 0, 0);
      acc[mt] = __builtin_amdgcn_mfma_f32_16x16x32_bf16(al, wh[tap], acc[mt], 0, 0, 0);
    }
  }
  // bias + relu + 2x2 pool in registers; store pooled
  int co = nt * 16 + lr;
  float bv = bias[co];
#pragma unroll
  for (int a = 0; a < 4; ++a) {
#pragma unroll
    for (int bb = 0; bb < 2; ++bb) {
      float v00 = fmaxf(acc[2 * a][2 * bb] + bv, 0.f);
      float v01 = fmaxf(acc[2 * a][2 * bb + 1] + bv, 0.f);
      float v10 = fmaxf(acc[2 * a + 1][2 * bb] + bv, 0.f);
      float v11 = fmaxf(acc[2 * a + 1][2 * bb + 1] + bv, 0.f);
      float p = fmaxf(fmaxf(v00, v01), fmaxf(v10, v11));
      int gy = (tY >> 1) + (mrow0 >> 1) + a;
      int gx = (tX >> 1) + lhi * 2 + bb;
      if (gy < 18 && gx < 18)
        h2[(((size_t)b * 18 + gy) * 18 + gx) * 32 + co] = p;
    }
  }
}

// ---------------- K3a: dense partial GEMM (K-split, MFMA split-bf16) -------
__global__ __launch_bounds__(256) void k_dense_part(
    const float* __restrict__ h2, const float* __restrict__ w,
    float* __restrict__ part) {
  __shared__ __align__(16) unsigned short Ah[128 * 40];
  __shared__ __align__(16) unsigned short Al[128 * 40];
  __shared__ __align__(16) unsigned short Bh[64 * 40];
  __shared__ __align__(16) unsigned short Bl[64 * 40];
  int tid = threadIdx.x;
  int n0 = blockIdx.x * 64;   // 14 blocks (last ragged)
  int kc = blockIdx.y;        // 18 K-chunks of 576
  int wv = tid >> 6, lane = tid & 63;
  int lr = lane & 15, lhi = lane >> 4;
  f32x4 acc[8];
#pragma unroll
  for (int m = 0; m < 8; ++m) acc[m] = (f32x4){0.f, 0.f, 0.f, 0.f};
  for (int kt = 0; kt < 18; ++kt) {
    int kb = kc * 576 + kt * 32;
    if (kt) __syncthreads();  // prior compute reads done before re-staging
#pragma unroll
    for (int it = 0; it < 4; ++it) {
      int f = tid + it * 256;  // 0..1023 : 128 m rows x 8 float4
      int ml = f >> 3, kq = f & 7;
      float4 p = *(const float4*)(h2 + (size_t)ml * 10368 + kb + kq * 4);
      unsigned short h0, l0, h1, l1, h2_, l2_, h3, l3;
      split2t(p.x, h0, l0); split2t(p.y, h1, l1);
      split2t(p.z, h2_, l2_); split2t(p.w, h3, l3);
      s16x4 vh = {(short)h0, (short)h1, (short)h2_, (short)h3};
      s16x4 vl = {(short)l0, (short)l1, (short)l2_, (short)l3};
      *(s16x4*)(Ah + ml * 40 + kq * 4) = vh;
      *(s16x4*)(Al + ml * 40 + kq * 4) = vl;
    }
#pragma unroll
    for (int it = 0; it < 2; ++it) {
      int f = tid + it * 256;  // 0..511 : 32 k rows x 16 float4
      int kr = f >> 4, n4 = (f & 15) * 4;
      float4 p = {0.f, 0.f, 0.f, 0.f};
      if (n0 + n4 < 864)
        p = *(const float4*)(w + (size_t)(kb + kr) * 864 + n0 + n4);
      unsigned short hh, ll;
      split2t(p.x, hh, ll); Bh[(n4 + 0) * 40 + kr] = hh; Bl[(n4 + 0) * 40 + kr] = ll;
      split2t(p.y, hh, ll); Bh[(n4 + 1) * 40 + kr] = hh; Bl[(n4 + 1) * 40 + kr] = ll;
      split2t(p.z, hh, ll); Bh[(n4 + 2) * 40 + kr] = hh; Bl[(n4 + 2) * 40 + kr] = ll;
      split2t(p.w, hh, ll); Bh[(n4 + 3) * 40 + kr] = hh; Bl[(n4 + 3) * 40 + kr] = ll;
    }
    __syncthreads();
    bf16x8 bh_ = *(const bf16x8*)(Bh + (wv * 16 + lr) * 40 + lhi * 8);
    bf16x8 bl_ = *(const bf16x8*)(Bl + (wv * 16 + lr) * 40 + lhi * 8);
#pragma unroll
    for (int m = 0; m < 8; ++m) {
      bf16x8 ah = *(const bf16x8*)(Ah + (m * 16 + lr) * 40 + lhi * 8);
      bf16x8 al = *(const bf16x8*)(Al + (m * 16 + lr) * 40 + lhi * 8);
      acc[m] = __builtin_amdgcn_mfma_f32_16x16x32_bf16(ah, bh_, acc[m], 0, 0, 0);
      acc[m] = __builtin_amdgcn_mfma_f32_16x16x32_bf16(ah, bl_, acc[m], 0, 0, 0);
      acc[m] = __builtin_amdgcn_mfma_f32_16x16x32_bf16(al, bh_, acc[m], 0, 0, 0);
    }
  }
  int n = n0 + wv * 16 + lr;
  if (n < 864) {
#pragma unroll
    for (int m = 0; m < 8; ++m) {
#pragma unroll
      for (int r = 0; r < 4; ++r) {
        int mm = m * 16 + lhi * 4 + r;
        part[((size_t)kc * 128 + mm) * 864 + n] = acc[m][r];
      }
    }
  }
}

// ---------------- K3b: reduce K-split partials + bias + relu ----------------
__global__ __launch_bounds__(256) void k_dense_fin(
    const float* __restrict__ part, const float* __restrict__ bias,
    float* __restrict__ filt) {
  int e = blockIdx.x * 256 + threadIdx.x;  // grid 432*256 = 128*864
  float s = bias[e % 864];
#pragma unroll
  for (int kc = 0; kc < 18; ++kc) s += part[(size_t)kc * 110592 + e];
  filt[e] = fmaxf(s, 0.f);
}

// ---------------- K_prep2: per-batch W1eff frags + (block 128) W2 frags ----
__global__ __launch_bounds__(256) void k_prep2(
    const float* __restrict__ filt, const float* __restrict__ W1,
    const float* __restrict__ W2,
    unsigned short* __restrict__ Eh, unsigned short* __restrict__ El,
    unsigned short* __restrict__ W2h, unsigned short* __restrict__ W2l) {
  __shared__ float fl[864];
  int b = blockIdx.x;
  int tid = threadIdx.x;
  if (b == 128) {  // W2 frag prep
    for (int t = tid; t < 2048; t += 256) {
      int j = t & 7, l = (t >> 3) & 63, ks = t >> 9;
      int k = 32 * ks + ((l >> 4) << 3) + j;
      int col = l & 15;
      float v = W2[k * 16 + col];
      unsigned short hh, ll;
      split2(v, hh, ll);
      W2h[t] = hh;
      W2l[t] = ll;
    }
    return;
  }
  for (int f = tid; f < 864; f += 256) fl[f] = filt[(size_t)b * 864 + f];
  __syncthreads();
  int col = tid & 127;
  int k0 = tid >> 7;
  for (int k = k0; k < 64; k += 2) {
    float v;
    if (k < 12) {
      v = W1[k * 128 + col];
    } else if (k < 48) {
      int h = (k - 12) / 3, t = (k - 12) % 3;
      const float* wp = W1 + (12 + t) * 128 + col;  // + c*384 walks rows 12+3c+t
      const float* fp = fl + h * 72;
      float a0 = 0.f, a1 = 0.f, a2 = 0.f, a3 = 0.f;
      for (int c = 0; c < 72; c += 4) {
        a0 = fmaf(fp[c], wp[(size_t)c * 384], a0);
        a1 = fmaf(fp[c + 1], wp[(size_t)(c + 1) * 384], a1);
        a2 = fmaf(fp[c + 2], wp[(size_t)(c + 2) * 384], a2);
        a3 = fmaf(fp[c + 3], wp[(size_t)(c + 3) * 384], a3);
      }
      v = (a0 + a1) + (a2 + a3);
    } else {
      v = 0.f;
    }
    unsigned short hh, ll;
    split2(v, hh, ll);
    int ks = k >> 5, j = k & 7, a4 = (k >> 3) & 3;
    int l = a4 * 16 + (col & 15), nt = col >> 4;
    size_t o = (((size_t)b * 8 + nt) * 2 + ks) * 512 + l * 8 + j;
    Eh[o] = hh;
    El[o] = ll;
  }
}

// ---------------- K4: fused CA update (all-MFMA incl. W2 tail) -------------
__global__ __launch_bounds__(256, 4) void k_ca(
    const float* __restrict__ x,
    const unsigned short* __restrict__ Eh, const unsigned short* __restrict__ El,
    const float* __restrict__ B1,
    const unsigned short* __restrict__ W2h, const unsigned short* __restrict__ W2l,
    const float* __restrict__ B2,
    float* __restrict__ xnew, float* __restrict__ aold,
    float* __restrict__ anew) {
  __shared__ __align__(16) unsigned char S[35072];
  float* ia = (float*)S;
  unsigned short* PAh = (unsigned short*)(S + 7680);
  unsigned short* PAl = (unsigned short*)(S + 16896);
  unsigned short* Uh = (unsigned short*)S;
  unsigned short* Ul = (unsigned short*)(S + 17408);
  float* mskL = (float*)(S + 34816);

  int tid = threadIdx.x;
  int b = blockIdx.y;
  int tx = (blockIdx.x & 7) * 8, ty = (blockIdx.x >> 3) * 8;
  int wv = tid >> 6, lane = tid & 63;
  int lr = lane & 15, lhi = lane >> 4;

  // prefetch W1eff B-frags (global, hides under phase A)
  bf16x8 bh[2][2], bl[2][2];
#pragma unroll
  for (int nt = 0; nt < 2; ++nt)
#pragma unroll
    for (int ks = 0; ks < 2; ++ks) {
      size_t base = (((size_t)b * 8 + (wv * 2 + nt)) * 2 + ks) * 512 + lane * 8;
      bh[nt][ks] = *(const bf16x8*)(Eh + base);
      bl[nt][ks] = *(const bf16x8*)(El + base);
    }
  // prefetch xo for phase D: px = wv*16 + lhi*4 + r, channel lr
  float xo[4];
#pragma unroll
  for (int r = 0; r < 4; ++r) {
    int px = wv * 16 + lhi * 4 + r;
    int gy = ty + (px >> 3), gx = tx + (px & 7);
    xo[r] = x[(((size_t)b * 64 + gy) * 64 + gx) * 16 + lr];
  }

  // ---- phase A: x halo -> ia; threefry -> mskL; zero PA k-pad 48..63
  if (tid < 200) {
    int px_ = tid >> 1, half = tid & 1;
    int hy = px_ / 10, hx = px_ - hy * 10;
    int pp = hy * 12 + hx;
    int gy = ty + hy - 1, gx = tx + hx - 1;
    float4 v0 = {0.f, 0.f, 0.f, 0.f}, v1 = {0.f, 0.f, 0.f, 0.f};
    if (gy >= 0 && gy < 64 && gx >= 0 && gx < 64) {
      const float* xp = x + (((size_t)b * 64 + gy) * 64 + gx) * 16 + half * 8;
      v0 = *(const float4*)xp;
      v1 = *(const float4*)(xp + 4);
    }
    int c0 = half * 8;
    ia[(c0 + 0) * 120 + pp] = v0.x; ia[(c0 + 1) * 120 + pp] = v0.y;
    ia[(c0 + 2) * 120 + pp] = v0.z; ia[(c0 + 3) * 120 + pp] = v0.w;
    ia[(c0 + 4) * 120 + pp] = v1.x; ia[(c0 + 5) * 120 + pp] = v1.y;
    ia[(c0 + 6) * 120 + pp] = v1.z; ia[(c0 + 7) * 120 + pp] = v1.w;
  }
  {
    if (tid >= 192) {
      int p = tid - 192;
      int gy = ty + (p >> 3), gx = tx + (p & 7);
      unsigned pix = (unsigned)(b * 4096 + gy * 64 + gx);
      mskL[p] = (tf42_uniform(pix) <= 0.5f) ? 1.f : 0.f;
    }
    const s16x4 z4 = {0, 0, 0, 0};
    if (wv == 2) {
#pragma unroll
      for (int g = 0; g < 4; ++g) *(s16x4*)(PAh + lane * 72 + 48 + 4 * g) = z4;
    }
    if (wv == 3) {
#pragma unroll
      for (int g = 0; g < 4; ++g) *(s16x4*)(PAl + lane * 72 + 48 + 4 * g) = z4;
    }
  }
  __syncthreads();

  // ---- phase P: perception of ch 4wv..4wv+3 -> PA cols 12wv..12wv+11
  {
    int py = lane >> 3, pxx = lane & 7;
    const float* pc0 = ia + (py + 1) * 12 + (pxx + 1);
    unsigned short oh[12], ol[12];
#pragma unroll
    for (int i = 0; i < 4; ++i) {
      const float* pc = pc0 + (wv * 4 + i) * 120;
      float n00 = pc[-13], n01 = pc[-12], n02 = pc[-11];
      float n10 = pc[-1],  n11 = pc[0],   n12 = pc[1];
      float n20 = pc[11],  n21 = pc[12],  n22 = pc[13];
      float pid = n11;
      float psx = ((n02 - n00) + 2.f * (n12 - n10) + (n22 - n20)) * 0.125f;
      float psy = ((n20 - n00) + 2.f * (n21 - n01) + (n22 - n02)) * 0.125f;
      split2t(pid, oh[3 * i + 0], ol[3 * i + 0]);
      split2t(psx, oh[3 * i + 1], ol[3 * i + 1]);
      split2t(psy, oh[3 * i + 2], ol[3 * i + 2]);
    }
    int off = lane * 72 + wv * 12;
#pragma unroll
    for (int g = 0; g < 3; ++g) {
      s16x4 vh = {(short)oh[4 * g], (short)oh[4 * g + 1],
                  (short)oh[4 * g + 2], (short)oh[4 * g + 3]};
      s16x4 vl = {(short)ol[4 * g], (short)ol[4 * g + 1],
                  (short)ol[4 * g + 2], (short)ol[4 * g + 3]};
      *(s16x4*)(PAh + off + 4 * g) = vh;
      *(s16x4*)(PAl + off + 4 * g) = vl;
    }
  }
  __syncthreads();

  // ---- phase M: main GEMM, 2 ks x 4 m x 2 nt x 3 passes
  f32x4 acc[4][2];
#pragma unroll
  for (int m = 0; m < 4; ++m)
#pragma unroll
    for (int nt = 0; nt < 2; ++nt)
      acc[m][nt] = (f32x4){0.f, 0.f, 0.f, 0.f};
#pragma unroll
  for (int ks = 0; ks < 2; ++ks) {
#pragma unroll
    for (int m = 0; m < 4; ++m) {
      int arow = m * 16 + lr;
      bf16x8 pah = *(const bf16x8*)(PAh + arow * 72 + ks * 32 + lhi * 8);
      bf16x8 pal = *(const bf16x8*)(PAl + arow * 72 + ks * 32 + lhi * 8);
#pragma unroll
      for (int nt = 0; nt < 2; ++nt) {
        acc[m][nt] = __builtin_amdgcn_mfma_f32_16x16x32_bf16(
            pah, bh[nt][ks], acc[m][nt], 0, 0, 0);
        acc[m][nt] = __builtin_amdgcn_mfma_f32_16x16x32_bf16(
            pah, bl[nt][ks], acc[m][nt], 0, 0, 0);
        acc[m][nt] = __builtin_amdgcn_mfma_f32_16x16x32_bf16(
            pal, bh[nt][ks], acc[m][nt], 0, 0, 0);
      }
    }
  }
  // prefetch W2 frags (consumed after next barrier)
  bf16x8 ch_[4], cl_[4];
#pragma unroll
  for (int ks = 0; ks < 4; ++ks) {
    ch_[ks] = *(const bf16x8*)(W2h + ks * 512 + lane * 8);
    cl_[ks] = *(const bf16x8*)(W2l + ks * 512 + lane * 8);
  }
  __syncthreads();  // PA dead -> U region may be written

  // ---- u-exchange: u = relu(acc + B1) as bf16 h/l into Uh/Ul [px][hid]
  int d0 = wv * 32;
  float b1v0 = B1[d0 + lr], b1v1 = B1[d0 + 16 + lr];
#pragma unroll
  for (int m = 0; m < 4; ++m)
#pragma unroll
    for (int nt = 0; nt < 2; ++nt) {
      float bv = nt ? b1v1 : b1v0;
      int hid = d0 + nt * 16 + lr;
#pragma unroll
      for (int r = 0; r < 4; ++r) {
        int px = m * 16 + lhi * 4 + r;
        float uval = fmaxf(acc[m][nt][r] + bv, 0.f);
        unsigned short hh, ll;
        split2t(uval, hh, ll);
        Uh[px * 136 + hid] = hh;
        Ul[px * 136 + hid] = ll;
      }
    }
  __syncthreads();

  // ---- dx MFMA: wave w computes px tile w (16 px x 16 e), K=128 hid
  f32x4 acc2 = {0.f, 0.f, 0.f, 0.f};
#pragma unroll
  for (int ks = 0; ks < 4; ++ks) {
    bf16x8 uh_ = *(const bf16x8*)(Uh + (wv * 16 + lr) * 136 + ks * 32 + lhi * 8);
    bf16x8 ul_ = *(const bf16x8*)(Ul + (wv * 16 + lr) * 136 + ks * 32 + lhi * 8);
    acc2 = __builtin_amdgcn_mfma_f32_16x16x32_bf16(uh_, ch_[ks], acc2, 0, 0, 0);
    acc2 = __builtin_amdgcn_mfma_f32_16x16x32_bf16(uh_, cl_[ks], acc2, 0, 0, 0);
    acc2 = __builtin_amdgcn_mfma_f32_16x16x32_bf16(ul_, ch_[ks], acc2, 0, 0, 0);
  }

  // ---- phase D: dx + fire mask + write x_new + alphas (lane holds e=lr)
  float b2v = B2[lr];
#pragma unroll
  for (int r = 0; r < 4; ++r) {
    int px = wv * 16 + lhi * 4 + r;
    int gy = ty + (px >> 3), gx = tx + (px & 7);
    float m_ = mskL[px];
    float xn = xo[r] + (acc2[r] + b2v) * m_;
    size_t o = (((size_t)b * 64 + gy) * 64 + gx) * 16 + lr;
    xnew[o] = xn;
    if (lr == 3) {
      unsigned pix = (unsigned)(b * 4096 + gy * 64 + gx);
      aold[pix] = xo[r];
      anew[pix] = xn;
    }
  }
}

// ---------------- K5: living masks + final multiply (in place on d_out) ----
__global__ __launch_bounds__(256) void k_final(
    float* __restrict__ xnew, const float* __restrict__ aold,
    const float* __restrict__ anew) {
  int t = blockIdx.x * 256 + threadIdx.x;  // grid 2048*256 = 524288
  int gx = t & 63, gy = (t >> 6) & 63, b = t >> 12;
  float mo = -1e30f, mn = -1e30f;
  for (int dy = -1; dy <= 1; ++dy) {
    int yy = gy + dy; if (yy < 0 || yy >= 64) continue;
    for (int dx = -1; dx <= 1; ++dx) {
      int xx = gx + dx; if (xx < 0 || xx >= 64) continue;
      int p = b * 4096 + yy * 64 + xx;
      mo = fmaxf(mo, aold[p]);
      mn = fmaxf(mn, anew[p]);
    }
  }
  float live = (mo > 0.1f && mn > 0.1f) ? 1.f : 0.f;
  size_t base = (size_t)t * 16;
#pragma unroll
  for (int c4 = 0; c4 < 4; ++c4) {
    float4 v = *(const float4*)(xnew + base + c4 * 4);
    v.x *= live; v.y *= live; v.z *= live; v.w *= live;
    *(float4*)(xnew + base + c4 * 4) = v;
  }
}

// ---------------- launch ----------------
extern "C" void kernel_launch(void* const* d_in, const int* in_sizes, int n_in,
                              void* d_out, int out_size, void* d_ws, size_t ws_size,
                              hipStream_t stream) {
  const float* x    = (const float*)d_in[0];
  const float* img  = (const float*)d_in[1];
  const float* g1   = (const float*)d_in[2];
  const float* be1  = (const float*)d_in[3];
  const float* m1   = (const float*)d_in[4];
  const float* v1   = (const float*)d_in[5];
  const float* w1c  = (const float*)d_in[6];
  const float* b1c  = (const float*)d_in[7];
  const float* g2   = (const float*)d_in[8];
  const float* be2  = (const float*)d_in[9];
  const float* m2   = (const float*)d_in[10];
  const float* v2   = (const float*)d_in[11];
  const float* w2c  = (const float*)d_in[12];
  const float* b2c  = (const float*)d_in[13];
  const float* dw   = (const float*)d_in[14];
  const float* db   = (const float*)d_in[15];
  const float* uw1  = (const float*)d_in[16];
  const float* ub1  = (const float*)d_in[17];
  const float* uw2  = (const float*)d_in[18];
  const float* ub2  = (const float*)d_in[19];

  char* ws = (char*)d_ws;
  float* h1   = (float*)(ws);                        // 21,233,664 B (dead after dense)
  float* part = h1;                                  // aliased
  float* h2   = (float*)(ws + 21233664);             // 5,308,416 B
  float* filt = (float*)(ws + 26542080);             // 442,368 B
  float* aold = (float*)(ws + 26984448);             // 2,097,152 B
  float* anew = (float*)(ws + 29081600);             // 2,097,152 B
  unsigned short* W2Bh = (unsigned short*)(ws + 31178752);  // 4,096 B
  unsigned short* W2Bl = (unsigned short*)(ws + 31182848);  // 4,096 B
  unsigned short* Wc2h = (unsigned short*)(ws + 31186944);  // 18,432 B
  unsigned short* Wc2l = (unsigned short*)(ws + 31205376);  // 18,432 B
  unsigned short* Wc1h = (unsigned short*)(ws + 31223808);  // 6,144 B
  unsigned short* Wc1l = (unsigned short*)(ws + 31229952);  // 6,144 B
  // W1eff frags alias the (dead by then) h1/part region:
  unsigned short* W1Eh = (unsigned short*)(ws);             // 2,097,152 B
  unsigned short* W1El = (unsigned short*)(ws + 2097152);   // 2,097,152 B
  float* xnew = (float*)d_out;                       // (128,64,64,16) f32

  k_prep4<<<12, 256, 0, stream>>>(w1c, Wc1h, Wc1l);
  k_prep3<<<36, 256, 0, stream>>>(w2c, Wc2h, Wc2l);
  k_conv1<<<dim3(25, 128), 256, 0, stream>>>(img, g1, be1, m1, v1, Wc1h, Wc1l,
                                             b1c, g2, be2, m2, v2, h1);
  k_conv2<<<dim3(9, 128), 256, 0, stream>>>(h1, Wc2h, Wc2l, b2c, h2);
  k_dense_part<<<dim3(14, 18), 256, 0, stream>>>(h2, dw, part);
  k_dense_fin<<<432, 256, 0, stream>>>(part, db, filt);
  k_prep2<<<129, 256, 0, stream>>>(filt, uw1, uw2, W1Eh, W1El, W2Bh, W2Bl);
  k_ca<<<dim3(64, 128), 256, 0, stream>>>(x, W1Eh, W1El, ub1, W2Bh, W2Bl, ub2,
                                          xnew, aold, anew);
  k_final<<<2048, 256, 0, stream>>>(xnew, aold, anew);
}

// Round 13
// 177.851 us; speedup vs baseline: 4.0456x; 1.0202x over previous
//
#include <hip/hip_runtime.h>

#define BN_EPS 1e-3f

typedef __attribute__((ext_vector_type(8))) short bf16x8;
typedef __attribute__((ext_vector_type(4))) short s16x4;
typedef __attribute__((ext_vector_type(4))) float f32x4;
typedef __attribute__((ext_vector_type(4))) unsigned u32x4;

// ---------------- bf16 split helpers ----------------
__device__ __forceinline__ unsigned short f2bf_rne(float f) {
  unsigned u = __float_as_uint(f);
  unsigned r = u + 0x7fffu + ((u >> 16) & 1u);
  return (unsigned short)(r >> 16);
}
__device__ __forceinline__ float bf2f(unsigned short h) {
  return __uint_as_float(((unsigned)h) << 16);
}
__device__ __forceinline__ void split2(float v, unsigned short& h, unsigned short& l) {
  h = f2bf_rne(v);
  l = f2bf_rne(v - bf2f(h));
}
// cheaper exact split: hi = truncated bf16 (bit AND), lo = RNE(v - hi).
__device__ __forceinline__ void split2t(float v, unsigned short& h, unsigned short& l) {
  unsigned u = __float_as_uint(v);
  float hi = __uint_as_float(u & 0xFFFF0000u);
  h = (unsigned short)(u >> 16);
  l = f2bf_rne(v - hi);
}
// packed split: returns (hi_trunc) | (lo_rne << 16) in one u32.
__device__ __forceinline__ unsigned pack_bf2(float v) {
  unsigned u = __float_as_uint(v);
  float lof = v - __uint_as_float(u & 0xFFFF0000u);
  unsigned lb = __float_as_uint(lof);
  unsigned rr = lb + 0x7fffu + ((lb >> 16) & 1u);
  return (u >> 16) | (rr & 0xFFFF0000u);
}

// ---------------- threefry2x32 (JAX partitionable path, key=[0,42]) --------
__device__ __forceinline__ unsigned rotl32(unsigned v, int n) {
  return (v << n) | (v >> (32 - n));
}

__device__ __forceinline__ float tf42_uniform(unsigned i) {
  unsigned x0 = 0u, x1 = i;
  const unsigned k0 = 0u, k1 = 42u, k2 = 0u ^ 42u ^ 0x1BD11BDAu;
  x0 += k0; x1 += k1;
#define TFR(r) { x0 += x1; x1 = rotl32(x1, r); x1 ^= x0; }
  TFR(13) TFR(15) TFR(26) TFR(6)
  x0 += k1; x1 += k2 + 1u;
  TFR(17) TFR(29) TFR(16) TFR(24)
  x0 += k2; x1 += k0 + 2u;
  TFR(13) TFR(15) TFR(26) TFR(6)
  x0 += k0; x1 += k1 + 3u;
  TFR(17) TFR(29) TFR(16) TFR(24)
  x0 += k1; x1 += k2 + 4u;
  TFR(13) TFR(15) TFR(26) TFR(6)
  x0 += k2; x1 += k0 + 5u;
#undef TFR
  unsigned bits = x0 ^ x1;
  return __uint_as_float((bits >> 9) | 0x3F800000u) - 1.0f;
}

// ---------------- K_prep_w: all static weight frags in one launch ----------
// blk 0..11: conv1 (3,3,4,32) -> [ks 3][nt 2][lane 64][8], invalid K -> 0
// blk 12..47: conv2 (3,3,32,32) -> [tap 9][nt 2][lane 64][8]
// blk 48: W2 (128,16) -> [ks 4][lane 64][8]
__global__ __launch_bounds__(256) void k_prep_w(
    const float* __restrict__ w1, const float* __restrict__ w2,
    const float* __restrict__ W2d,
    unsigned short* __restrict__ W1h, unsigned short* __restrict__ W1l,
    unsigned short* __restrict__ W2h_, unsigned short* __restrict__ W2l_,
    unsigned short* __restrict__ WD2h, unsigned short* __restrict__ WD2l) {
  int blk = blockIdx.x, tid = threadIdx.x;
  if (blk < 12) {
    int t = blk * 256 + tid;
    int j = t & 7, l = (t >> 3) & 63, nt = (t >> 9) & 1, ks = t >> 10;
    int k = 32 * ks + ((l >> 4) << 3) + j;
    int tap = k >> 3, ci = k & 7;
    float v = (tap < 9 && ci < 4) ? w1[tap * 128 + ci * 32 + nt * 16 + (l & 15)] : 0.f;
    unsigned short hh, ll; split2(v, hh, ll);
    W1h[t] = hh; W1l[t] = ll;
  } else if (blk < 48) {
    int t = (blk - 12) * 256 + tid;
    int j = t & 7, l = (t >> 3) & 63, nt = (t >> 9) & 1, tap = t >> 10;
    int ci = ((l >> 4) << 3) + j, co = nt * 16 + (l & 15);
    float v = w2[tap * 1024 + ci * 32 + co];
    unsigned short hh, ll; split2(v, hh, ll);
    W2h_[t] = hh; W2l_[t] = ll;
  } else {
    for (int t = tid; t < 2048; t += 256) {
      int j = t & 7, l = (t >> 3) & 63, ks = t >> 9;
      int k = 32 * ks + ((l >> 4) << 3) + j;
      int col = l & 15;
      float v = W2d[k * 16 + col];
      unsigned short hh, ll; split2(v, hh, ll);
      WD2h[t] = hh; WD2l[t] = ll;
    }
  }
}

// ---------------- K1: bn1 + conv1(4->32) + relu + maxpool2 + bn2 (MFMA) ----
__global__ __launch_bounds__(256) void k_conv1(
    const float* __restrict__ img,
    const float* __restrict__ g1, const float* __restrict__ be1,
    const float* __restrict__ m1, const float* __restrict__ v1,
    const unsigned short* __restrict__ Wc1h, const unsigned short* __restrict__ Wc1l,
    const float* __restrict__ bias,
    const float* __restrict__ g2, const float* __restrict__ be2,
    const float* __restrict__ m2, const float* __restrict__ v2,
    float* __restrict__ h1) {
  __shared__ __align__(16) unsigned short Lh[2592];  // 324 px * 8
  __shared__ __align__(16) unsigned short Ll[2592];
  int tid = threadIdx.x;
  int b = blockIdx.y;
  int tY = (blockIdx.x / 5) * 16, tX = (blockIdx.x % 5) * 16;
  float s1[4], t1[4];
#pragma unroll
  for (int ci = 0; ci < 4; ++ci) {
    float s = g1[ci] / sqrtf(v1[ci] + BN_EPS);
    s1[ci] = s; t1[ci] = be1[ci] - m1[ci] * s;
  }
  const s16x4 z4 = {0, 0, 0, 0};
  for (int idx = tid; idx < 324; idx += 256) {
    int ly = idx / 18, lx = idx - ly * 18;
    int gy = tY - 1 + ly, gx = tX - 1 + lx;
    float4 v = {0.f, 0.f, 0.f, 0.f};
    if (gy >= 0 && gy < 72 && gx >= 0 && gx < 72) {
      v = *(const float4*)(img + (((size_t)b * 72 + gy) * 72 + gx) * 4);
      v.x = v.x * s1[0] + t1[0];
      v.y = v.y * s1[1] + t1[1];
      v.z = v.z * s1[2] + t1[2];
      v.w = v.w * s1[3] + t1[3];
    }
    unsigned short ha, la, hb, lb, hc, lc, hd, ld;
    split2t(v.x, ha, la); split2t(v.y, hb, lb);
    split2t(v.z, hc, lc); split2t(v.w, hd, ld);
    s16x4 vh = {(short)ha, (short)hb, (short)hc, (short)hd};
    s16x4 vl = {(short)la, (short)lb, (short)lc, (short)ld};
    *(s16x4*)(Lh + idx * 8) = vh;
    *(s16x4*)(Lh + idx * 8 + 4) = z4;
    *(s16x4*)(Ll + idx * 8) = vl;
    *(s16x4*)(Ll + idx * 8 + 4) = z4;
  }
  __syncthreads();
  int wv = tid >> 6, lane = tid & 63;
  int lr = lane & 15, lhi = lane >> 4;
  int nt = wv & 1, mrow0 = (wv >> 1) * 8;
  bf16x8 wh[3], wl[3];
#pragma unroll
  for (int ks = 0; ks < 3; ++ks) {
    int base = ((ks * 2 + nt) * 64 + lane) * 8;
    wh[ks] = *(const bf16x8*)(Wc1h + base);
    wl[ks] = *(const bf16x8*)(Wc1l + base);
  }
  f32x4 acc[8];
#pragma unroll
  for (int mt = 0; mt < 8; ++mt) acc[mt] = (f32x4){0.f, 0.f, 0.f, 0.f};
#pragma unroll
  for (int ks = 0; ks < 3; ++ks) {
    int tap = 4 * ks + lhi;
    int tc = tap > 8 ? 8 : tap;  // invalid taps have B == 0
    int dy = tc / 3, dx = tc - 3 * dy;
#pragma unroll
    for (int mt = 0; mt < 8; ++mt) {
      int row = mrow0 + mt;
      int px = (row + dy) * 18 + lr + dx;
      bf16x8 ah = *(const bf16x8*)(Lh + px * 8);
      bf16x8 al = *(const bf16x8*)(Ll + px * 8);
      acc[mt] = __builtin_amdgcn_mfma_f32_16x16x32_bf16(ah, wh[ks], acc[mt], 0, 0, 0);
      acc[mt] = __builtin_amdgcn_mfma_f32_16x16x32_bf16(ah, wl[ks], acc[mt], 0, 0, 0);
      acc[mt] = __builtin_amdgcn_mfma_f32_16x16x32_bf16(al, wh[ks], acc[mt], 0, 0, 0);
    }
  }
  int co = nt * 16 + lr;
  float bv = bias[co];
  float s2 = g2[co] / sqrtf(v2[co] + BN_EPS);
  float t2 = be2[co] - m2[co] * s2;
#pragma unroll
  for (int a = 0; a < 4; ++a) {
#pragma unroll
    for (int bb = 0; bb < 2; ++bb) {
      float v00 = fmaxf(acc[2 * a][2 * bb] + bv, 0.f);
      float v01 = fmaxf(acc[2 * a][2 * bb + 1] + bv, 0.f);
      float v10 = fmaxf(acc[2 * a + 1][2 * bb] + bv, 0.f);
      float v11 = fmaxf(acc[2 * a + 1][2 * bb + 1] + bv, 0.f);
      float p = fmaxf(fmaxf(v00, v01), fmaxf(v10, v11));
      int gy = (tY >> 1) + (mrow0 >> 1) + a;
      int gx = (tX >> 1) + lhi * 2 + bb;
      if (gy < 36 && gx < 36)
        h1[(((size_t)b * 36 + gy) * 36 + gx) * 32 + co] = p * s2 + t2;
    }
  }
}

// ---------------- K2: conv2(32->32) + relu + maxpool2 (MFMA) ---------------
__global__ __launch_bounds__(256, 3) void k_conv2(
    const float* __restrict__ hin,
    const unsigned short* __restrict__ Wch, const unsigned short* __restrict__ Wcl,
    const float* __restrict__ bias, float* __restrict__ h2) {
  __shared__ __align__(16) unsigned short Lh[12960];  // 324 px * 40
  __shared__ __align__(16) unsigned short Ll[12960];
  int tid = threadIdx.x;
  int b = blockIdx.y;
  int tY = (blockIdx.x / 3) * 16, tX = (blockIdx.x % 3) * 16;
  for (int idx = tid; idx < 2592; idx += 256) {
    int pix = idx >> 3, c4 = idx & 7;
    int ly = pix / 18, lx = pix - ly * 18;
    int gy = tY - 1 + ly, gx = tX - 1 + lx;
    float4 v = {0.f, 0.f, 0.f, 0.f};
    if (gy >= 0 && gy < 36 && gx >= 0 && gx < 36)
      v = *(const float4*)(hin + (((size_t)b * 36 + gy) * 36 + gx) * 32 + c4 * 4);
    unsigned short ha, la, hb, lb, hc, lc, hd, ld;
    split2t(v.x, ha, la); split2t(v.y, hb, lb);
    split2t(v.z, hc, lc); split2t(v.w, hd, ld);
    s16x4 vh = {(short)ha, (short)hb, (short)hc, (short)hd};
    s16x4 vl = {(short)la, (short)lb, (short)lc, (short)ld};
    *(s16x4*)(Lh + pix * 40 + c4 * 4) = vh;
    *(s16x4*)(Ll + pix * 40 + c4 * 4) = vl;
  }
  __syncthreads();
  int wv = tid >> 6, lane = tid & 63;
  int lr = lane & 15, lhi = lane >> 4;
  int nt = wv & 1, mrow0 = (wv >> 1) * 8;
  bf16x8 wh[9], wl[9];
#pragma unroll
  for (int tap = 0; tap < 9; ++tap) {
    int base = ((tap * 2 + nt) * 64 + lane) * 8;
    wh[tap] = *(const bf16x8*)(Wch + base);
    wl[tap] = *(const bf16x8*)(Wcl + base);
  }
  f32x4 acc[8];
#pragma unroll
  for (int mt = 0; mt < 8; ++mt) acc[mt] = (f32x4){0.f, 0.f, 0.f, 0.f};
#pragma unroll
  for (int mt = 0; mt < 8; ++mt) {
    int row = mrow0 + mt;
#pragma unroll
    for (int tap = 0; tap < 9; ++tap) {
      int dy = tap / 3, dx = tap - dy * 3;
      int pixel = (row + dy) * 18 + (lr + dx);
      bf16x8 ah = *(const bf16x8*)(Lh + pixel * 40 + lhi * 8);
      bf16x8 al = *(const bf16x8*)(Ll + pixel * 40 + lhi * 8);
      acc[mt] = __builtin_amdgcn_mfma_f32_16x16x32_bf16(ah, wh[tap], acc[mt], 0, 0, 0);
      acc[mt] = __builtin_amdgcn_mfma_f32_16x16x32_bf16(ah, wl[tap], acc[mt], 0, 0, 0);
      acc[mt] = __builtin_amdgcn_mfma_f32_16x16x32_bf16(al, wh[tap], acc[mt], 0, 0, 0);
    }
  }
  int co = nt * 16 + lr;
  float bv = bias[co];
#pragma unroll
  for (int a = 0; a < 4; ++a) {
#pragma unroll
    for (int bb = 0; bb < 2; ++bb) {
      float v00 = fmaxf(acc[2 * a][2 * bb] + bv, 0.f);
      float v01 = fmaxf(acc[2 * a][2 * bb + 1] + bv, 0.f);
      float v10 = fmaxf(acc[2 * a + 1][2 * bb] + bv, 0.f);
      float v11 = fmaxf(acc[2 * a + 1][2 * bb + 1] + bv, 0.f);
      float p = fmaxf(fmaxf(v00, v01), fmaxf(v10, v11));
      int gy = (tY >> 1) + (mrow0 >> 1) + a;
      int gx = (tX >> 1) + lhi * 2 + bb;
      if (gy < 18 && gx < 18)
        h2[(((size_t)b * 18 + gy) * 18 + gx) * 32 + co] = p;
    }
  }
}

// ---------------- K3a: dense partial GEMM (K-split, MFMA split-bf16) -------
__global__ __launch_bounds__(256) void k_dense_part(
    const float* __restrict__ h2, const float* __restrict__ w,
    float* __restrict__ part) {
  __shared__ __align__(16) unsigned short Ah[128 * 40];
  __shared__ __align__(16) unsigned short Al[128 * 40];
  __shared__ __align__(16) unsigned short Bh[64 * 40];
  __shared__ __align__(16) unsigned short Bl[64 * 40];
  int tid = threadIdx.x;
  int n0 = blockIdx.x * 64;   // 14 blocks (last ragged)
  int kc = blockIdx.y;        // 18 K-chunks of 576
  int wv = tid >> 6, lane = tid & 63;
  int lr = lane & 15, lhi = lane >> 4;
  f32x4 acc[8];
#pragma unroll
  for (int m = 0; m < 8; ++m) acc[m] = (f32x4){0.f, 0.f, 0.f, 0.f};
  for (int kt = 0; kt < 18; ++kt) {
    int kb = kc * 576 + kt * 32;
    if (kt) __syncthreads();
#pragma unroll
    for (int it = 0; it < 4; ++it) {
      int f = tid + it * 256;  // 0..1023 : 128 m rows x 8 float4
      int ml = f >> 3, kq = f & 7;
      float4 p = *(const float4*)(h2 + (size_t)ml * 10368 + kb + kq * 4);
      unsigned short h0, l0, h1, l1, h2_, l2_, h3, l3;
      split2t(p.x, h0, l0); split2t(p.y, h1, l1);
      split2t(p.z, h2_, l2_); split2t(p.w, h3, l3);
      s16x4 vh = {(short)h0, (short)h1, (short)h2_, (short)h3};
      s16x4 vl = {(short)l0, (short)l1, (short)l2_, (short)l3};
      *(s16x4*)(Ah + ml * 40 + kq * 4) = vh;
      *(s16x4*)(Al + ml * 40 + kq * 4) = vl;
    }
#pragma unroll
    for (int it = 0; it < 2; ++it) {
      int f = tid + it * 256;  // 0..511 : 32 k rows x 16 float4
      int kr = f >> 4, n4 = (f & 15) * 4;
      float4 p = {0.f, 0.f, 0.f, 0.f};
      if (n0 + n4 < 864)
        p = *(const float4*)(w + (size_t)(kb + kr) * 864 + n0 + n4);
      unsigned short hh, ll;
      split2t(p.x, hh, ll); Bh[(n4 + 0) * 40 + kr] = hh; Bl[(n4 + 0) * 40 + kr] = ll;
      split2t(p.y, hh, ll); Bh[(n4 + 1) * 40 + kr] = hh; Bl[(n4 + 1) * 40 + kr] = ll;
      split2t(p.z, hh, ll); Bh[(n4 + 2) * 40 + kr] = hh; Bl[(n4 + 2) * 40 + kr] = ll;
      split2t(p.w, hh, ll); Bh[(n4 + 3) * 40 + kr] = hh; Bl[(n4 + 3) * 40 + kr] = ll;
    }
    __syncthreads();
    bf16x8 bh_ = *(const bf16x8*)(Bh + (wv * 16 + lr) * 40 + lhi * 8);
    bf16x8 bl_ = *(const bf16x8*)(Bl + (wv * 16 + lr) * 40 + lhi * 8);
#pragma unroll
    for (int m = 0; m < 8; ++m) {
      bf16x8 ah = *(const bf16x8*)(Ah + (m * 16 + lr) * 40 + lhi * 8);
      bf16x8 al = *(const bf16x8*)(Al + (m * 16 + lr) * 40 + lhi * 8);
      acc[m] = __builtin_amdgcn_mfma_f32_16x16x32_bf16(ah, bh_, acc[m], 0, 0, 0);
      acc[m] = __builtin_amdgcn_mfma_f32_16x16x32_bf16(ah, bl_, acc[m], 0, 0, 0);
      acc[m] = __builtin_amdgcn_mfma_f32_16x16x32_bf16(al, bh_, acc[m], 0, 0, 0);
    }
  }
  int n = n0 + wv * 16 + lr;
  if (n < 864) {
#pragma unroll
    for (int m = 0; m < 8; ++m) {
#pragma unroll
      for (int r = 0; r < 4; ++r) {
        int mm = m * 16 + lhi * 4 + r;
        part[((size_t)kc * 128 + mm) * 864 + n] = acc[m][r];
      }
    }
  }
}

// ---------------- K_finprep: reduce partials -> filt (LDS) -> W1eff frags --
// block b: filt[b][:] = relu(bias + sum_kc part[kc][b][:]) into LDS, then
// W1eff[k][col] frags (prep2 body). filt never hits global.
__global__ __launch_bounds__(256) void k_finprep(
    const float* __restrict__ part, const float* __restrict__ bias,
    const float* __restrict__ W1,
    unsigned short* __restrict__ Eh, unsigned short* __restrict__ El) {
  __shared__ float fl[864];
  int b = blockIdx.x;
  int tid = threadIdx.x;
  for (int e = tid; e < 864; e += 256) {
    float s = bias[e];
#pragma unroll
    for (int kc = 0; kc < 18; ++kc) s += part[(size_t)kc * 110592 + b * 864 + e];
    fl[e] = fmaxf(s, 0.f);
  }
  __syncthreads();
  int col = tid & 127;
  int k0 = tid >> 7;
  for (int k = k0; k < 64; k += 2) {
    float v;
    if (k < 12) {
      v = W1[k * 128 + col];
    } else if (k < 48) {
      int h = (k - 12) / 3, t = (k - 12) % 3;
      const float* wp = W1 + (12 + t) * 128 + col;  // + c*384 walks rows 12+3c+t
      const float* fp = fl + h * 72;
      float a0 = 0.f, a1 = 0.f, a2 = 0.f, a3 = 0.f;
      for (int c = 0; c < 72; c += 4) {
        a0 = fmaf(fp[c], wp[(size_t)c * 384], a0);
        a1 = fmaf(fp[c + 1], wp[(size_t)(c + 1) * 384], a1);
        a2 = fmaf(fp[c + 2], wp[(size_t)(c + 2) * 384], a2);
        a3 = fmaf(fp[c + 3], wp[(size_t)(c + 3) * 384], a3);
      }
      v = (a0 + a1) + (a2 + a3);
    } else {
      v = 0.f;
    }
    unsigned short hh, ll;
    split2(v, hh, ll);
    int ks = k >> 5, j = k & 7, a4 = (k >> 3) & 3;
    int l = a4 * 16 + (col & 15), nt = col >> 4;
    size_t o = (((size_t)b * 8 + nt) * 2 + ks) * 512 + l * 8 + j;
    Eh[o] = hh;
    El[o] = ll;
  }
}

// ---------------- K4: fused CA update (all-MFMA; packed-u32 u-exchange) ----
__global__ __launch_bounds__(256, 4) void k_ca(
    const float* __restrict__ x,
    const unsigned short* __restrict__ Eh, const unsigned short* __restrict__ El,
    const float* __restrict__ B1,
    const unsigned short* __restrict__ W2h, const unsigned short* __restrict__ W2l,
    const float* __restrict__ B2,
    float* __restrict__ xnew, float* __restrict__ aold,
    float* __restrict__ anew) {
  // staging: ia [16][120] f32 @0 (7680) | PAh @7680 (9216) | PAl @16896 (9216)
  // union after main GEMM: U32 @0 [64 px][132] u32 (33792) | mskL @33792 (256)
  __shared__ __align__(16) unsigned char S[34048];
  float* ia = (float*)S;
  unsigned short* PAh = (unsigned short*)(S + 7680);
  unsigned short* PAl = (unsigned short*)(S + 16896);
  unsigned* U32 = (unsigned*)S;
  float* mskL = (float*)(S + 33792);

  int tid = threadIdx.x;
  int b = blockIdx.y;
  int tx = (blockIdx.x & 7) * 8, ty = (blockIdx.x >> 3) * 8;
  int wv = tid >> 6, lane = tid & 63;
  int lr = lane & 15, lhi = lane >> 4;

  // prefetch W1eff B-frags (global, hides under phase A)
  bf16x8 bh[2][2], bl[2][2];
#pragma unroll
  for (int nt = 0; nt < 2; ++nt)
#pragma unroll
    for (int ks = 0; ks < 2; ++ks) {
      size_t base = (((size_t)b * 8 + (wv * 2 + nt)) * 2 + ks) * 512 + lane * 8;
      bh[nt][ks] = *(const bf16x8*)(Eh + base);
      bl[nt][ks] = *(const bf16x8*)(El + base);
    }
  // prefetch xo for phase D: px = wv*16 + lhi*4 + r, channel lr
  float xo[4];
#pragma unroll
  for (int r = 0; r < 4; ++r) {
    int px = wv * 16 + lhi * 4 + r;
    int gy = ty + (px >> 3), gx = tx + (px & 7);
    xo[r] = x[(((size_t)b * 64 + gy) * 64 + gx) * 16 + lr];
  }

  // ---- phase A: x halo -> ia; threefry -> mskL; zero PA k-pad 48..63
  if (tid < 200) {
    int px_ = tid >> 1, half = tid & 1;
    int hy = px_ / 10, hx = px_ - hy * 10;
    int pp = hy * 12 + hx;
    int gy = ty + hy - 1, gx = tx + hx - 1;
    float4 v0 = {0.f, 0.f, 0.f, 0.f}, v1 = {0.f, 0.f, 0.f, 0.f};
    if (gy >= 0 && gy < 64 && gx >= 0 && gx < 64) {
      const float* xp = x + (((size_t)b * 64 + gy) * 64 + gx) * 16 + half * 8;
      v0 = *(const float4*)xp;
      v1 = *(const float4*)(xp + 4);
    }
    int c0 = half * 8;
    ia[(c0 + 0) * 120 + pp] = v0.x; ia[(c0 + 1) * 120 + pp] = v0.y;
    ia[(c0 + 2) * 120 + pp] = v0.z; ia[(c0 + 3) * 120 + pp] = v0.w;
    ia[(c0 + 4) * 120 + pp] = v1.x; ia[(c0 + 5) * 120 + pp] = v1.y;
    ia[(c0 + 6) * 120 + pp] = v1.z; ia[(c0 + 7) * 120 + pp] = v1.w;
  }
  {
    if (tid >= 192) {
      int p = tid - 192;
      int gy = ty + (p >> 3), gx = tx + (p & 7);
      unsigned pix = (unsigned)(b * 4096 + gy * 64 + gx);
      mskL[p] = (tf42_uniform(pix) <= 0.5f) ? 1.f : 0.f;
    }
    const s16x4 z4 = {0, 0, 0, 0};
    if (wv == 2) {
#pragma unroll
      for (int g = 0; g < 4; ++g) *(s16x4*)(PAh + lane * 72 + 48 + 4 * g) = z4;
    }
    if (wv == 3) {
#pragma unroll
      for (int g = 0; g < 4; ++g) *(s16x4*)(PAl + lane * 72 + 48 + 4 * g) = z4;
    }
  }
  __syncthreads();

  // ---- phase P: perception of ch 4wv..4wv+3 -> PA cols 12wv..12wv+11
  {
    int py = lane >> 3, pxx = lane & 7;
    const float* pc0 = ia + (py + 1) * 12 + (pxx + 1);
    unsigned short oh[12], ol[12];
#pragma unroll
    for (int i = 0; i < 4; ++i) {
      const float* pc = pc0 + (wv * 4 + i) * 120;
      float n00 = pc[-13], n01 = pc[-12], n02 = pc[-11];
      float n10 = pc[-1],  n11 = pc[0],   n12 = pc[1];
      float n20 = pc[11],  n21 = pc[12],  n22 = pc[13];
      float pid = n11;
      float psx = ((n02 - n00) + 2.f * (n12 - n10) + (n22 - n20)) * 0.125f;
      float psy = ((n20 - n00) + 2.f * (n21 - n01) + (n22 - n02)) * 0.125f;
      split2t(pid, oh[3 * i + 0], ol[3 * i + 0]);
      split2t(psx, oh[3 * i + 1], ol[3 * i + 1]);
      split2t(psy, oh[3 * i + 2], ol[3 * i + 2]);
    }
    int off = lane * 72 + wv * 12;
#pragma unroll
    for (int g = 0; g < 3; ++g) {
      s16x4 vh = {(short)oh[4 * g], (short)oh[4 * g + 1],
                  (short)oh[4 * g + 2], (short)oh[4 * g + 3]};
      s16x4 vl = {(short)ol[4 * g], (short)ol[4 * g + 1],
                  (short)ol[4 * g + 2], (short)ol[4 * g + 3]};
      *(s16x4*)(PAh + off + 4 * g) = vh;
      *(s16x4*)(PAl + off + 4 * g) = vl;
    }
  }
  __syncthreads();

  // ---- phase M: main GEMM, 2 ks x 4 m x 2 nt x 3 passes
  f32x4 acc[4][2];
#pragma unroll
  for (int m = 0; m < 4; ++m)
#pragma unroll
    for (int nt = 0; nt < 2; ++nt)
      acc[m][nt] = (f32x4){0.f, 0.f, 0.f, 0.f};
#pragma unroll
  for (int ks = 0; ks < 2; ++ks) {
#pragma unroll
    for (int m = 0; m < 4; ++m) {
      int arow = m * 16 + lr;
      bf16x8 pah = *(const bf16x8*)(PAh + arow * 72 + ks * 32 + lhi * 8);
      bf16x8 pal = *(const bf16x8*)(PAl + arow * 72 + ks * 32 + lhi * 8);
#pragma unroll
      for (int nt = 0; nt < 2; ++nt) {
        acc[m][nt] = __builtin_amdgcn_mfma_f32_16x16x32_bf16(
            pah, bh[nt][ks], acc[m][nt], 0, 0, 0);
        acc[m][nt] = __builtin_amdgcn_mfma_f32_16x16x32_bf16(
            pah, bl[nt][ks], acc[m][nt], 0, 0, 0);
        acc[m][nt] = __builtin_amdgcn_mfma_f32_16x16x32_bf16(
            pal, bh[nt][ks], acc[m][nt], 0, 0, 0);
      }
    }
  }
  // prefetch W2 frags (consumed after next barrier)
  bf16x8 ch_[4], cl_[4];
#pragma unroll
  for (int ks = 0; ks < 4; ++ks) {
    ch_[ks] = *(const bf16x8*)(W2h + ks * 512 + lane * 8);
    cl_[ks] = *(const bf16x8*)(W2l + ks * 512 + lane * 8);
  }
  __syncthreads();  // PA dead -> U region may be written

  // ---- u-exchange: u = relu(acc + B1) packed (hi | lo<<16) into U32 [px][hid]
  int d0 = wv * 32;
  float b1v0 = B1[d0 + lr], b1v1 = B1[d0 + 16 + lr];
#pragma unroll
  for (int m = 0; m < 4; ++m)
#pragma unroll
    for (int nt = 0; nt < 2; ++nt) {
      float bv = nt ? b1v1 : b1v0;
      int hid = d0 + nt * 16 + lr;
#pragma unroll
      for (int r = 0; r < 4; ++r) {
        int px = m * 16 + lhi * 4 + r;
        U32[px * 132 + hid] = pack_bf2(fmaxf(acc[m][nt][r] + bv, 0.f));
      }
    }
  __syncthreads();

  // ---- dx MFMA: wave w computes px tile w (16 px x 16 e), K=128 hid
  union Cvt { unsigned d[4]; bf16x8 v8; };
  f32x4 acc2 = {0.f, 0.f, 0.f, 0.f};
  const unsigned* urow = U32 + (wv * 16 + lr) * 132;
#pragma unroll
  for (int ks = 0; ks < 4; ++ks) {
    u32x4 q0 = *(const u32x4*)(urow + ks * 32 + lhi * 8);
    u32x4 q1 = *(const u32x4*)(urow + ks * 32 + lhi * 8 + 4);
    Cvt ah, al;
#pragma unroll
    for (int i = 0; i < 2; ++i) {
      unsigned p0 = q0[2 * i], p1 = q0[2 * i + 1];
      ah.d[i] = (p0 & 0xffffu) | (p1 << 16);
      al.d[i] = (p0 >> 16) | (p1 & 0xffff0000u);
    }
#pragma unroll
    for (int i = 0; i < 2; ++i) {
      unsigned p0 = q1[2 * i], p1 = q1[2 * i + 1];
      ah.d[2 + i] = (p0 & 0xffffu) | (p1 << 16);
      al.d[2 + i] = (p0 >> 16) | (p1 & 0xffff0000u);
    }
    acc2 = __builtin_amdgcn_mfma_f32_16x16x32_bf16(ah.v8, ch_[ks], acc2, 0, 0, 0);
    acc2 = __builtin_amdgcn_mfma_f32_16x16x32_bf16(ah.v8, cl_[ks], acc2, 0, 0, 0);
    acc2 = __builtin_amdgcn_mfma_f32_16x16x32_bf16(al.v8, ch_[ks], acc2, 0, 0, 0);
  }

  // ---- phase D: dx + fire mask + write x_new + alphas (lane holds e=lr)
  float b2v = B2[lr];
#pragma unroll
  for (int r = 0; r < 4; ++r) {
    int px = wv * 16 + lhi * 4 + r;
    int gy = ty + (px >> 3), gx = tx + (px & 7);
    float m_ = mskL[px];
    float xn = xo[r] + (acc2[r] + b2v) * m_;
    size_t o = (((size_t)b * 64 + gy) * 64 + gx) * 16 + lr;
    xnew[o] = xn;
    if (lr == 3) {
      unsigned pix = (unsigned)(b * 4096 + gy * 64 + gx);
      aold[pix] = xo[r];
      anew[pix] = xn;
    }
  }
}

// ---------------- K5: living masks + final multiply (in place on d_out) ----
__global__ __launch_bounds__(256) void k_final(
    float* __restrict__ xnew, const float* __restrict__ aold,
    const float* __restrict__ anew) {
  int t = blockIdx.x * 256 + threadIdx.x;  // grid 2048*256 = 524288
  int gx = t & 63, gy = (t >> 6) & 63, b = t >> 12;
  float mo = -1e30f, mn = -1e30f;
  for (int dy = -1; dy <= 1; ++dy) {
    int yy = gy + dy; if (yy < 0 || yy >= 64) continue;
    for (int dx = -1; dx <= 1; ++dx) {
      int xx = gx + dx; if (xx < 0 || xx >= 64) continue;
      int p = b * 4096 + yy * 64 + xx;
      mo = fmaxf(mo, aold[p]);
      mn = fmaxf(mn, anew[p]);
    }
  }
  float live = (mo > 0.1f && mn > 0.1f) ? 1.f : 0.f;
  size_t base = (size_t)t * 16;
#pragma unroll
  for (int c4 = 0; c4 < 4; ++c4) {
    float4 v = *(const float4*)(xnew + base + c4 * 4);
    v.x *= live; v.y *= live; v.z *= live; v.w *= live;
    *(float4*)(xnew + base + c4 * 4) = v;
  }
}

// ---------------- launch ----------------
extern "C" void kernel_launch(void* const* d_in, const int* in_sizes, int n_in,
                              void* d_out, int out_size, void* d_ws, size_t ws_size,
                              hipStream_t stream) {
  const float* x    = (const float*)d_in[0];
  const float* img  = (const float*)d_in[1];
  const float* g1   = (const float*)d_in[2];
  const float* be1  = (const float*)d_in[3];
  const float* m1   = (const float*)d_in[4];
  const float* v1   = (const float*)d_in[5];
  const float* w1c  = (const float*)d_in[6];
  const float* b1c  = (const float*)d_in[7];
  const float* g2   = (const float*)d_in[8];
  const float* be2  = (const float*)d_in[9];
  const float* m2   = (const float*)d_in[10];
  const float* v2   = (const float*)d_in[11];
  const float* w2c  = (const float*)d_in[12];
  const float* b2c  = (const float*)d_in[13];
  const float* dw   = (const float*)d_in[14];
  const float* db   = (const float*)d_in[15];
  const float* uw1  = (const float*)d_in[16];
  const float* ub1  = (const float*)d_in[17];
  const float* uw2  = (const float*)d_in[18];
  const float* ub2  = (const float*)d_in[19];

  char* ws = (char*)d_ws;
  float* h1   = (float*)(ws);                        // 21,233,664 B (dead after conv2)
  float* part = h1;                                  // aliased (written by dense)
  float* h2   = (float*)(ws + 21233664);             // 5,308,416 B
  float* aold = (float*)(ws + 26542080);             // 2,097,152 B
  float* anew = (float*)(ws + 28639232);             // 2,097,152 B
  unsigned short* W2Bh = (unsigned short*)(ws + 30736384);  // 4,096 B
  unsigned short* W2Bl = (unsigned short*)(ws + 30740480);  // 4,096 B
  unsigned short* Wc2h = (unsigned short*)(ws + 30744576);  // 18,432 B
  unsigned short* Wc2l = (unsigned short*)(ws + 30763008);  // 18,432 B
  unsigned short* Wc1h = (unsigned short*)(ws + 30781440);  // 6,144 B
  unsigned short* Wc1l = (unsigned short*)(ws + 30787584);  // 6,144 B
  unsigned short* W1Eh = (unsigned short*)(ws + 30793728);  // 2,097,152 B
  unsigned short* W1El = (unsigned short*)(ws + 32890880);  // 2,097,152 B
  // total 34,988,032 B
  float* xnew = (float*)d_out;                       // (128,64,64,16) f32

  k_prep_w<<<49, 256, 0, stream>>>(w1c, w2c, uw2, Wc1h, Wc1l, Wc2h, Wc2l,
                                   W2Bh, W2Bl);
  k_conv1<<<dim3(25, 128), 256, 0, stream>>>(img, g1, be1, m1, v1, Wc1h, Wc1l,
                                             b1c, g2, be2, m2, v2, h1);
  k_conv2<<<dim3(9, 128), 256, 0, stream>>>(h1, Wc2h, Wc2l, b2c, h2);
  k_dense_part<<<dim3(14, 18), 256, 0, stream>>>(h2, dw, part);
  k_finprep<<<128, 256, 0, stream>>>(part, db, uw1, W1Eh, W1El);
  k_ca<<<dim3(64, 128), 256, 0, stream>>>(x, W1Eh, W1El, ub1, W2Bh, W2Bl, ub2,
                                          xnew, aold, anew);
  k_final<<<2048, 256, 0, stream>>>(xnew, aold, anew);
}